// Round 16
// baseline (832.310 us; speedup 1.0000x reference)
//
#include <hip/hip_runtime.h>
#include <stdint.h>
#include <math.h>

#define T_ 2048
#define DM 2048
#define NH 16
#define NKV 2
#define HD 128
#define QKVN 2560
#define NE 16
#define IM 768
#define ISH 768
#define MAXROWS 10240
#define ROWS_ALL 12288   // MAXROWS + T_ (shared region appended)
#define NBLK 136         // 16*17/2 causal 128x128 blocks per head
#define SM_SCALE 0.08838834764831845f

typedef __attribute__((ext_vector_type(8))) short short8;
typedef __attribute__((ext_vector_type(4))) float f32x4;

__device__ __forceinline__ float bf2f(unsigned short u){ return __uint_as_float(((unsigned int)u)<<16); }
__device__ __forceinline__ unsigned short f2bf(float f){
  unsigned int u = __float_as_uint(f);
  return (unsigned short)((u + 0x7FFFu + ((u>>16)&1u)) >> 16);
}
__device__ __forceinline__ void split2(float x, unsigned short& hi, unsigned short& lo){
  hi = f2bf(x);
  lo = f2bf(x - bf2f(hi));
}

__device__ __forceinline__ void gload16(const void* g, void* l){
  __builtin_amdgcn_global_load_lds((const __attribute__((address_space(1))) unsigned int*)g,
                                   (__attribute__((address_space(3))) unsigned int*)l, 16, 0, 0);
}

// bijective XCD swizzle (m204)
__device__ __forceinline__ int xcd_swz(int bid, int nwg){
  int q = nwg >> 3, r = nwg & 7, x = bid & 7, p = bid >> 3;
  return (x < r ? x*(q+1) : r*(q+1) + (x-r)*q) + p;
}

#define BAR()    asm volatile("s_barrier" ::: "memory")
#define VW(N)    asm volatile("s_waitcnt vmcnt(" #N ")" ::: "memory")
#define LW0()    do{ asm volatile("s_waitcnt lgkmcnt(0)" ::: "memory"); __builtin_amdgcn_sched_barrier(0); }while(0)

// ------- transpose conv f32 -> bf16, vectorized (64x64 tile, float4 in, short8 out) ----
// ILV: g/u 8-col interleave. Last z (== gridDim.z-1) optionally reads/writes shared-weight ptrs.
template<bool ILV>
__global__ void k_tconv(const float* __restrict__ src, unsigned short* __restrict__ dst,
                        const float* __restrict__ srcS, unsigned short* __restrict__ dstS,
                        int R, int C, size_t sS, size_t sD){
  int z = blockIdx.z;
  if (srcS && z == gridDim.z-1){ src = srcS; dst = dstS; }
  else { src += (size_t)z * sS; dst += (size_t)z * sD; }
  __shared__ float tile[64*65];
  int tid = threadIdx.x;
  int r0 = blockIdx.y*64, c0 = blockIdx.x*64;
  int lr = tid>>4, lc = (tid&15)*4;
  #pragma unroll
  for (int j=0;j<4;j++){
    int row = j*16 + lr;
    float4 v = *(const float4*)&src[(size_t)(r0+row)*C + c0 + lc];
    float* t = &tile[row*65 + lc];
    t[0]=v.x; t[1]=v.y; t[2]=v.z; t[3]=v.w;
  }
  __syncthreads();
  #pragma unroll
  for (int jj=0;jj<2;jj++){
    int slot = jj*256 + tid;
    int c = slot>>3, ro = (slot&7)*8;
    int cg = c0 + c;
    int cd = cg;
    if (ILV){ int b = cg>>3, inner = cg&7; cd = (b<96 ? b*16 : (b-96)*16+8) + inner; }
    short8 o;
    #pragma unroll
    for (int k=0;k<8;k++) o[k] = (short)f2bf(tile[(ro+k)*65 + c]);
    *(short8*)&dst[(size_t)cd*R + r0 + ro] = o;
  }
}

// ------- transpose conv f32 -> bf16 hi + lo planes, vectorized -------
__global__ void k_tconv2(const float* __restrict__ src, unsigned short* __restrict__ dhi,
                         unsigned short* __restrict__ dlo, int R, int C){
  __shared__ float tile[64*65];
  int tid = threadIdx.x;
  int r0 = blockIdx.y*64, c0 = blockIdx.x*64;
  int lr = tid>>4, lc = (tid&15)*4;
  #pragma unroll
  for (int j=0;j<4;j++){
    int row = j*16 + lr;
    float4 v = *(const float4*)&src[(size_t)(r0+row)*C + c0 + lc];
    float* t = &tile[row*65 + lc];
    t[0]=v.x; t[1]=v.y; t[2]=v.z; t[3]=v.w;
  }
  __syncthreads();
  #pragma unroll
  for (int jj=0;jj<2;jj++){
    int slot = jj*256 + tid;
    int c = slot>>3, ro = (slot&7)*8;
    short8 oh, ol;
    #pragma unroll
    for (int k=0;k<8;k++){
      unsigned short h_, l_;
      split2(tile[(ro+k)*65 + c], h_, l_);
      oh[k] = (short)h_; ol[k] = (short)l_;
    }
    size_t o = (size_t)(c0+c)*R + r0 + ro;
    *(short8*)&dhi[o] = oh;
    *(short8*)&dlo[o] = ol;
  }
}

// ---------------- add + rmsnorm; ROUTE: fused MoE gate (no global atomics) ----------------
template<bool ROUTE>
__global__ void k_add_rmsnorm(const float* __restrict__ a, const float* __restrict__ b,
                              const float* __restrict__ w, float* __restrict__ resout,
                              unsigned short* __restrict__ ohi, unsigned short* __restrict__ olo,
                              unsigned short* __restrict__ obf,
                              const float* __restrict__ gw, const float* __restrict__ gbias,
                              int* __restrict__ idx4, float* __restrict__ w4){
  int t = blockIdx.x, tid = threadIdx.x;
  const float4* a4 = (const float4*)(a + (size_t)t*DM);
  const float4* b4 = (const float4*)(b + (size_t)t*DM);
  float4 va = a4[tid], vb = b4[tid];
  float4 wa = a4[tid+256], wb = b4[tid+256];
  float4 v0, v1;
  v0.x=va.x+vb.x; v0.y=va.y+vb.y; v0.z=va.z+vb.z; v0.w=va.w+vb.w;
  v1.x=wa.x+wb.x; v1.y=wa.y+wb.y; v1.z=wa.z+wb.z; v1.w=wa.w+wb.w;
  float s = v0.x*v0.x+v0.y*v0.y+v0.z*v0.z+v0.w*v0.w
          + v1.x*v1.x+v1.y*v1.y+v1.z*v1.z+v1.w*v1.w;
  #pragma unroll
  for (int o=32;o;o>>=1) s += __shfl_xor(s,o);
  __shared__ float sm[4];
  if ((tid&63)==0) sm[tid>>6]=s;
  __syncthreads();
  s = sm[0]+sm[1]+sm[2]+sm[3];
  float rs = rsqrtf(s*(1.f/(float)DM) + 1e-5f);
  ((float4*)(resout + (size_t)t*DM))[tid] = v0;
  ((float4*)(resout + (size_t)t*DM))[tid+256] = v1;
  const float4* w4p_ = (const float4*)w;
  float4 w0 = w4p_[tid], w1 = w4p_[tid+256];
  float n[8] = { v0.x*rs*w0.x, v0.y*rs*w0.y, v0.z*rs*w0.z, v0.w*rs*w0.w,
                 v1.x*rs*w1.x, v1.y*rs*w1.y, v1.z*rs*w1.z, v1.w*rs*w1.w };
  if (ohi){
    ushort4 h0,h1,l0,l1;
    split2(n[0],h0.x,l0.x); split2(n[1],h0.y,l0.y); split2(n[2],h0.z,l0.z); split2(n[3],h0.w,l0.w);
    split2(n[4],h1.x,l1.x); split2(n[5],h1.y,l1.y); split2(n[6],h1.z,l1.z); split2(n[7],h1.w,l1.w);
    ((ushort4*)(ohi + (size_t)t*DM))[tid] = h0;
    ((ushort4*)(ohi + (size_t)t*DM))[tid+256] = h1;
    ((ushort4*)(olo + (size_t)t*DM))[tid] = l0;
    ((ushort4*)(olo + (size_t)t*DM))[tid+256] = l1;
  }
  if (obf){
    ushort4 o0 = make_ushort4(f2bf(n[0]),f2bf(n[1]),f2bf(n[2]),f2bf(n[3]));
    ushort4 o1 = make_ushort4(f2bf(n[4]),f2bf(n[5]),f2bf(n[6]),f2bf(n[7]));
    ((ushort4*)(obf + (size_t)t*DM))[tid] = o0;
    ((ushort4*)(obf + (size_t)t*DM))[tid+256] = o1;
  }
  if constexpr (ROUTE){
    __shared__ float xrow[DM];          // 8 KB
    __shared__ float red[16][17];
    #pragma unroll
    for (int jj=0;jj<4;jj++) xrow[4*tid+jj] = n[jj];
    #pragma unroll
    for (int jj=0;jj<4;jj++) xrow[1024+4*tid+jj] = n[4+jj];
    __syncthreads();
    // coalesced gate GEMV: lane (grp=tid>>4, e=tid&15); gw row-major [DM][16]
    int e = tid & 15, grp = tid >> 4;
    float part = 0.f;
    #pragma unroll 8
    for (int c = grp; c < DM; c += 16)
      part += xrow[c] * gw[(size_t)c*16 + e];
    red[grp][e] = part;
    __syncthreads();
    if (tid==0){
      float sc[16], sb[16];
      for (int ee=0;ee<16;ee++){
        float lg = 0.f;
        for (int g2=0;g2<16;g2++) lg += red[g2][ee];
        sc[ee] = 1.f/(1.f+expf(-lg));
        sb[ee] = sc[ee] + gbias[ee];
      }
      float gs[4];
      for (int g=0;g<4;g++){
        float m1=-3.4e38f, m2=-3.4e38f;
        for (int j=0;j<4;j++){
          float v = sb[g*4+j];
          if (v>m1){ m2=m1; m1=v; } else if (v>m2) m2=v;
        }
        gs[g]=m1+m2;
      }
      int g1=0; for (int g=1;g<4;g++) if (gs[g]>gs[g1]) g1=g;
      int g2=-1; for (int g=0;g<4;g++){ if (g==g1) continue; if (g2<0 || gs[g]>gs[g2]) g2=g; }
      float msk[16];
      for (int ee=0;ee<16;ee++){ int g=ee>>2; msk[ee] = (g==g1||g==g2)? sb[ee] : -3.4e38f; }
      int id[4]; float wv[4]; float wsum=0.f;
      for (int s2=0;s2<4;s2++){
        int bb=0; float bv=-3.5e38f;
        for (int ee=0;ee<16;ee++) if (msk[ee]>bv){ bv=msk[ee]; bb=ee; }
        id[s2]=bb; wv[s2]=sc[bb]; wsum+=sc[bb]; msk[bb]=-3.5e38f;
      }
      float invs = 1.f/wsum;
      for (int s2=0;s2<4;s2++){
        idx4[t*4+s2]=id[s2];
        w4[t*4+s2]=wv[s2]*invs;
      }
    }
  }
}

// ------- grouped bf16 GEMM (experts + shared), BK=32 counted-vmcnt 2-deep pipeline -------
// ACT: B cols are (g,u) 8-interleaved; epilogue computes silu(g)*u -> bf16 C [rows][IM]
template<bool GATHER, bool ACT>
__global__ __launch_bounds__(256) void k_gemm2(
    const unsigned short* __restrict__ A, const unsigned short* __restrict__ Be,
    const unsigned short* __restrict__ Bsh, unsigned short* __restrict__ C,
    int K, int lda, int ldb, int ldc,
    const int* __restrict__ offs, size_t sBe, const int* __restrict__ tok){
  int nx = gridDim.x;
  int nwg = nx * gridDim.y;
  int wid_ = xcd_swz(blockIdx.x + nx*blockIdx.y, nwg);
  int tN = wid_ % nx, tM = wid_ / nx;
  int rb = tM*128;
  if (rb >= offs[17]) return;
  const unsigned short* B;
  if (rb >= offs[16]) B = Bsh;
  else {
    int e=0;
    for (; e<15; ++e) if (offs[e+1] > rb) break;
    B = Be + (size_t)e*sBe;
  }
  __shared__ __align__(16) unsigned short As[2][4096];
  __shared__ __align__(16) unsigned short Bs[2][4096];
  int tid = threadIdx.x, lane = tid & 63, wwid = tid >> 6;
  int wr = wwid >> 1, wc = wwid & 1;
  const unsigned short* Bb = B + (size_t)tN*128*ldb;

  const unsigned short* Asrc0;
  const unsigned short* Asrc1;
  int r0s = tid>>2, r1s = r0s + 64;
  {
    if (GATHER){
      Asrc0 = A + (size_t)tok[rb + r0s]*lda;
      Asrc1 = A + (size_t)tok[rb + r1s]*lda;
    } else {
      Asrc0 = A + (size_t)(rb + r0s)*lda;
      Asrc1 = A + (size_t)(rb + r1s)*lda;
    }
  }
  int kc = tid&3;
  int sw = (r0s>>1)&3;
  int kcS = (kc ^ sw)*8;

  f32x4 acc[4][4];
  #pragma unroll
  for (int m=0;m<4;m++)
    #pragma unroll
    for (int n=0;n<4;n++) acc[m][n] = (f32x4){0.f,0.f,0.f,0.f};

  auto STAGE = [&](int b, int k0){
    gload16(Asrc0 + k0 + kcS, As[b] + (size_t)tid*8);
    gload16(Asrc1 + k0 + kcS, As[b] + (size_t)(256+tid)*8);
    gload16(Bb + (size_t)r0s*ldb + k0 + kcS, Bs[b] + (size_t)tid*8);
    gload16(Bb + (size_t)r1s*ldb + k0 + kcS, Bs[b] + (size_t)(256+tid)*8);
  };

  int nt = K >> 5, L = nt - 1;
  STAGE(0, 0);
  if (L >= 1) STAGE(1, 32);
  int i15 = lane & 15, g = lane >> 4;
  for (int i=0; i<nt; ++i){
    int cur = i & 1;
    if (i < L) { VW(4); } else { VW(0); }
    BAR();
    short8 af[4], bfr[4];
    #pragma unroll
    for (int m=0;m<4;m++){
      int row = wr*64 + m*16 + i15;
      int geff = g ^ ((row>>1)&3);
      af[m] = *(const short8*)(As[cur] + row*32 + geff*8);
    }
    #pragma unroll
    for (int n=0;n<4;n++){
      int row = wc*64 + n*16 + i15;
      int geff = g ^ ((row>>1)&3);
      bfr[n] = *(const short8*)(Bs[cur] + row*32 + geff*8);
    }
    LW0();
    BAR();
    if (i + 2 <= L) STAGE(cur, (i+2)*32);
    __builtin_amdgcn_s_setprio(1);
    #pragma unroll
    for (int m=0;m<4;m++)
      #pragma unroll
      for (int n=0;n<4;n++)
        acc[m][n] = __builtin_amdgcn_mfma_f32_16x16x32_bf16(af[m], bfr[n], acc[m][n], 0,0,0);
    __builtin_amdgcn_s_setprio(0);
  }

  if (ACT){
    int rbase = rb + wr*64, cb = tN*128 + wc*64;
    #pragma unroll
    for (int m=0;m<4;m++){
      int r0 = rbase + m*16 + ((lane>>4)<<2);
      #pragma unroll
      for (int n=0;n<4;n++){
        int f = ((cb + n*16)>>1) + (lane&7);
        #pragma unroll
        for (int r=0;r<4;r++){
          float v = acc[m][n][r];
          float vp = __shfl_xor(v, 8);
          if (!(lane&8)){
            float gg = v;
            float a = gg/(1.f+__expf(-gg))*vp;
            C[(size_t)(r0+r)*ldc + f] = f2bf(a);
          }
        }
      }
    }
  } else {
    int rbase = rb + wr*64, cb = tN*128 + wc*64;
    #pragma unroll
    for (int m=0;m<4;m++){
      int r0 = rbase + m*16 + ((lane>>4)<<2);
      #pragma unroll
      for (int n=0;n<4;n++){
        int c = cb + n*16 + (lane&15);
        #pragma unroll
        for (int r=0;r<4;r++) C[(size_t)(r0+r)*ldc + c] = f2bf(acc[m][n][r]);
      }
    }
  }
}

// ---------------- high-precision bf16x3 GEMM (plain, XCD swizzle) ----
__global__ __launch_bounds__(256) void k_gemm_hp(
    const unsigned short* __restrict__ Ah, const unsigned short* __restrict__ Al,
    const unsigned short* __restrict__ Bh, const unsigned short* __restrict__ Bl,
    float* __restrict__ Cf,
    int K, int lda, int ldb, int ldc){
  int nx = gridDim.x, nwg = nx*gridDim.y;
  int w = xcd_swz(blockIdx.x + nx*blockIdx.y, nwg);
  int tN = w % nx, tM = w / nx;

  __shared__ __align__(16) unsigned short AsH[2][4096], AsL[2][4096];
  __shared__ __align__(16) unsigned short BsH[2][4096], BsL[2][4096];
  int tid = threadIdx.x, lane = tid & 63, wid = tid >> 6;
  int wr = wid >> 1, wc = wid & 1;
  const unsigned short* Abh = Ah + (size_t)tM*128*lda;
  const unsigned short* Abl = Al + (size_t)tM*128*lda;
  const unsigned short* Bbh = Bh + (size_t)tN*128*ldb;
  const unsigned short* Bbl = Bl + (size_t)tN*128*ldb;

  f32x4 acc[4][4];
  #pragma unroll
  for (int m=0;m<4;m++)
    #pragma unroll
    for (int n=0;n<4;n++) acc[m][n] = (f32x4){0.f,0.f,0.f,0.f};

  auto STAGE = [&](int b, int k0){
    #pragma unroll
    for (int j=0;j<2;j++){
      int cb = j*256 + tid;
      int row = cb>>2, kc = cb&3;
      int kcS = (kc ^ ((row>>1)&3))*8;
      size_t go = (size_t)row*lda + k0 + kcS;
      gload16(Abh + go, AsH[b] + (size_t)cb*8);
      gload16(Abl + go, AsL[b] + (size_t)cb*8);
      size_t bo = (size_t)row*ldb + k0 + kcS;
      gload16(Bbh + bo, BsH[b] + (size_t)cb*8);
      gload16(Bbl + bo, BsL[b] + (size_t)cb*8);
    }
  };

  int nt = K >> 5, L = nt - 1;
  STAGE(0, 0);
  if (L >= 1) STAGE(1, 32);
  int i15 = lane & 15, g = lane >> 4;
  for (int i=0; i<nt; ++i){
    int cur = i & 1;
    if (i < L) { VW(8); } else { VW(0); }
    BAR();
    short8 afh[4], afl[4], bfh[4], bfl[4];
    #pragma unroll
    for (int m=0;m<4;m++){
      int row = wr*64 + m*16 + i15;
      int ro = row*32 + (g ^ ((row>>1)&3))*8;
      afh[m] = *(const short8*)(AsH[cur] + ro);
      afl[m] = *(const short8*)(AsL[cur] + ro);
    }
    #pragma unroll
    for (int n=0;n<4;n++){
      int row = wc*64 + n*16 + i15;
      int ro = row*32 + (g ^ ((row>>1)&3))*8;
      bfh[n] = *(const short8*)(BsH[cur] + ro);
      bfl[n] = *(const short8*)(BsL[cur] + ro);
    }
    LW0();
    BAR();
    if (i + 2 <= L) STAGE(cur, (i+2)*32);
    __builtin_amdgcn_s_setprio(1);
    #pragma unroll
    for (int m=0;m<4;m++)
      #pragma unroll
      for (int n=0;n<4;n++){
        acc[m][n] = __builtin_amdgcn_mfma_f32_16x16x32_bf16(afh[m], bfh[n], acc[m][n], 0,0,0);
        acc[m][n] = __builtin_amdgcn_mfma_f32_16x16x32_bf16(afh[m], bfl[n], acc[m][n], 0,0,0);
        acc[m][n] = __builtin_amdgcn_mfma_f32_16x16x32_bf16(afl[m], bfh[n], acc[m][n], 0,0,0);
      }
    __builtin_amdgcn_s_setprio(0);
  }

  int rb = tM*128 + wr*64, cb = tN*128 + wc*64;
  #pragma unroll
  for (int m=0;m<4;m++){
    int r0 = rb + m*16 + ((lane>>4)<<2);
    #pragma unroll
    for (int n=0;n<4;n++){
      int c = cb + n*16 + (lane&15);
      #pragma unroll
      for (int r=0;r<4;r++) Cf[(size_t)(r0+r)*ldc + c] = acc[m][n][r];
    }
  }
}

// ------- persistent block-row QK^T (hp bf16x3) + fused softmax partials -------
// grid (tM, head). Per 128x128 tile writes S and per-wave (max, sum) partials.
__global__ __launch_bounds__(256) void k_qk_pers(
    const unsigned short* __restrict__ Qh, const unsigned short* __restrict__ Ql,
    const unsigned short* __restrict__ Kh, const unsigned short* __restrict__ Kl,
    float* __restrict__ Sp, float* __restrict__ mpart, float* __restrict__ lpart){
  int tM = blockIdx.x, z = blockIdx.y;
  int kvh = z >> 3;
  size_t tri = (size_t)tM*(tM+1)/2;
  const int ldq = NH*HD, ldk = NKV*HD;
  const unsigned short* Qbh = Qh + (size_t)(tM*128)*ldq + (size_t)z*HD;
  const unsigned short* Qbl = Ql + (size_t)(tM*128)*ldq + (size_t)z*HD;
  const unsigned short* Kbh = Kh + (size_t)kvh*HD;
  const unsigned short* Kbl = Kl + (size_t)kvh*HD;

  __shared__ __align__(16) unsigned short QsH[16384], QsL[16384];
  __shared__ __align__(16) unsigned short BsH[2][4096], BsL[2][4096];

  int tid = threadIdx.x, lane = tid & 63, wid = tid >> 6;
  int wr = wid >> 1, wc = wid & 1;
  int i15 = lane & 15, g = lane >> 4;

  #pragma unroll
  for (int j=0;j<8;j++){
    int gi = j*256 + tid;
    int chunk = gi >> 9;
    int row = (gi >> 2) & 127;
    int gg = gi & 3;
    int col = chunk*32 + (gg ^ ((row>>1)&3))*8;
    gload16(Qbh + (size_t)row*ldq + col, QsH + (size_t)gi*8);
    gload16(Qbl + (size_t)row*ldq + col, QsL + (size_t)gi*8);
  }

  auto BSTAGE = [&](int b, int ci){
    int tn = ci >> 2, c = ci & 3;
    const unsigned short* sh = Kbh + (size_t)(tn*128)*ldk;
    const unsigned short* sl = Kbl + (size_t)(tn*128)*ldk;
    #pragma unroll
    for (int j=0;j<2;j++){
      int gi = j*256 + tid;
      int row = gi >> 2, gg = gi & 3;
      int col = c*32 + (gg ^ ((row>>1)&3))*8;
      gload16(sh + (size_t)row*ldk + col, BsH[b] + (size_t)gi*8);
      gload16(sl + (size_t)row*ldk + col, BsL[b] + (size_t)gi*8);
    }
  };

  f32x4 acc[4][4];
  #pragma unroll
  for (int m=0;m<4;m++)
    #pragma unroll
    for (int n=0;n<4;n++) acc[m][n] = (f32x4){0.f,0.f,0.f,0.f};

  int NC = (tM+1)*4;
  BSTAGE(0, 0);
  BSTAGE(1, 1);
  for (int ci=0; ci<NC; ++ci){
    int cur = ci & 1, c = ci & 3, tn = ci >> 2;
    if (ci < NC-1) { VW(4); } else { VW(0); }
    BAR();
    short8 afh[4], afl[4], bfh[4], bfl[4];
    #pragma unroll
    for (int m=0;m<4;m++){
      int row = wr*64 + m*16 + i15;
      int ro = c*4096 + row*32 + (g ^ ((row>>1)&3))*8;
      afh[m] = *(const short8*)(QsH + ro);
      afl[m] = *(const short8*)(QsL + ro);
    }
    #pragma unroll
    for (int n=0;n<4;n++){
      int row = wc*64 + n*16 + i15;
      int ro = row*32 + (g ^ ((row>>1)&3))*8;
      bfh[n] = *(const short8*)(BsH[cur] + ro);
      bfl[n] = *(const short8*)(BsL[cur] + ro);
    }
    LW0();
    BAR();
    if (ci + 2 < NC) BSTAGE(cur, ci+2);
    __builtin_amdgcn_s_setprio(1);
    #pragma unroll
    for (int m=0;m<4;m++)
      #pragma unroll
      for (int n=0;n<4;n++){
        acc[m][n] = __builtin_amdgcn_mfma_f32_16x16x32_bf16(afh[m], bfh[n], acc[m][n], 0,0,0);
        acc[m][n] = __builtin_amdgcn_mfma_f32_16x16x32_bf16(afh[m], bfl[n], acc[m][n], 0,0,0);
        acc[m][n] = __builtin_amdgcn_mfma_f32_16x16x32_bf16(afl[m], bfh[n], acc[m][n], 0,0,0);
      }
    __builtin_amdgcn_s_setprio(0);
    if (c == 3){
      float* Cb = Sp + ((size_t)z*NBLK + tri + tn)*16384;
      #pragma unroll
      for (int m=0;m<4;m++){
        int r0 = wr*64 + m*16 + (g<<2);
        #pragma unroll
        for (int n=0;n<4;n++){
          int ccol = wc*64 + n*16 + i15;
          #pragma unroll
          for (int r=0;r<4;r++) Cb[(size_t)(r0+r)*128 + ccol] = acc[m][n][r];
        }
      }
      // per-wave softmax partials over this wave's 64 cols (causal-masked on diagonal)
      int diag = (tn == tM);
      #pragma unroll
      for (int m=0;m<4;m++){
        #pragma unroll
        for (int r=0;r<4;r++){
          int rl = wr*64 + m*16 + (g<<2) + r;
          float vmax = -3.0e38f;
          #pragma unroll
          for (int n=0;n<4;n++){
            int cl = wc*64 + n*16 + i15;
            float v = acc[m][n][r]*SM_SCALE;
            if (diag && cl > rl) v = -3.0e38f;
            vmax = fmaxf(vmax, v);
          }
          #pragma unroll
          for (int o=1;o<16;o<<=1) vmax = fmaxf(vmax, __shfl_xor(vmax, o));
          float s = 0.f;
          #pragma unroll
          for (int n=0;n<4;n++){
            int cl = wc*64 + n*16 + i15;
            float v = acc[m][n][r]*SM_SCALE;
            float e = (diag && cl > rl) ? 0.f : __expf(v - vmax);
            s += e;
          }
          #pragma unroll
          for (int o=1;o<16;o<<=1) s += __shfl_xor(s, o);
          if ((lane&15)==0){
            int rg = tM*128 + rl;
            size_t o = (((size_t)z*T_ + rg)*16 + tn)*2 + wc;
            mpart[o] = vmax;
            lpart[o] = s;
          }
        }
      }
      #pragma unroll
      for (int m=0;m<4;m++)
        #pragma unroll
        for (int n=0;n<4;n++) acc[m][n] = (f32x4){0.f,0.f,0.f,0.f};
    }
  }
}

// combine per-block partials -> m'' = max + ln(sum)
__global__ void k_mlcombine(const float* __restrict__ mpart, const float* __restrict__ lpart,
                            float* __restrict__ mlb){
  int idx = blockIdx.x*256 + threadIdx.x;   // h*T_ + t
  if (idx >= NH*T_) return;
  int t = idx & (T_-1);
  int nb = ((t>>7)+1)*2;
  const float* mp = mpart + (size_t)idx*32;
  const float* lp = lpart + (size_t)idx*32;
  float m = -3.0e38f;
  for (int i=0;i<nb;i++) m = fmaxf(m, mp[i]);
  float l = 0.f;
  for (int i=0;i<nb;i++) l += lp[i]*__expf(mp[i]-m);
  mlb[idx] = m + logf(l);
}

// ---------------- PV split-K, softmax fused in fragment read (diag-masked) ----------------
__global__ __launch_bounds__(256) void k_pv_hp(
    const float* __restrict__ Sp, const float* __restrict__ mlb,
    const unsigned short* __restrict__ Vh, const unsigned short* __restrict__ Vl,
    float* __restrict__ part){
  int c = blockIdx.x, tM = blockIdx.y, z = blockIdx.z;
  int kbeg = c*512;
  int kend = min((tM+1)*128, (c+1)*512);
  if (kbeg >= kend) return;
  int tMk = tM*128;
  size_t tri = (size_t)tM*(tM+1)/2;
  const float* Ab = Sp + ((size_t)z*NBLK + tri)*16384;
  const unsigned short* Bbh = Vh + (size_t)(z>>3)*HD*T_;
  const unsigned short* Bbl = Vl + (size_t)(z>>3)*HD*T_;

  __shared__ __align__(16) float Asf[2][4096];
  __shared__ __align__(16) unsigned short BsH[2][4096], BsL[2][4096];
  int tid = threadIdx.x, lane = tid & 63, wid = tid >> 6;
  int wr = wid >> 1, wc = wid & 1;
  int i15 = lane & 15, g2 = (lane>>4)*2;

  float mrow[4];
  #pragma unroll
  for (int m=0;m<4;m++)
    mrow[m] = mlb[(size_t)z*T_ + tMk + wr*64 + m*16 + i15];

  int r0s = tid>>2, r1s = r0s + 64;
  int kcB = ((tid&3) ^ ((r0s>>1)&3))*8;
  int rowA = tid>>3, gA = tid&7;

  f32x4 acc[4][4];
  #pragma unroll
  for (int m=0;m<4;m++)
    #pragma unroll
    for (int n=0;n<4;n++) acc[m][n] = (f32x4){0.f,0.f,0.f,0.f};

  auto STAGE = [&](int b, int k0){
    #pragma unroll
    for (int j=0;j<4;j++){
      int r = j*32 + rowA;
      int gS = gA ^ (r & 7);
      size_t ga = (size_t)(k0>>7)*16384 + (size_t)r*128 + (k0&127) + gS*4;
      gload16(Ab + ga, Asf[b] + ((size_t)j*256 + tid)*4);
    }
    size_t bo0 = (size_t)r0s*T_ + k0 + kcB;
    size_t bo1 = (size_t)r1s*T_ + k0 + kcB;
    gload16(Bbh + bo0, BsH[b] + (size_t)tid*8);
    gload16(Bbh + bo1, BsH[b] + (size_t)(256+tid)*8);
    gload16(Bbl + bo0, BsL[b] + (size_t)tid*8);
    gload16(Bbl + bo1, BsL[b] + (size_t)(256+tid)*8);
  };

  int nt = (kend - kbeg) >> 5, L = nt - 1;
  STAGE(0, kbeg);
  if (L >= 1) STAGE(1, kbeg + 32);
  for (int i=0; i<nt; ++i){
    int cur = i & 1;
    int k0 = kbeg + i*32;
    if (i < L) { VW(8); } else { VW(0); }
    BAR();
    int diag = (k0 >= tMk);
    short8 afh[4], afl[4], bfh[4], bfl[4];
    #pragma unroll
    for (int m=0;m<4;m++){
      int r = wr*64 + m*16 + i15;
      int s0 = r*8 + ((g2  ) ^ (r&7));
      int s1 = r*8 + ((g2+1) ^ (r&7));
      f32x4 a0 = *(const f32x4*)(Asf[cur] + s0*4);
      f32x4 a1 = *(const f32x4*)(Asf[cur] + s1*4);
      float pv[8] = {a0[0],a0[1],a0[2],a0[3],a1[0],a1[1],a1[2],a1[3]};
      if (diag){
        int kb = k0 & 127;
        #pragma unroll
        for (int j=0;j<8;j++){
          int kl = kb + ((j<4) ? g2*4 + j : (g2+1)*4 + (j-4));
          if (kl > r) pv[j] = -3.0e38f;
        }
      }
      short8 h8, l8;
      #pragma unroll
      for (int j=0;j<8;j++){
        float p = __expf(pv[j]*SM_SCALE - mrow[m]);
        unsigned short hh, ll; split2(p, hh, ll);
        h8[j] = (short)hh; l8[j] = (short)ll;
      }
      afh[m] = h8; afl[m] = l8;
    }
    #pragma unroll
    for (int n=0;n<4;n++){
      int row = wc*64 + n*16 + i15;
      int ro = row*32 + ((lane>>4) ^ ((row>>1)&3))*8;
      bfh[n] = *(const short8*)(BsH[cur] + ro);
      bfl[n] = *(const short8*)(BsL[cur] + ro);
    }
    LW0();
    BAR();
    if (i + 2 <= L) STAGE(cur, kbeg + (i+2)*32);
    __builtin_amdgcn_s_setprio(1);
    #pragma unroll
    for (int m=0;m<4;m++)
      #pragma unroll
      for (int n=0;n<4;n++){
        acc[m][n] = __builtin_amdgcn_mfma_f32_16x16x32_bf16(afh[m], bfh[n], acc[m][n], 0,0,0);
        acc[m][n] = __builtin_amdgcn_mfma_f32_16x16x32_bf16(afh[m], bfl[n], acc[m][n], 0,0,0);
        acc[m][n] = __builtin_amdgcn_mfma_f32_16x16x32_bf16(afl[m], bfh[n], acc[m][n], 0,0,0);
      }
    __builtin_amdgcn_s_setprio(0);
  }

  float* Cb = part + (size_t)c*T_*DM + (size_t)tMk*DM + (size_t)z*HD;
  #pragma unroll
  for (int m=0;m<4;m++){
    int r0 = wr*64 + m*16 + ((lane>>4)<<2);
    #pragma unroll
    for (int n=0;n<4;n++){
      int ccol = wc*64 + n*16 + (lane&15);
      #pragma unroll
      for (int r=0;r<4;r++) Cb[(size_t)(r0+r)*DM + ccol] = acc[m][n][r];
    }
  }
}

// reduce partials -> aoh/aol (bf16 hi/lo)
__global__ void k_pv_reduce(const float* __restrict__ part,
                            unsigned short* __restrict__ aoh, unsigned short* __restrict__ aol){
  int t = blockIdx.x, tid = threadIdx.x;
  int nc = ((t>>7) + 4) >> 2;
  #pragma unroll
  for (int half=0; half<2; ++half){
    int idx = tid + half*256;
    float4 s = ((const float4*)(part + (size_t)t*DM))[idx];
    for (int c=1; c<nc; ++c){
      float4 v = ((const float4*)(part + (size_t)c*T_*DM + (size_t)t*DM))[idx];
      s.x+=v.x; s.y+=v.y; s.z+=v.z; s.w+=v.w;
    }
    ushort4 h_, l_;
    split2(s.x,h_.x,l_.x); split2(s.y,h_.y,l_.y); split2(s.z,h_.z,l_.z); split2(s.w,h_.w,l_.w);
    ((ushort4*)(aoh + (size_t)t*DM))[idx] = h_;
    ((ushort4*)(aol + (size_t)t*DM))[idx] = l_;
  }
}

// ---------------- qkv post ----------------
__global__ void k_qkv_post_hp(const float* __restrict__ qkv, const float* __restrict__ bias,
                              const float* __restrict__ qnw, const float* __restrict__ knw,
                              const int* __restrict__ pos_,
                              unsigned short* __restrict__ qhi, unsigned short* __restrict__ qlo,
                              unsigned short* __restrict__ khi, unsigned short* __restrict__ klo,
                              unsigned short* __restrict__ vThi, unsigned short* __restrict__ vTlo){
  int t = blockIdx.x;
  int half = threadIdx.x >> 7;
  int d = threadIdx.x & 127;
  int wseg = (threadIdx.x >> 6) & 1;
  float posf = (float)pos_[t];
  __shared__ float buf[2][128];
  __shared__ float ssum[2][2];
  __shared__ float inv_sh[32];
  if (threadIdx.x < 32)
    inv_sh[threadIdx.x] = (float)pow(1000000.0, -(double)threadIdx.x/32.0);
  __syncthreads();
  for (int it=0; it<10; ++it){
    int seg = it*2 + half;
    float x = qkv[(size_t)t*QKVN + seg*128 + d] + bias[seg*128 + d];
    float p = x*x;
    #pragma unroll
    for (int o=32;o;o>>=1) p += __shfl_xor(p,o);
    if ((threadIdx.x&63)==0) ssum[half][wseg] = p;
    __syncthreads();
    float rs = rsqrtf((ssum[half][0]+ssum[half][1])*(1.f/128.f) + 1e-5f);
    float w = (seg<16) ? qnw[d] : ((seg<18) ? knw[d] : 1.f);
    float nv = x*rs*w;
    buf[half][d] = nv;
    __syncthreads();
    float outv = (seg<18) ? nv : x;
    if (seg < 18 && d < 64){
      int i = d & 31;
      float ang = posf * inv_sh[i];
      float sn, cs; sincosf(ang, &sn, &cs);
      if (d < 32) outv = nv*cs - buf[half][d+32]*sn;
      else        outv = nv*cs + buf[half][d-32]*sn;
    }
    unsigned short h_, l_; split2(outv, h_, l_);
    if (seg < 16){ size_t o = ((size_t)t*NH + seg)*HD + d; qhi[o]=h_; qlo[o]=l_; }
    else if (seg < 18){ size_t o = ((size_t)t*NKV + (seg-16))*HD + d; khi[o]=h_; klo[o]=l_; }
    else { size_t o = ((size_t)(seg-18)*HD + d)*T_ + t; vThi[o]=h_; vTlo[o]=l_; }
    __syncthreads();
  }
}

// ---- offsets: histogram idx4 in LDS (no global atomics), init padded fill, zero tok ----
__global__ void k_offsets(const int* __restrict__ idx4, int* __restrict__ offs,
                          int* __restrict__ fill, int* __restrict__ tok){
  __shared__ int hist[16];
  if (threadIdx.x < 16) hist[threadIdx.x] = 0;
  __syncthreads();
  for (int i = threadIdx.x; i < ROWS_ALL; i += 256) tok[i] = 0;
  for (int i = threadIdx.x; i < T_*4; i += 256)
    atomicAdd(&hist[idx4[i]], 1);
  __syncthreads();
  fill[threadIdx.x] = 0;                        // padded fill: 256 ints, counter at e*16
  if (threadIdx.x == 0){
    int o = 0;
    for (int e=0;e<16;e++){ offs[e]=o; o += ((hist[e]+127)>>7)<<7; }
    offs[16]=o;
    offs[17]=o + T_;
  }
}

__global__ void k_place(const int* __restrict__ idx4, const int* __restrict__ offs,
                        int* __restrict__ fill, int* __restrict__ rrow, int* __restrict__ tok){
  int t = blockIdx.x*256 + threadIdx.x;
  if (t>=T_) return;
  for (int s=0;s<4;s++){
    int e = idx4[t*4+s];
    int p = atomicAdd(&fill[e*16],1);           // one counter per 64B line
    int r = offs[e]+p;
    rrow[t*4+s]=r;
    tok[r]=t;
  }
  tok[offs[16]+t] = t;
}

__global__ void k_combine(const unsigned short* __restrict__ eout,
                          const int* __restrict__ rrow, const float* __restrict__ w4,
                          const int* __restrict__ offs, float* __restrict__ outh){
  int t = blockIdx.x;
  int rs = offs[16] + t;
  int r0=rrow[t*4+0], r1=rrow[t*4+1], r2=rrow[t*4+2], r3=rrow[t*4+3];
  float w0=w4[t*4+0], w1=w4[t*4+1], w2=w4[t*4+2], w3=w4[t*4+3];
  for (int d=threadIdx.x; d<DM; d+=256){
    float v = bf2f(eout[(size_t)rs*DM+d])
            + w0*bf2f(eout[(size_t)r0*DM+d]) + w1*bf2f(eout[(size_t)r1*DM+d])
            + w2*bf2f(eout[(size_t)r2*DM+d]) + w3*bf2f(eout[(size_t)r3*DM+d]);
    outh[(size_t)t*DM+d] = v;
  }
}

// =========================================================================
extern "C" void kernel_launch(void* const* d_in, const int* in_sizes, int n_in,
                              void* d_out, int out_size, void* d_ws, size_t ws_size,
                              hipStream_t stream){
  const int*   positions = (const int*)d_in[0];
  const float* hidden    = (const float*)d_in[1];
  const float* residual  = (const float*)d_in[2];
  const float* ln1       = (const float*)d_in[3];
  const float* ln2       = (const float*)d_in[4];
  const float* w_qkv     = (const float*)d_in[5];
  const float* b_qkv     = (const float*)d_in[6];
  const float* w_o       = (const float*)d_in[7];
  const float* qnw       = (const float*)d_in[8];
  const float* knw       = (const float*)d_in[9];
  const float* gate_w    = (const float*)d_in[10];
  const float* gate_b    = (const float*)d_in[11];
  const float* sh_wgu    = (const float*)d_in[12];
  const float* sh_wd     = (const float*)d_in[13];
  const float* e_wgu     = (const float*)d_in[14];
  const float* e_wd      = (const float*)d_in[15];
  float* out_h   = (float*)d_out;
  float* out_res = (float*)d_out + (size_t)T_*DM;

  char* ws = (char*)d_ws;
  size_t off = 0;
  auto alloc = [&](size_t b){ size_t r = off; off += (b + 255) & ~(size_t)255; return r; };

  // ---- persistent ----
  size_t o_h2b  = alloc((size_t)T_*DM*2);
  size_t o_idx  = alloc((size_t)T_*4*4);
  size_t o_w4   = alloc((size_t)T_*4*4);
  size_t o_offs = alloc(72);
  size_t o_fill = alloc(1024);
  size_t o_rrow = alloc((size_t)T_*4*4);
  size_t o_tok  = alloc((size_t)ROWS_ALL*4);

  // ---- phase-union arena ----
  size_t U0 = off;
  size_t a = U0;
  auto allocA = [&](size_t b){ size_t r = a; a += (b + 255) & ~(size_t)255; return r; };
  size_t o_h1h  = allocA((size_t)T_*DM*2);
  size_t o_h1l  = allocA((size_t)T_*DM*2);
  size_t o_wqh  = allocA((size_t)QKVN*DM*2);
  size_t o_wql  = allocA((size_t)QKVN*DM*2);
  size_t o_qkvf = allocA((size_t)T_*QKVN*4);
  size_t o_qh   = allocA((size_t)T_*NH*HD*2);
  size_t o_ql   = allocA((size_t)T_*NH*HD*2);
  size_t o_kh   = allocA((size_t)T_*NKV*HD*2);
  size_t o_kl   = allocA((size_t)T_*NKV*HD*2);
  size_t o_vth  = allocA((size_t)NKV*HD*T_*2);
  size_t o_vtl  = allocA((size_t)NKV*HD*T_*2);
  size_t o_woh  = allocA((size_t)DM*DM*2);
  size_t o_wol  = allocA((size_t)DM*DM*2);
  size_t o_aoh  = allocA((size_t)T_*DM*2);
  size_t o_aol  = allocA((size_t)T_*DM*2);
  size_t o_attnP= allocA((size_t)T_*DM*4);
  size_t o_mlb  = allocA((size_t)NH*T_*4);
  size_t o_mpart= allocA((size_t)NH*T_*32*4);
  size_t o_lpart= allocA((size_t)NH*T_*32*4);
  size_t o_Sp   = allocA((size_t)NH*NBLK*16384*4);
  size_t o_pvp  = allocA((size_t)4*T_*DM*4);
  // phase B (MoE)
  size_t b_ = U0;
  auto allocB = [&](size_t b){ size_t r = b_; b_ += (b + 255) & ~(size_t)255; return r; };
  size_t o_ewgu = allocB((size_t)NE*2*IM*DM*2);
  size_t o_ewd  = allocB((size_t)NE*DM*IM*2);
  size_t o_shgu = allocB((size_t)2*ISH*DM*2);
  size_t o_shwd = allocB((size_t)DM*ISH*2);
  size_t o_actx = allocB((size_t)ROWS_ALL*IM*2);
  size_t o_eout = allocB((size_t)ROWS_ALL*DM*2);

  unsigned short* h2b   = (unsigned short*)(ws+o_h2b);
  int*   idx4  = (int*)(ws+o_idx);
  float* w4p   = (float*)(ws+o_w4);
  int*   offs  = (int*)(ws+o_offs);
  int*   fill  = (int*)(ws+o_fill);
  int*   rrow  = (int*)(ws+o_rrow);
  int*   tok   = (int*)(ws+o_tok);
  unsigned short* h1h = (unsigned short*)(ws+o_h1h);
  unsigned short* h1l = (unsigned short*)(ws+o_h1l);
  unsigned short* wqh = (unsigned short*)(ws+o_wqh);
  unsigned short* wql = (unsigned short*)(ws+o_wql);
  float*          qkvf= (float*)(ws+o_qkvf);
  unsigned short* qh  = (unsigned short*)(ws+o_qh);
  unsigned short* ql  = (unsigned short*)(ws+o_ql);
  unsigned short* kh  = (unsigned short*)(ws+o_kh);
  unsigned short* kl  = (unsigned short*)(ws+o_kl);
  unsigned short* vth = (unsigned short*)(ws+o_vth);
  unsigned short* vtl = (unsigned short*)(ws+o_vtl);
  unsigned short* woh = (unsigned short*)(ws+o_woh);
  unsigned short* wol = (unsigned short*)(ws+o_wol);
  unsigned short* aoh = (unsigned short*)(ws+o_aoh);
  unsigned short* aol = (unsigned short*)(ws+o_aol);
  float*          attnP=(float*)(ws+o_attnP);
  float*          mlb = (float*)(ws+o_mlb);
  float*          mpart=(float*)(ws+o_mpart);
  float*          lpart=(float*)(ws+o_lpart);
  float*          Sp  = (float*)(ws+o_Sp);
  float*          pvpart = (float*)(ws+o_pvp);
  unsigned short* ewguT=(unsigned short*)(ws+o_ewgu);
  unsigned short* ewdT = (unsigned short*)(ws+o_ewd);
  unsigned short* shguT=(unsigned short*)(ws+o_shgu);
  unsigned short* shwdT=(unsigned short*)(ws+o_shwd);
  unsigned short* actx= (unsigned short*)(ws+o_actx);
  unsigned short* eout= (unsigned short*)(ws+o_eout);

  // ---- attention phase (high precision) ----
  k_tconv2<<<dim3(QKVN/64, DM/64, 1),256,0,stream>>>(w_qkv, wqh, wql, DM, QKVN);
  k_tconv2<<<dim3(DM/64, DM/64, 1),256,0,stream>>>(w_o, woh, wol, DM, DM);

  k_add_rmsnorm<false><<<T_,256,0,stream>>>(hidden, residual, ln1, out_res, h1h, h1l, nullptr,
                                            nullptr, nullptr, nullptr, nullptr);

  k_gemm_hp<<<dim3(QKVN/128,T_/128,1),256,0,stream>>>(
      h1h, h1l, wqh, wql, qkvf, DM, DM, DM, QKVN);
  k_qkv_post_hp<<<T_,256,0,stream>>>(qkvf, b_qkv, qnw, knw, positions, qh, ql, kh, kl, vth, vtl);

  k_qk_pers<<<dim3(T_/128,NH),256,0,stream>>>(qh, ql, kh, kl, Sp, mpart, lpart);
  k_mlcombine<<<(NH*T_+255)/256,256,0,stream>>>(mpart, lpart, mlb);
  k_pv_hp<<<dim3(4,T_/128,NH),256,0,stream>>>(Sp, mlb, vth, vtl, pvpart);
  k_pv_reduce<<<T_,256,0,stream>>>(pvpart, aoh, aol);
  k_gemm_hp<<<dim3(DM/128,T_/128,1),256,0,stream>>>(
      aoh, aol, woh, wol, attnP, DM, DM, DM, DM);

  // rmsnorm2 with fused MoE routing (no global atomics)
  k_add_rmsnorm<true><<<T_,256,0,stream>>>(attnP, out_res, ln2, out_res, nullptr, nullptr, h2b,
                                           gate_w, gate_b, idx4, w4p);

  k_offsets<<<1,256,0,stream>>>(idx4, offs, fill, tok);
  k_place<<<T_/256,256,0,stream>>>(idx4, offs, fill, rrow, tok);

  // ---- weight conversion (phase A arena dead now); shared weights merged as z==16 ----
  k_tconv<true ><<<dim3(2*IM/64, DM/64, NE+1),256,0,stream>>>(
      e_wgu, ewguT, sh_wgu, shguT, DM, 2*IM, (size_t)DM*2*IM, (size_t)2*IM*DM);
  k_tconv<false><<<dim3(DM/64, IM/64, NE+1),256,0,stream>>>(
      e_wd,  ewdT,  sh_wd,  shwdT, IM, DM,   (size_t)IM*DM,   (size_t)DM*IM);

  // ---- unified grouped MLP (experts + shared); silu fused into up-GEMM epilogue ----
  k_gemm2<true, true ><<<dim3(2*IM/128, ROWS_ALL/128, 1),256,0,stream>>>(
      h2b, ewguT, shguT, actx, DM, DM, DM, IM, offs, (size_t)2*IM*DM, tok);
  k_gemm2<false, false><<<dim3(DM/128, ROWS_ALL/128, 1),256,0,stream>>>(
      actx, ewdT, shwdT, eout, IM, IM, IM, DM, offs, (size_t)DM*IM, nullptr);

  // ---- combine ----
  k_combine<<<T_,256,0,stream>>>(eout, rrow, w4p, offs, out_h);
}

// Round 17
// 752.123 us; speedup vs baseline: 1.1066x; 1.1066x over previous
//
#include <hip/hip_runtime.h>
#include <stdint.h>
#include <math.h>

#define T_ 2048
#define DM 2048
#define NH 16
#define NKV 2
#define HD 128
#define QKVN 2560
#define NE 16
#define IM 768
#define ISH 768
#define MAXROWS 10240
#define ROWS_ALL 12288   // MAXROWS + T_ (shared region appended)
#define NBLK 136         // 16*17/2 causal 128x128 blocks per head
#define SM_SCALE 0.08838834764831845f

typedef __attribute__((ext_vector_type(8))) short short8;
typedef __attribute__((ext_vector_type(4))) float f32x4;

__device__ __forceinline__ float bf2f(unsigned short u){ return __uint_as_float(((unsigned int)u)<<16); }
__device__ __forceinline__ unsigned short f2bf(float f){
  unsigned int u = __float_as_uint(f);
  return (unsigned short)((u + 0x7FFFu + ((u>>16)&1u)) >> 16);
}
__device__ __forceinline__ void split2(float x, unsigned short& hi, unsigned short& lo){
  hi = f2bf(x);
  lo = f2bf(x - bf2f(hi));
}

__device__ __forceinline__ void gload16(const void* g, void* l){
  __builtin_amdgcn_global_load_lds((const __attribute__((address_space(1))) unsigned int*)g,
                                   (__attribute__((address_space(3))) unsigned int*)l, 16, 0, 0);
}

// bijective XCD swizzle (m204)
__device__ __forceinline__ int xcd_swz(int bid, int nwg){
  int q = nwg >> 3, r = nwg & 7, x = bid & 7, p = bid >> 3;
  return (x < r ? x*(q+1) : r*(q+1) + (x-r)*q) + p;
}

#define BAR()    asm volatile("s_barrier" ::: "memory")
#define VW(N)    asm volatile("s_waitcnt vmcnt(" #N ")" ::: "memory")
#define LW0()    do{ asm volatile("s_waitcnt lgkmcnt(0)" ::: "memory"); __builtin_amdgcn_sched_barrier(0); }while(0)

// ------- transpose conv f32 -> bf16, vectorized (64x64 tile, float4 in, short8 out) ----
// ILV: g/u 8-col interleave. Last z (== gridDim.z-1) optionally reads/writes shared-weight ptrs.
template<bool ILV>
__global__ void k_tconv(const float* __restrict__ src, unsigned short* __restrict__ dst,
                        const float* __restrict__ srcS, unsigned short* __restrict__ dstS,
                        int R, int C, size_t sS, size_t sD){
  int z = blockIdx.z;
  if (srcS && z == gridDim.z-1){ src = srcS; dst = dstS; }
  else { src += (size_t)z * sS; dst += (size_t)z * sD; }
  __shared__ float tile[64*65];
  int tid = threadIdx.x;
  int r0 = blockIdx.y*64, c0 = blockIdx.x*64;
  int lr = tid>>4, lc = (tid&15)*4;
  #pragma unroll
  for (int j=0;j<4;j++){
    int row = j*16 + lr;
    float4 v = *(const float4*)&src[(size_t)(r0+row)*C + c0 + lc];
    float* t = &tile[row*65 + lc];
    t[0]=v.x; t[1]=v.y; t[2]=v.z; t[3]=v.w;
  }
  __syncthreads();
  #pragma unroll
  for (int jj=0;jj<2;jj++){
    int slot = jj*256 + tid;
    int c = slot>>3, ro = (slot&7)*8;
    int cg = c0 + c;
    int cd = cg;
    if (ILV){ int b = cg>>3, inner = cg&7; cd = (b<96 ? b*16 : (b-96)*16+8) + inner; }
    short8 o;
    #pragma unroll
    for (int k=0;k<8;k++) o[k] = (short)f2bf(tile[(ro+k)*65 + c]);
    *(short8*)&dst[(size_t)cd*R + r0 + ro] = o;
  }
}

// ------- transpose conv f32 -> bf16 hi + lo planes, vectorized -------
__global__ void k_tconv2(const float* __restrict__ src, unsigned short* __restrict__ dhi,
                         unsigned short* __restrict__ dlo, int R, int C){
  __shared__ float tile[64*65];
  int tid = threadIdx.x;
  int r0 = blockIdx.y*64, c0 = blockIdx.x*64;
  int lr = tid>>4, lc = (tid&15)*4;
  #pragma unroll
  for (int j=0;j<4;j++){
    int row = j*16 + lr;
    float4 v = *(const float4*)&src[(size_t)(r0+row)*C + c0 + lc];
    float* t = &tile[row*65 + lc];
    t[0]=v.x; t[1]=v.y; t[2]=v.z; t[3]=v.w;
  }
  __syncthreads();
  #pragma unroll
  for (int jj=0;jj<2;jj++){
    int slot = jj*256 + tid;
    int c = slot>>3, ro = (slot&7)*8;
    short8 oh, ol;
    #pragma unroll
    for (int k=0;k<8;k++){
      unsigned short h_, l_;
      split2(tile[(ro+k)*65 + c], h_, l_);
      oh[k] = (short)h_; ol[k] = (short)l_;
    }
    size_t o = (size_t)(c0+c)*R + r0 + ro;
    *(short8*)&dhi[o] = oh;
    *(short8*)&dlo[o] = ol;
  }
}

// ---------------- add + rmsnorm; ROUTE: fused MoE gate (no global atomics) ----------------
template<bool ROUTE>
__global__ void k_add_rmsnorm(const float* __restrict__ a, const float* __restrict__ b,
                              const float* __restrict__ w, float* __restrict__ resout,
                              unsigned short* __restrict__ ohi, unsigned short* __restrict__ olo,
                              unsigned short* __restrict__ obf,
                              const float* __restrict__ gw, const float* __restrict__ gbias,
                              int* __restrict__ idx4, float* __restrict__ w4){
  int t = blockIdx.x, tid = threadIdx.x;
  const float4* a4 = (const float4*)(a + (size_t)t*DM);
  const float4* b4 = (const float4*)(b + (size_t)t*DM);
  float4 va = a4[tid], vb = b4[tid];
  float4 wa = a4[tid+256], wb = b4[tid+256];
  float4 v0, v1;
  v0.x=va.x+vb.x; v0.y=va.y+vb.y; v0.z=va.z+vb.z; v0.w=va.w+vb.w;
  v1.x=wa.x+wb.x; v1.y=wa.y+wb.y; v1.z=wa.z+wb.z; v1.w=wa.w+wb.w;
  float s = v0.x*v0.x+v0.y*v0.y+v0.z*v0.z+v0.w*v0.w
          + v1.x*v1.x+v1.y*v1.y+v1.z*v1.z+v1.w*v1.w;
  #pragma unroll
  for (int o=32;o;o>>=1) s += __shfl_xor(s,o);
  __shared__ float sm[4];
  if ((tid&63)==0) sm[tid>>6]=s;
  __syncthreads();
  s = sm[0]+sm[1]+sm[2]+sm[3];
  float rs = rsqrtf(s*(1.f/(float)DM) + 1e-5f);
  ((float4*)(resout + (size_t)t*DM))[tid] = v0;
  ((float4*)(resout + (size_t)t*DM))[tid+256] = v1;
  const float4* w4p_ = (const float4*)w;
  float4 w0 = w4p_[tid], w1 = w4p_[tid+256];
  float n[8] = { v0.x*rs*w0.x, v0.y*rs*w0.y, v0.z*rs*w0.z, v0.w*rs*w0.w,
                 v1.x*rs*w1.x, v1.y*rs*w1.y, v1.z*rs*w1.z, v1.w*rs*w1.w };
  if (ohi){
    ushort4 h0,h1,l0,l1;
    split2(n[0],h0.x,l0.x); split2(n[1],h0.y,l0.y); split2(n[2],h0.z,l0.z); split2(n[3],h0.w,l0.w);
    split2(n[4],h1.x,l1.x); split2(n[5],h1.y,l1.y); split2(n[6],h1.z,l1.z); split2(n[7],h1.w,l1.w);
    ((ushort4*)(ohi + (size_t)t*DM))[tid] = h0;
    ((ushort4*)(ohi + (size_t)t*DM))[tid+256] = h1;
    ((ushort4*)(olo + (size_t)t*DM))[tid] = l0;
    ((ushort4*)(olo + (size_t)t*DM))[tid+256] = l1;
  }
  if (obf){
    ushort4 o0 = make_ushort4(f2bf(n[0]),f2bf(n[1]),f2bf(n[2]),f2bf(n[3]));
    ushort4 o1 = make_ushort4(f2bf(n[4]),f2bf(n[5]),f2bf(n[6]),f2bf(n[7]));
    ((ushort4*)(obf + (size_t)t*DM))[tid] = o0;
    ((ushort4*)(obf + (size_t)t*DM))[tid+256] = o1;
  }
  if constexpr (ROUTE){
    __shared__ float xrow[DM];          // 8 KB
    __shared__ float red[16][17];
    #pragma unroll
    for (int jj=0;jj<4;jj++) xrow[4*tid+jj] = n[jj];
    #pragma unroll
    for (int jj=0;jj<4;jj++) xrow[1024+4*tid+jj] = n[4+jj];
    __syncthreads();
    // coalesced gate GEMV: lane (grp=tid>>4, e=tid&15); gw row-major [DM][16]
    int e = tid & 15, grp = tid >> 4;
    float part = 0.f;
    #pragma unroll 8
    for (int c = grp; c < DM; c += 16)
      part += xrow[c] * gw[(size_t)c*16 + e];
    red[grp][e] = part;
    __syncthreads();
    if (tid==0){
      float sc[16], sb[16];
      for (int ee=0;ee<16;ee++){
        float lg = 0.f;
        for (int g2=0;g2<16;g2++) lg += red[g2][ee];
        sc[ee] = 1.f/(1.f+expf(-lg));
        sb[ee] = sc[ee] + gbias[ee];
      }
      float gs[4];
      for (int g=0;g<4;g++){
        float m1=-3.4e38f, m2=-3.4e38f;
        for (int j=0;j<4;j++){
          float v = sb[g*4+j];
          if (v>m1){ m2=m1; m1=v; } else if (v>m2) m2=v;
        }
        gs[g]=m1+m2;
      }
      int g1=0; for (int g=1;g<4;g++) if (gs[g]>gs[g1]) g1=g;
      int g2=-1; for (int g=0;g<4;g++){ if (g==g1) continue; if (g2<0 || gs[g]>gs[g2]) g2=g; }
      float msk[16];
      for (int ee=0;ee<16;ee++){ int g=ee>>2; msk[ee] = (g==g1||g==g2)? sb[ee] : -3.4e38f; }
      int id[4]; float wv[4]; float wsum=0.f;
      for (int s2=0;s2<4;s2++){
        int bb=0; float bv=-3.5e38f;
        for (int ee=0;ee<16;ee++) if (msk[ee]>bv){ bv=msk[ee]; bb=ee; }
        id[s2]=bb; wv[s2]=sc[bb]; wsum+=sc[bb]; msk[bb]=-3.5e38f;
      }
      float invs = 1.f/wsum;
      for (int s2=0;s2<4;s2++){
        idx4[t*4+s2]=id[s2];
        w4[t*4+s2]=wv[s2]*invs;
      }
    }
  }
}

// ------- grouped bf16 GEMM (experts + shared), BK=32 counted-vmcnt 2-deep pipeline -------
// ACT: B cols are (g,u) 8-interleaved; epilogue computes silu(g)*u -> bf16 C [rows][IM]
template<bool GATHER, bool ACT>
__global__ __launch_bounds__(256) void k_gemm2(
    const unsigned short* __restrict__ A, const unsigned short* __restrict__ Be,
    const unsigned short* __restrict__ Bsh, unsigned short* __restrict__ C,
    int K, int lda, int ldb, int ldc,
    const int* __restrict__ offs, size_t sBe, const int* __restrict__ tok){
  int nx = gridDim.x;
  int nwg = nx * gridDim.y;
  int wid_ = xcd_swz(blockIdx.x + nx*blockIdx.y, nwg);
  int tN = wid_ % nx, tM = wid_ / nx;
  int rb = tM*128;
  if (rb >= offs[17]) return;
  const unsigned short* B;
  if (rb >= offs[16]) B = Bsh;
  else {
    int e=0;
    for (; e<15; ++e) if (offs[e+1] > rb) break;
    B = Be + (size_t)e*sBe;
  }
  __shared__ __align__(16) unsigned short As[2][4096];
  __shared__ __align__(16) unsigned short Bs[2][4096];
  int tid = threadIdx.x, lane = tid & 63, wwid = tid >> 6;
  int wr = wwid >> 1, wc = wwid & 1;
  const unsigned short* Bb = B + (size_t)tN*128*ldb;

  const unsigned short* Asrc0;
  const unsigned short* Asrc1;
  int r0s = tid>>2, r1s = r0s + 64;
  {
    if (GATHER){
      Asrc0 = A + (size_t)tok[rb + r0s]*lda;
      Asrc1 = A + (size_t)tok[rb + r1s]*lda;
    } else {
      Asrc0 = A + (size_t)(rb + r0s)*lda;
      Asrc1 = A + (size_t)(rb + r1s)*lda;
    }
  }
  int kc = tid&3;
  int sw = (r0s>>1)&3;
  int kcS = (kc ^ sw)*8;

  f32x4 acc[4][4];
  #pragma unroll
  for (int m=0;m<4;m++)
    #pragma unroll
    for (int n=0;n<4;n++) acc[m][n] = (f32x4){0.f,0.f,0.f,0.f};

  auto STAGE = [&](int b, int k0){
    gload16(Asrc0 + k0 + kcS, As[b] + (size_t)tid*8);
    gload16(Asrc1 + k0 + kcS, As[b] + (size_t)(256+tid)*8);
    gload16(Bb + (size_t)r0s*ldb + k0 + kcS, Bs[b] + (size_t)tid*8);
    gload16(Bb + (size_t)r1s*ldb + k0 + kcS, Bs[b] + (size_t)(256+tid)*8);
  };

  int nt = K >> 5, L = nt - 1;
  STAGE(0, 0);
  if (L >= 1) STAGE(1, 32);
  int i15 = lane & 15, g = lane >> 4;
  for (int i=0; i<nt; ++i){
    int cur = i & 1;
    if (i < L) { VW(4); } else { VW(0); }
    BAR();
    short8 af[4], bfr[4];
    #pragma unroll
    for (int m=0;m<4;m++){
      int row = wr*64 + m*16 + i15;
      int geff = g ^ ((row>>1)&3);
      af[m] = *(const short8*)(As[cur] + row*32 + geff*8);
    }
    #pragma unroll
    for (int n=0;n<4;n++){
      int row = wc*64 + n*16 + i15;
      int geff = g ^ ((row>>1)&3);
      bfr[n] = *(const short8*)(Bs[cur] + row*32 + geff*8);
    }
    LW0();
    BAR();
    if (i + 2 <= L) STAGE(cur, (i+2)*32);
    __builtin_amdgcn_s_setprio(1);
    #pragma unroll
    for (int m=0;m<4;m++)
      #pragma unroll
      for (int n=0;n<4;n++)
        acc[m][n] = __builtin_amdgcn_mfma_f32_16x16x32_bf16(af[m], bfr[n], acc[m][n], 0,0,0);
    __builtin_amdgcn_s_setprio(0);
  }

  if (ACT){
    int rbase = rb + wr*64, cb = tN*128 + wc*64;
    #pragma unroll
    for (int m=0;m<4;m++){
      int r0 = rbase + m*16 + ((lane>>4)<<2);
      #pragma unroll
      for (int n=0;n<4;n++){
        int f = ((cb + n*16)>>1) + (lane&7);
        #pragma unroll
        for (int r=0;r<4;r++){
          float v = acc[m][n][r];
          float vp = __shfl_xor(v, 8);
          if (!(lane&8)){
            float gg = v;
            float a = gg/(1.f+__expf(-gg))*vp;
            C[(size_t)(r0+r)*ldc + f] = f2bf(a);
          }
        }
      }
    }
  } else {
    int rbase = rb + wr*64, cb = tN*128 + wc*64;
    #pragma unroll
    for (int m=0;m<4;m++){
      int r0 = rbase + m*16 + ((lane>>4)<<2);
      #pragma unroll
      for (int n=0;n<4;n++){
        int c = cb + n*16 + (lane&15);
        #pragma unroll
        for (int r=0;r<4;r++) C[(size_t)(r0+r)*ldc + c] = f2bf(acc[m][n][r]);
      }
    }
  }
}

// ---------------- high-precision bf16x3 GEMM (plain, XCD swizzle) ----
__global__ __launch_bounds__(256) void k_gemm_hp(
    const unsigned short* __restrict__ Ah, const unsigned short* __restrict__ Al,
    const unsigned short* __restrict__ Bh, const unsigned short* __restrict__ Bl,
    float* __restrict__ Cf,
    int K, int lda, int ldb, int ldc){
  int nx = gridDim.x, nwg = nx*gridDim.y;
  int w = xcd_swz(blockIdx.x + nx*blockIdx.y, nwg);
  int tN = w % nx, tM = w / nx;

  __shared__ __align__(16) unsigned short AsH[2][4096], AsL[2][4096];
  __shared__ __align__(16) unsigned short BsH[2][4096], BsL[2][4096];
  int tid = threadIdx.x, lane = tid & 63, wid = tid >> 6;
  int wr = wid >> 1, wc = wid & 1;
  const unsigned short* Abh = Ah + (size_t)tM*128*lda;
  const unsigned short* Abl = Al + (size_t)tM*128*lda;
  const unsigned short* Bbh = Bh + (size_t)tN*128*ldb;
  const unsigned short* Bbl = Bl + (size_t)tN*128*ldb;

  f32x4 acc[4][4];
  #pragma unroll
  for (int m=0;m<4;m++)
    #pragma unroll
    for (int n=0;n<4;n++) acc[m][n] = (f32x4){0.f,0.f,0.f,0.f};

  auto STAGE = [&](int b, int k0){
    #pragma unroll
    for (int j=0;j<2;j++){
      int cb = j*256 + tid;
      int row = cb>>2, kc = cb&3;
      int kcS = (kc ^ ((row>>1)&3))*8;
      size_t go = (size_t)row*lda + k0 + kcS;
      gload16(Abh + go, AsH[b] + (size_t)cb*8);
      gload16(Abl + go, AsL[b] + (size_t)cb*8);
      size_t bo = (size_t)row*ldb + k0 + kcS;
      gload16(Bbh + bo, BsH[b] + (size_t)cb*8);
      gload16(Bbl + bo, BsL[b] + (size_t)cb*8);
    }
  };

  int nt = K >> 5, L = nt - 1;
  STAGE(0, 0);
  if (L >= 1) STAGE(1, 32);
  int i15 = lane & 15, g = lane >> 4;
  for (int i=0; i<nt; ++i){
    int cur = i & 1;
    if (i < L) { VW(8); } else { VW(0); }
    BAR();
    short8 afh[4], afl[4], bfh[4], bfl[4];
    #pragma unroll
    for (int m=0;m<4;m++){
      int row = wr*64 + m*16 + i15;
      int ro = row*32 + (g ^ ((row>>1)&3))*8;
      afh[m] = *(const short8*)(AsH[cur] + ro);
      afl[m] = *(const short8*)(AsL[cur] + ro);
    }
    #pragma unroll
    for (int n=0;n<4;n++){
      int row = wc*64 + n*16 + i15;
      int ro = row*32 + (g ^ ((row>>1)&3))*8;
      bfh[n] = *(const short8*)(BsH[cur] + ro);
      bfl[n] = *(const short8*)(BsL[cur] + ro);
    }
    LW0();
    BAR();
    if (i + 2 <= L) STAGE(cur, (i+2)*32);
    __builtin_amdgcn_s_setprio(1);
    #pragma unroll
    for (int m=0;m<4;m++)
      #pragma unroll
      for (int n=0;n<4;n++){
        acc[m][n] = __builtin_amdgcn_mfma_f32_16x16x32_bf16(afh[m], bfh[n], acc[m][n], 0,0,0);
        acc[m][n] = __builtin_amdgcn_mfma_f32_16x16x32_bf16(afh[m], bfl[n], acc[m][n], 0,0,0);
        acc[m][n] = __builtin_amdgcn_mfma_f32_16x16x32_bf16(afl[m], bfh[n], acc[m][n], 0,0,0);
      }
    __builtin_amdgcn_s_setprio(0);
  }

  int rb = tM*128 + wr*64, cb = tN*128 + wc*64;
  #pragma unroll
  for (int m=0;m<4;m++){
    int r0 = rb + m*16 + ((lane>>4)<<2);
    #pragma unroll
    for (int n=0;n<4;n++){
      int c = cb + n*16 + (lane&15);
      #pragma unroll
      for (int r=0;r<4;r++) Cf[(size_t)(r0+r)*ldc + c] = acc[m][n][r];
    }
  }
}

// ------- persistent block-row QK^T (hp bf16x3): grid (tM, head) -------
__global__ __launch_bounds__(256) void k_qk_pers(
    const unsigned short* __restrict__ Qh, const unsigned short* __restrict__ Ql,
    const unsigned short* __restrict__ Kh, const unsigned short* __restrict__ Kl,
    float* __restrict__ Sp){
  int tM = blockIdx.x, z = blockIdx.y;
  int kvh = z >> 3;
  size_t tri = (size_t)tM*(tM+1)/2;
  const int ldq = NH*HD, ldk = NKV*HD;
  const unsigned short* Qbh = Qh + (size_t)(tM*128)*ldq + (size_t)z*HD;
  const unsigned short* Qbl = Ql + (size_t)(tM*128)*ldq + (size_t)z*HD;
  const unsigned short* Kbh = Kh + (size_t)kvh*HD;
  const unsigned short* Kbl = Kl + (size_t)kvh*HD;

  __shared__ __align__(16) unsigned short QsH[16384], QsL[16384];
  __shared__ __align__(16) unsigned short BsH[2][4096], BsL[2][4096];

  int tid = threadIdx.x, lane = tid & 63, wid = tid >> 6;
  int wr = wid >> 1, wc = wid & 1;
  int i15 = lane & 15, g = lane >> 4;

  #pragma unroll
  for (int j=0;j<8;j++){
    int gi = j*256 + tid;
    int chunk = gi >> 9;
    int row = (gi >> 2) & 127;
    int gg = gi & 3;
    int col = chunk*32 + (gg ^ ((row>>1)&3))*8;
    gload16(Qbh + (size_t)row*ldq + col, QsH + (size_t)gi*8);
    gload16(Qbl + (size_t)row*ldq + col, QsL + (size_t)gi*8);
  }

  auto BSTAGE = [&](int b, int ci){
    int tn = ci >> 2, c = ci & 3;
    const unsigned short* sh = Kbh + (size_t)(tn*128)*ldk;
    const unsigned short* sl = Kbl + (size_t)(tn*128)*ldk;
    #pragma unroll
    for (int j=0;j<2;j++){
      int gi = j*256 + tid;
      int row = gi >> 2, gg = gi & 3;
      int col = c*32 + (gg ^ ((row>>1)&3))*8;
      gload16(sh + (size_t)row*ldk + col, BsH[b] + (size_t)gi*8);
      gload16(sl + (size_t)row*ldk + col, BsL[b] + (size_t)gi*8);
    }
  };

  f32x4 acc[4][4];
  #pragma unroll
  for (int m=0;m<4;m++)
    #pragma unroll
    for (int n=0;n<4;n++) acc[m][n] = (f32x4){0.f,0.f,0.f,0.f};

  int NC = (tM+1)*4;
  BSTAGE(0, 0);
  BSTAGE(1, 1);
  for (int ci=0; ci<NC; ++ci){
    int cur = ci & 1, c = ci & 3, tn = ci >> 2;
    if (ci < NC-1) { VW(4); } else { VW(0); }
    BAR();
    short8 afh[4], afl[4], bfh[4], bfl[4];
    #pragma unroll
    for (int m=0;m<4;m++){
      int row = wr*64 + m*16 + i15;
      int ro = c*4096 + row*32 + (g ^ ((row>>1)&3))*8;
      afh[m] = *(const short8*)(QsH + ro);
      afl[m] = *(const short8*)(QsL + ro);
    }
    #pragma unroll
    for (int n=0;n<4;n++){
      int row = wc*64 + n*16 + i15;
      int ro = row*32 + (g ^ ((row>>1)&3))*8;
      bfh[n] = *(const short8*)(BsH[cur] + ro);
      bfl[n] = *(const short8*)(BsL[cur] + ro);
    }
    LW0();
    BAR();
    if (ci + 2 < NC) BSTAGE(cur, ci+2);
    __builtin_amdgcn_s_setprio(1);
    #pragma unroll
    for (int m=0;m<4;m++)
      #pragma unroll
      for (int n=0;n<4;n++){
        acc[m][n] = __builtin_amdgcn_mfma_f32_16x16x32_bf16(afh[m], bfh[n], acc[m][n], 0,0,0);
        acc[m][n] = __builtin_amdgcn_mfma_f32_16x16x32_bf16(afh[m], bfl[n], acc[m][n], 0,0,0);
        acc[m][n] = __builtin_amdgcn_mfma_f32_16x16x32_bf16(afl[m], bfh[n], acc[m][n], 0,0,0);
      }
    __builtin_amdgcn_s_setprio(0);
    if (c == 3){
      float* Cb = Sp + ((size_t)z*NBLK + tri + tn)*16384;
      #pragma unroll
      for (int m=0;m<4;m++){
        int r0 = wr*64 + m*16 + (g<<2);
        #pragma unroll
        for (int n=0;n<4;n++){
          int ccol = wc*64 + n*16 + i15;
          #pragma unroll
          for (int r=0;r<4;r++) Cb[(size_t)(r0+r)*128 + ccol] = acc[m][n][r];
        }
      }
      #pragma unroll
      for (int m=0;m<4;m++)
        #pragma unroll
        for (int n=0;n<4;n++) acc[m][n] = (f32x4){0.f,0.f,0.f,0.f};
    }
  }
}

// -------- softmax stats: m'' = rowmax + ln(rowsum); poison causal pad with -1e30 --------
__global__ void k_softmax_ml(float* __restrict__ Sp, float* __restrict__ mlb){
  int t = blockIdx.x, h = blockIdx.y, tid = threadIdx.x;
  int tM = t>>7, tr = t&127;
  size_t base = ((size_t)h*NBLK + (size_t)tM*(tM+1)/2)*16384 + (size_t)tr*128;
  int nv = t+1, kc = (tM+1)<<7;
  __shared__ float sm[4];
  float rv[8];
  #pragma unroll
  for (int j=0;j<8;j++){
    int s = tid + j*256;
    rv[j] = (s<nv) ? Sp[base + (size_t)(s>>7)*16384 + (s&127)]*SM_SCALE : -1e30f;
  }
  float m = rv[0];
  #pragma unroll
  for (int j=1;j<8;j++) m = fmaxf(m, rv[j]);
  #pragma unroll
  for (int o=32;o;o>>=1) m = fmaxf(m, __shfl_xor(m,o));
  if ((tid&63)==0) sm[tid>>6]=m;
  __syncthreads();
  m = fmaxf(fmaxf(sm[0],sm[1]),fmaxf(sm[2],sm[3]));
  __syncthreads();
  float sum = 0.f;
  #pragma unroll
  for (int j=0;j<8;j++) sum += __expf(rv[j]-m);
  #pragma unroll
  for (int o=32;o;o>>=1) sum += __shfl_xor(sum,o);
  if ((tid&63)==0) sm[tid>>6]=sum;
  __syncthreads();
  sum = sm[0]+sm[1]+sm[2]+sm[3];
  if (tid==0) mlb[(size_t)h*T_ + t] = m + logf(sum);
  for (int s = nv + tid; s < kc; s += 256)
    Sp[base + (size_t)(s>>7)*16384 + (s&127)] = -1e30f;
}

// ---------------- PV split-K, softmax fused in fragment read ----------------
__global__ __launch_bounds__(256) void k_pv_hp(
    const float* __restrict__ Sp, const float* __restrict__ mlb,
    const unsigned short* __restrict__ Vh, const unsigned short* __restrict__ Vl,
    float* __restrict__ part){
  int c = blockIdx.x, tM = blockIdx.y, z = blockIdx.z;
  int kbeg = c*512;
  int kend = min((tM+1)*128, (c+1)*512);
  if (kbeg >= kend) return;
  size_t tri = (size_t)tM*(tM+1)/2;
  const float* Ab = Sp + ((size_t)z*NBLK + tri)*16384;
  const unsigned short* Bbh = Vh + (size_t)(z>>3)*HD*T_;
  const unsigned short* Bbl = Vl + (size_t)(z>>3)*HD*T_;

  __shared__ __align__(16) float Asf[2][4096];
  __shared__ __align__(16) unsigned short BsH[2][4096], BsL[2][4096];
  int tid = threadIdx.x, lane = tid & 63, wid = tid >> 6;
  int wr = wid >> 1, wc = wid & 1;
  int i15 = lane & 15, g2 = (lane>>4)*2;

  float mrow[4];
  #pragma unroll
  for (int m=0;m<4;m++)
    mrow[m] = mlb[(size_t)z*T_ + tM*128 + wr*64 + m*16 + i15];

  int r0s = tid>>2, r1s = r0s + 64;
  int kcB = ((tid&3) ^ ((r0s>>1)&3))*8;
  int rowA = tid>>3, gA = tid&7;

  f32x4 acc[4][4];
  #pragma unroll
  for (int m=0;m<4;m++)
    #pragma unroll
    for (int n=0;n<4;n++) acc[m][n] = (f32x4){0.f,0.f,0.f,0.f};

  auto STAGE = [&](int b, int k0){
    #pragma unroll
    for (int j=0;j<4;j++){
      int r = j*32 + rowA;
      int gS = gA ^ (r & 7);
      size_t ga = (size_t)(k0>>7)*16384 + (size_t)r*128 + (k0&127) + gS*4;
      gload16(Ab + ga, Asf[b] + ((size_t)j*256 + tid)*4);
    }
    size_t bo0 = (size_t)r0s*T_ + k0 + kcB;
    size_t bo1 = (size_t)r1s*T_ + k0 + kcB;
    gload16(Bbh + bo0, BsH[b] + (size_t)tid*8);
    gload16(Bbh + bo1, BsH[b] + (size_t)(256+tid)*8);
    gload16(Bbl + bo0, BsL[b] + (size_t)tid*8);
    gload16(Bbl + bo1, BsL[b] + (size_t)(256+tid)*8);
  };

  int nt = (kend - kbeg) >> 5, L = nt - 1;
  STAGE(0, kbeg);
  if (L >= 1) STAGE(1, kbeg + 32);
  for (int i=0; i<nt; ++i){
    int cur = i & 1;
    if (i < L) { VW(8); } else { VW(0); }
    BAR();
    short8 afh[4], afl[4], bfh[4], bfl[4];
    #pragma unroll
    for (int m=0;m<4;m++){
      int r = wr*64 + m*16 + i15;
      int s0 = r*8 + ((g2  ) ^ (r&7));
      int s1 = r*8 + ((g2+1) ^ (r&7));
      f32x4 a0 = *(const f32x4*)(Asf[cur] + s0*4);
      f32x4 a1 = *(const f32x4*)(Asf[cur] + s1*4);
      float pv[8] = {a0[0],a0[1],a0[2],a0[3],a1[0],a1[1],a1[2],a1[3]};
      short8 h8, l8;
      #pragma unroll
      for (int j=0;j<8;j++){
        float p = __expf(pv[j]*SM_SCALE - mrow[m]);
        unsigned short hh, ll; split2(p, hh, ll);
        h8[j] = (short)hh; l8[j] = (short)ll;
      }
      afh[m] = h8; afl[m] = l8;
    }
    #pragma unroll
    for (int n=0;n<4;n++){
      int row = wc*64 + n*16 + i15;
      int ro = row*32 + ((lane>>4) ^ ((row>>1)&3))*8;
      bfh[n] = *(const short8*)(BsH[cur] + ro);
      bfl[n] = *(const short8*)(BsL[cur] + ro);
    }
    LW0();
    BAR();
    if (i + 2 <= L) STAGE(cur, kbeg + (i+2)*32);
    __builtin_amdgcn_s_setprio(1);
    #pragma unroll
    for (int m=0;m<4;m++)
      #pragma unroll
      for (int n=0;n<4;n++){
        acc[m][n] = __builtin_amdgcn_mfma_f32_16x16x32_bf16(afh[m], bfh[n], acc[m][n], 0,0,0);
        acc[m][n] = __builtin_amdgcn_mfma_f32_16x16x32_bf16(afh[m], bfl[n], acc[m][n], 0,0,0);
        acc[m][n] = __builtin_amdgcn_mfma_f32_16x16x32_bf16(afl[m], bfh[n], acc[m][n], 0,0,0);
      }
    __builtin_amdgcn_s_setprio(0);
  }

  float* Cb = part + (size_t)c*T_*DM + (size_t)tM*128*DM + (size_t)z*HD;
  #pragma unroll
  for (int m=0;m<4;m++){
    int r0 = wr*64 + m*16 + ((lane>>4)<<2);
    #pragma unroll
    for (int n=0;n<4;n++){
      int ccol = wc*64 + n*16 + (lane&15);
      #pragma unroll
      for (int r=0;r<4;r++) Cb[(size_t)(r0+r)*DM + ccol] = acc[m][n][r];
    }
  }
}

// reduce partials -> aoh/aol (bf16 hi/lo)
__global__ void k_pv_reduce(const float* __restrict__ part,
                            unsigned short* __restrict__ aoh, unsigned short* __restrict__ aol){
  int t = blockIdx.x, tid = threadIdx.x;
  int nc = ((t>>7) + 4) >> 2;
  #pragma unroll
  for (int half=0; half<2; ++half){
    int idx = tid + half*256;
    float4 s = ((const float4*)(part + (size_t)t*DM))[idx];
    for (int c=1; c<nc; ++c){
      float4 v = ((const float4*)(part + (size_t)c*T_*DM + (size_t)t*DM))[idx];
      s.x+=v.x; s.y+=v.y; s.z+=v.z; s.w+=v.w;
    }
    ushort4 h_, l_;
    split2(s.x,h_.x,l_.x); split2(s.y,h_.y,l_.y); split2(s.z,h_.z,l_.z); split2(s.w,h_.w,l_.w);
    ((ushort4*)(aoh + (size_t)t*DM))[idx] = h_;
    ((ushort4*)(aol + (size_t)t*DM))[idx] = l_;
  }
}

// ---------------- qkv post ----------------
__global__ void k_qkv_post_hp(const float* __restrict__ qkv, const float* __restrict__ bias,
                              const float* __restrict__ qnw, const float* __restrict__ knw,
                              const int* __restrict__ pos_,
                              unsigned short* __restrict__ qhi, unsigned short* __restrict__ qlo,
                              unsigned short* __restrict__ khi, unsigned short* __restrict__ klo,
                              unsigned short* __restrict__ vThi, unsigned short* __restrict__ vTlo){
  int t = blockIdx.x;
  int half = threadIdx.x >> 7;
  int d = threadIdx.x & 127;
  int wseg = (threadIdx.x >> 6) & 1;
  float posf = (float)pos_[t];
  __shared__ float buf[2][128];
  __shared__ float ssum[2][2];
  __shared__ float inv_sh[32];
  if (threadIdx.x < 32)
    inv_sh[threadIdx.x] = (float)pow(1000000.0, -(double)threadIdx.x/32.0);
  __syncthreads();
  for (int it=0; it<10; ++it){
    int seg = it*2 + half;
    float x = qkv[(size_t)t*QKVN + seg*128 + d] + bias[seg*128 + d];
    float p = x*x;
    #pragma unroll
    for (int o=32;o;o>>=1) p += __shfl_xor(p,o);
    if ((threadIdx.x&63)==0) ssum[half][wseg] = p;
    __syncthreads();
    float rs = rsqrtf((ssum[half][0]+ssum[half][1])*(1.f/128.f) + 1e-5f);
    float w = (seg<16) ? qnw[d] : ((seg<18) ? knw[d] : 1.f);
    float nv = x*rs*w;
    buf[half][d] = nv;
    __syncthreads();
    float outv = (seg<18) ? nv : x;
    if (seg < 18 && d < 64){
      int i = d & 31;
      float ang = posf * inv_sh[i];
      float sn, cs; sincosf(ang, &sn, &cs);
      if (d < 32) outv = nv*cs - buf[half][d+32]*sn;
      else        outv = nv*cs + buf[half][d-32]*sn;
    }
    unsigned short h_, l_; split2(outv, h_, l_);
    if (seg < 16){ size_t o = ((size_t)t*NH + seg)*HD + d; qhi[o]=h_; qlo[o]=l_; }
    else if (seg < 18){ size_t o = ((size_t)t*NKV + (seg-16))*HD + d; khi[o]=h_; klo[o]=l_; }
    else { size_t o = ((size_t)(seg-18)*HD + d)*T_ + t; vThi[o]=h_; vTlo[o]=l_; }
    __syncthreads();
  }
}

// ---- offsets: histogram idx4 in LDS (no global atomics), init padded fill, zero tok ----
__global__ void k_offsets(const int* __restrict__ idx4, int* __restrict__ offs,
                          int* __restrict__ fill, int* __restrict__ tok){
  __shared__ int hist[16];
  if (threadIdx.x < 16) hist[threadIdx.x] = 0;
  __syncthreads();
  for (int i = threadIdx.x; i < ROWS_ALL; i += 256) tok[i] = 0;
  for (int i = threadIdx.x; i < T_*4; i += 256)
    atomicAdd(&hist[idx4[i]], 1);
  __syncthreads();
  fill[threadIdx.x] = 0;                        // padded fill: 256 ints, counter at e*16
  if (threadIdx.x == 0){
    int o = 0;
    for (int e=0;e<16;e++){ offs[e]=o; o += ((hist[e]+127)>>7)<<7; }
    offs[16]=o;
    offs[17]=o + T_;
  }
}

__global__ void k_place(const int* __restrict__ idx4, const int* __restrict__ offs,
                        int* __restrict__ fill, int* __restrict__ rrow, int* __restrict__ tok){
  int t = blockIdx.x*256 + threadIdx.x;
  if (t>=T_) return;
  for (int s=0;s<4;s++){
    int e = idx4[t*4+s];
    int p = atomicAdd(&fill[e*16],1);           // one counter per 64B line
    int r = offs[e]+p;
    rrow[t*4+s]=r;
    tok[r]=t;
  }
  tok[offs[16]+t] = t;
}

__global__ void k_combine(const unsigned short* __restrict__ eout,
                          const int* __restrict__ rrow, const float* __restrict__ w4,
                          const int* __restrict__ offs, float* __restrict__ outh){
  int t = blockIdx.x;
  int rs = offs[16] + t;
  int r0=rrow[t*4+0], r1=rrow[t*4+1], r2=rrow[t*4+2], r3=rrow[t*4+3];
  float w0=w4[t*4+0], w1=w4[t*4+1], w2=w4[t*4+2], w3=w4[t*4+3];
  for (int d=threadIdx.x; d<DM; d+=256){
    float v = bf2f(eout[(size_t)rs*DM+d])
            + w0*bf2f(eout[(size_t)r0*DM+d]) + w1*bf2f(eout[(size_t)r1*DM+d])
            + w2*bf2f(eout[(size_t)r2*DM+d]) + w3*bf2f(eout[(size_t)r3*DM+d]);
    outh[(size_t)t*DM+d] = v;
  }
}

// =========================================================================
extern "C" void kernel_launch(void* const* d_in, const int* in_sizes, int n_in,
                              void* d_out, int out_size, void* d_ws, size_t ws_size,
                              hipStream_t stream){
  const int*   positions = (const int*)d_in[0];
  const float* hidden    = (const float*)d_in[1];
  const float* residual  = (const float*)d_in[2];
  const float* ln1       = (const float*)d_in[3];
  const float* ln2       = (const float*)d_in[4];
  const float* w_qkv     = (const float*)d_in[5];
  const float* b_qkv     = (const float*)d_in[6];
  const float* w_o       = (const float*)d_in[7];
  const float* qnw       = (const float*)d_in[8];
  const float* knw       = (const float*)d_in[9];
  const float* gate_w    = (const float*)d_in[10];
  const float* gate_b    = (const float*)d_in[11];
  const float* sh_wgu    = (const float*)d_in[12];
  const float* sh_wd     = (const float*)d_in[13];
  const float* e_wgu     = (const float*)d_in[14];
  const float* e_wd      = (const float*)d_in[15];
  float* out_h   = (float*)d_out;
  float* out_res = (float*)d_out + (size_t)T_*DM;

  char* ws = (char*)d_ws;
  size_t off = 0;
  auto alloc = [&](size_t b){ size_t r = off; off += (b + 255) & ~(size_t)255; return r; };

  // ---- persistent ----
  size_t o_h2b  = alloc((size_t)T_*DM*2);
  size_t o_idx  = alloc((size_t)T_*4*4);
  size_t o_w4   = alloc((size_t)T_*4*4);
  size_t o_offs = alloc(72);
  size_t o_fill = alloc(1024);
  size_t o_rrow = alloc((size_t)T_*4*4);
  size_t o_tok  = alloc((size_t)ROWS_ALL*4);

  // ---- phase-union arena ----
  size_t U0 = off;
  size_t a = U0;
  auto allocA = [&](size_t b){ size_t r = a; a += (b + 255) & ~(size_t)255; return r; };
  size_t o_h1h  = allocA((size_t)T_*DM*2);
  size_t o_h1l  = allocA((size_t)T_*DM*2);
  size_t o_wqh  = allocA((size_t)QKVN*DM*2);
  size_t o_wql  = allocA((size_t)QKVN*DM*2);
  size_t o_qkvf = allocA((size_t)T_*QKVN*4);
  size_t o_qh   = allocA((size_t)T_*NH*HD*2);
  size_t o_ql   = allocA((size_t)T_*NH*HD*2);
  size_t o_kh   = allocA((size_t)T_*NKV*HD*2);
  size_t o_kl   = allocA((size_t)T_*NKV*HD*2);
  size_t o_vth  = allocA((size_t)NKV*HD*T_*2);
  size_t o_vtl  = allocA((size_t)NKV*HD*T_*2);
  size_t o_woh  = allocA((size_t)DM*DM*2);
  size_t o_wol  = allocA((size_t)DM*DM*2);
  size_t o_aoh  = allocA((size_t)T_*DM*2);
  size_t o_aol  = allocA((size_t)T_*DM*2);
  size_t o_attnP= allocA((size_t)T_*DM*4);
  size_t o_mlb  = allocA((size_t)NH*T_*4);
  size_t o_Sp   = allocA((size_t)NH*NBLK*16384*4);
  size_t o_pvp  = allocA((size_t)4*T_*DM*4);
  // phase B (MoE)
  size_t b_ = U0;
  auto allocB = [&](size_t b){ size_t r = b_; b_ += (b + 255) & ~(size_t)255; return r; };
  size_t o_ewgu = allocB((size_t)NE*2*IM*DM*2);
  size_t o_ewd  = allocB((size_t)NE*DM*IM*2);
  size_t o_shgu = allocB((size_t)2*ISH*DM*2);
  size_t o_shwd = allocB((size_t)DM*ISH*2);
  size_t o_actx = allocB((size_t)ROWS_ALL*IM*2);
  size_t o_eout = allocB((size_t)ROWS_ALL*DM*2);

  unsigned short* h2b   = (unsigned short*)(ws+o_h2b);
  int*   idx4  = (int*)(ws+o_idx);
  float* w4p   = (float*)(ws+o_w4);
  int*   offs  = (int*)(ws+o_offs);
  int*   fill  = (int*)(ws+o_fill);
  int*   rrow  = (int*)(ws+o_rrow);
  int*   tok   = (int*)(ws+o_tok);
  unsigned short* h1h = (unsigned short*)(ws+o_h1h);
  unsigned short* h1l = (unsigned short*)(ws+o_h1l);
  unsigned short* wqh = (unsigned short*)(ws+o_wqh);
  unsigned short* wql = (unsigned short*)(ws+o_wql);
  float*          qkvf= (float*)(ws+o_qkvf);
  unsigned short* qh  = (unsigned short*)(ws+o_qh);
  unsigned short* ql  = (unsigned short*)(ws+o_ql);
  unsigned short* kh  = (unsigned short*)(ws+o_kh);
  unsigned short* kl  = (unsigned short*)(ws+o_kl);
  unsigned short* vth = (unsigned short*)(ws+o_vth);
  unsigned short* vtl = (unsigned short*)(ws+o_vtl);
  unsigned short* woh = (unsigned short*)(ws+o_woh);
  unsigned short* wol = (unsigned short*)(ws+o_wol);
  unsigned short* aoh = (unsigned short*)(ws+o_aoh);
  unsigned short* aol = (unsigned short*)(ws+o_aol);
  float*          attnP=(float*)(ws+o_attnP);
  float*          mlb = (float*)(ws+o_mlb);
  float*          Sp  = (float*)(ws+o_Sp);
  float*          pvpart = (float*)(ws+o_pvp);
  unsigned short* ewguT=(unsigned short*)(ws+o_ewgu);
  unsigned short* ewdT = (unsigned short*)(ws+o_ewd);
  unsigned short* shguT=(unsigned short*)(ws+o_shgu);
  unsigned short* shwdT=(unsigned short*)(ws+o_shwd);
  unsigned short* actx= (unsigned short*)(ws+o_actx);
  unsigned short* eout= (unsigned short*)(ws+o_eout);

  hipMemsetAsync(tok, 0, (size_t)ROWS_ALL*4, stream);

  // ---- attention phase (high precision) ----
  k_tconv2<<<dim3(QKVN/64, DM/64, 1),256,0,stream>>>(w_qkv, wqh, wql, DM, QKVN);
  k_tconv2<<<dim3(DM/64, DM/64, 1),256,0,stream>>>(w_o, woh, wol, DM, DM);

  k_add_rmsnorm<false><<<T_,256,0,stream>>>(hidden, residual, ln1, out_res, h1h, h1l, nullptr,
                                            nullptr, nullptr, nullptr, nullptr);

  k_gemm_hp<<<dim3(QKVN/128,T_/128,1),256,0,stream>>>(
      h1h, h1l, wqh, wql, qkvf, DM, DM, DM, QKVN);
  k_qkv_post_hp<<<T_,256,0,stream>>>(qkvf, b_qkv, qnw, knw, positions, qh, ql, kh, kl, vth, vtl);

  k_qk_pers<<<dim3(T_/128,NH),256,0,stream>>>(qh, ql, kh, kl, Sp);
  k_softmax_ml<<<dim3(T_,NH),256,0,stream>>>(Sp, mlb);
  k_pv_hp<<<dim3(4,T_/128,NH),256,0,stream>>>(Sp, mlb, vth, vtl, pvpart);
  k_pv_reduce<<<T_,256,0,stream>>>(pvpart, aoh, aol);
  k_gemm_hp<<<dim3(DM/128,T_/128,1),256,0,stream>>>(
      aoh, aol, woh, wol, attnP, DM, DM, DM, DM);

  // rmsnorm2 with fused MoE routing (no global atomics)
  k_add_rmsnorm<true><<<T_,256,0,stream>>>(attnP, out_res, ln2, out_res, nullptr, nullptr, h2b,
                                           gate_w, gate_b, idx4, w4p);

  k_offsets<<<1,256,0,stream>>>(idx4, offs, fill, tok);
  k_place<<<T_/256,256,0,stream>>>(idx4, offs, fill, rrow, tok);

  // ---- weight conversion (phase A arena dead now); shared weights merged as z==16 ----
  k_tconv<true ><<<dim3(2*IM/64, DM/64, NE+1),256,0,stream>>>(
      e_wgu, ewguT, sh_wgu, shguT, DM, 2*IM, (size_t)DM*2*IM, (size_t)2*IM*DM);
  k_tconv<false><<<dim3(DM/64, IM/64, NE+1),256,0,stream>>>(
      e_wd,  ewdT,  sh_wd,  shwdT, IM, DM,   (size_t)IM*DM,   (size_t)DM*IM);

  // ---- unified grouped MLP (experts + shared); silu fused into up-GEMM epilogue ----
  k_gemm2<true, true ><<<dim3(2*IM/128, ROWS_ALL/128, 1),256,0,stream>>>(
      h2b, ewguT, shguT, actx, DM, DM, DM, IM, offs, (size_t)2*IM*DM, tok);
  k_gemm2<false, false><<<dim3(DM/128, ROWS_ALL/128, 1),256,0,stream>>>(
      actx, ewdT, shwdT, eout, IM, IM, IM, DM, offs, (size_t)DM*IM, nullptr);

  // ---- combine ----
  k_combine<<<T_,256,0,stream>>>(eout, rrow, w4p, offs, out_h);
}

// Round 18
// 737.400 us; speedup vs baseline: 1.1287x; 1.0200x over previous
//
#include <hip/hip_runtime.h>
#include <stdint.h>
#include <math.h>

#define T_ 2048
#define DM 2048
#define NH 16
#define NKV 2
#define HD 128
#define QKVN 2560
#define NE 16
#define IM 768
#define ISH 768
#define MAXROWS 10240
#define ROWS_ALL 12288   // MAXROWS + T_ (shared region appended)
#define NBLK 136         // 16*17/2 causal 128x128 blocks per head
#define SM_SCALE 0.08838834764831845f

typedef __attribute__((ext_vector_type(8))) short short8;
typedef __attribute__((ext_vector_type(4))) float f32x4;

__device__ __forceinline__ float bf2f(unsigned short u){ return __uint_as_float(((unsigned int)u)<<16); }
__device__ __forceinline__ unsigned short f2bf(float f){
  unsigned int u = __float_as_uint(f);
  return (unsigned short)((u + 0x7FFFu + ((u>>16)&1u)) >> 16);
}
__device__ __forceinline__ void split2(float x, unsigned short& hi, unsigned short& lo){
  hi = f2bf(x);
  lo = f2bf(x - bf2f(hi));
}

__device__ __forceinline__ void gload16(const void* g, void* l){
  __builtin_amdgcn_global_load_lds((const __attribute__((address_space(1))) unsigned int*)g,
                                   (__attribute__((address_space(3))) unsigned int*)l, 16, 0, 0);
}

// bijective XCD swizzle (m204)
__device__ __forceinline__ int xcd_swz(int bid, int nwg){
  int q = nwg >> 3, r = nwg & 7, x = bid & 7, p = bid >> 3;
  return (x < r ? x*(q+1) : r*(q+1) + (x-r)*q) + p;
}

#define BAR()    asm volatile("s_barrier" ::: "memory")
#define VW(N)    asm volatile("s_waitcnt vmcnt(" #N ")" ::: "memory")
#define LW0()    do{ asm volatile("s_waitcnt lgkmcnt(0)" ::: "memory"); __builtin_amdgcn_sched_barrier(0); }while(0)

// ------- transpose conv f32 -> bf16, vectorized (64x64 tile, float4 in, short8 out) ----
// ILV: g/u 8-col interleave. Last z (== gridDim.z-1) optionally reads/writes shared-weight ptrs.
template<bool ILV>
__global__ void k_tconv(const float* __restrict__ src, unsigned short* __restrict__ dst,
                        const float* __restrict__ srcS, unsigned short* __restrict__ dstS,
                        int R, int C, size_t sS, size_t sD){
  int z = blockIdx.z;
  if (srcS && z == gridDim.z-1){ src = srcS; dst = dstS; }
  else { src += (size_t)z * sS; dst += (size_t)z * sD; }
  __shared__ float tile[64*65];
  int tid = threadIdx.x;
  int r0 = blockIdx.y*64, c0 = blockIdx.x*64;
  int lr = tid>>4, lc = (tid&15)*4;
  #pragma unroll
  for (int j=0;j<4;j++){
    int row = j*16 + lr;
    float4 v = *(const float4*)&src[(size_t)(r0+row)*C + c0 + lc];
    float* t = &tile[row*65 + lc];
    t[0]=v.x; t[1]=v.y; t[2]=v.z; t[3]=v.w;
  }
  __syncthreads();
  #pragma unroll
  for (int jj=0;jj<2;jj++){
    int slot = jj*256 + tid;
    int c = slot>>3, ro = (slot&7)*8;
    int cg = c0 + c;
    int cd = cg;
    if (ILV){ int b = cg>>3, inner = cg&7; cd = (b<96 ? b*16 : (b-96)*16+8) + inner; }
    short8 o;
    #pragma unroll
    for (int k=0;k<8;k++) o[k] = (short)f2bf(tile[(ro+k)*65 + c]);
    *(short8*)&dst[(size_t)cd*R + r0 + ro] = o;
  }
}

// ------- transpose conv f32 -> bf16 hi + lo planes, vectorized -------
__global__ void k_tconv2(const float* __restrict__ src, unsigned short* __restrict__ dhi,
                         unsigned short* __restrict__ dlo, int R, int C){
  __shared__ float tile[64*65];
  int tid = threadIdx.x;
  int r0 = blockIdx.y*64, c0 = blockIdx.x*64;
  int lr = tid>>4, lc = (tid&15)*4;
  #pragma unroll
  for (int j=0;j<4;j++){
    int row = j*16 + lr;
    float4 v = *(const float4*)&src[(size_t)(r0+row)*C + c0 + lc];
    float* t = &tile[row*65 + lc];
    t[0]=v.x; t[1]=v.y; t[2]=v.z; t[3]=v.w;
  }
  __syncthreads();
  #pragma unroll
  for (int jj=0;jj<2;jj++){
    int slot = jj*256 + tid;
    int c = slot>>3, ro = (slot&7)*8;
    short8 oh, ol;
    #pragma unroll
    for (int k=0;k<8;k++){
      unsigned short h_, l_;
      split2(tile[(ro+k)*65 + c], h_, l_);
      oh[k] = (short)h_; ol[k] = (short)l_;
    }
    size_t o = (size_t)(c0+c)*R + r0 + ro;
    *(short8*)&dhi[o] = oh;
    *(short8*)&dlo[o] = ol;
  }
}

// ---------------- add + rmsnorm; ROUTE: fused MoE gate (no global atomics) ----------------
template<bool ROUTE>
__global__ void k_add_rmsnorm(const float* __restrict__ a, const float* __restrict__ b,
                              const float* __restrict__ w, float* __restrict__ resout,
                              unsigned short* __restrict__ ohi, unsigned short* __restrict__ olo,
                              unsigned short* __restrict__ obf,
                              const float* __restrict__ gw, const float* __restrict__ gbias,
                              int* __restrict__ idx4, float* __restrict__ w4){
  int t = blockIdx.x, tid = threadIdx.x;
  const float4* a4 = (const float4*)(a + (size_t)t*DM);
  const float4* b4 = (const float4*)(b + (size_t)t*DM);
  float4 va = a4[tid], vb = b4[tid];
  float4 wa = a4[tid+256], wb = b4[tid+256];
  float4 v0, v1;
  v0.x=va.x+vb.x; v0.y=va.y+vb.y; v0.z=va.z+vb.z; v0.w=va.w+vb.w;
  v1.x=wa.x+wb.x; v1.y=wa.y+wb.y; v1.z=wa.z+wb.z; v1.w=wa.w+wb.w;
  float s = v0.x*v0.x+v0.y*v0.y+v0.z*v0.z+v0.w*v0.w
          + v1.x*v1.x+v1.y*v1.y+v1.z*v1.z+v1.w*v1.w;
  #pragma unroll
  for (int o=32;o;o>>=1) s += __shfl_xor(s,o);
  __shared__ float sm[4];
  if ((tid&63)==0) sm[tid>>6]=s;
  __syncthreads();
  s = sm[0]+sm[1]+sm[2]+sm[3];
  float rs = rsqrtf(s*(1.f/(float)DM) + 1e-5f);
  ((float4*)(resout + (size_t)t*DM))[tid] = v0;
  ((float4*)(resout + (size_t)t*DM))[tid+256] = v1;
  const float4* w4p_ = (const float4*)w;
  float4 w0 = w4p_[tid], w1 = w4p_[tid+256];
  float n[8] = { v0.x*rs*w0.x, v0.y*rs*w0.y, v0.z*rs*w0.z, v0.w*rs*w0.w,
                 v1.x*rs*w1.x, v1.y*rs*w1.y, v1.z*rs*w1.z, v1.w*rs*w1.w };
  if (ohi){
    ushort4 h0,h1,l0,l1;
    split2(n[0],h0.x,l0.x); split2(n[1],h0.y,l0.y); split2(n[2],h0.z,l0.z); split2(n[3],h0.w,l0.w);
    split2(n[4],h1.x,l1.x); split2(n[5],h1.y,l1.y); split2(n[6],h1.z,l1.z); split2(n[7],h1.w,l1.w);
    ((ushort4*)(ohi + (size_t)t*DM))[tid] = h0;
    ((ushort4*)(ohi + (size_t)t*DM))[tid+256] = h1;
    ((ushort4*)(olo + (size_t)t*DM))[tid] = l0;
    ((ushort4*)(olo + (size_t)t*DM))[tid+256] = l1;
  }
  if (obf){
    ushort4 o0 = make_ushort4(f2bf(n[0]),f2bf(n[1]),f2bf(n[2]),f2bf(n[3]));
    ushort4 o1 = make_ushort4(f2bf(n[4]),f2bf(n[5]),f2bf(n[6]),f2bf(n[7]));
    ((ushort4*)(obf + (size_t)t*DM))[tid] = o0;
    ((ushort4*)(obf + (size_t)t*DM))[tid+256] = o1;
  }
  if constexpr (ROUTE){
    __shared__ float xrow[DM];          // 8 KB
    __shared__ float red[16][17];
    #pragma unroll
    for (int jj=0;jj<4;jj++) xrow[4*tid+jj] = n[jj];
    #pragma unroll
    for (int jj=0;jj<4;jj++) xrow[1024+4*tid+jj] = n[4+jj];
    __syncthreads();
    // coalesced gate GEMV: lane (grp=tid>>4, e=tid&15); gw row-major [DM][16]
    int e = tid & 15, grp = tid >> 4;
    float part = 0.f;
    #pragma unroll 8
    for (int c = grp; c < DM; c += 16)
      part += xrow[c] * gw[(size_t)c*16 + e];
    red[grp][e] = part;
    __syncthreads();
    if (tid==0){
      float sc[16], sb[16];
      for (int ee=0;ee<16;ee++){
        float lg = 0.f;
        for (int g2=0;g2<16;g2++) lg += red[g2][ee];
        sc[ee] = 1.f/(1.f+expf(-lg));
        sb[ee] = sc[ee] + gbias[ee];
      }
      float gs[4];
      for (int g=0;g<4;g++){
        float m1=-3.4e38f, m2=-3.4e38f;
        for (int j=0;j<4;j++){
          float v = sb[g*4+j];
          if (v>m1){ m2=m1; m1=v; } else if (v>m2) m2=v;
        }
        gs[g]=m1+m2;
      }
      int g1=0; for (int g=1;g<4;g++) if (gs[g]>gs[g1]) g1=g;
      int g2=-1; for (int g=0;g<4;g++){ if (g==g1) continue; if (g2<0 || gs[g]>gs[g2]) g2=g; }
      float msk[16];
      for (int ee=0;ee<16;ee++){ int g=ee>>2; msk[ee] = (g==g1||g==g2)? sb[ee] : -3.4e38f; }
      int id[4]; float wv[4]; float wsum=0.f;
      for (int s2=0;s2<4;s2++){
        int bb=0; float bv=-3.5e38f;
        for (int ee=0;ee<16;ee++) if (msk[ee]>bv){ bv=msk[ee]; bb=ee; }
        id[s2]=bb; wv[s2]=sc[bb]; wsum+=sc[bb]; msk[bb]=-3.5e38f;
      }
      float invs = 1.f/wsum;
      for (int s2=0;s2<4;s2++){
        idx4[t*4+s2]=id[s2];
        w4[t*4+s2]=wv[s2]*invs;
      }
    }
  }
}

// ------- grouped bf16 GEMM (experts + shared), BK=32 counted-vmcnt 2-deep pipeline -------
// ACT: B cols are (g,u) 8-interleaved; epilogue computes silu(g)*u -> bf16 C [rows][IM]
template<bool GATHER, bool ACT>
__global__ __launch_bounds__(256) void k_gemm2(
    const unsigned short* __restrict__ A, const unsigned short* __restrict__ Be,
    const unsigned short* __restrict__ Bsh, unsigned short* __restrict__ C,
    int K, int lda, int ldb, int ldc,
    const int* __restrict__ offs, size_t sBe, const int* __restrict__ tok){
  int nx = gridDim.x;
  int nwg = nx * gridDim.y;
  int wid_ = xcd_swz(blockIdx.x + nx*blockIdx.y, nwg);
  int tN = wid_ % nx, tM = wid_ / nx;
  int rb = tM*128;
  if (rb >= offs[17]) return;
  const unsigned short* B;
  if (rb >= offs[16]) B = Bsh;
  else {
    int e=0;
    for (; e<15; ++e) if (offs[e+1] > rb) break;
    B = Be + (size_t)e*sBe;
  }
  __shared__ __align__(16) unsigned short As[2][4096];
  __shared__ __align__(16) unsigned short Bs[2][4096];
  int tid = threadIdx.x, lane = tid & 63, wwid = tid >> 6;
  int wr = wwid >> 1, wc = wwid & 1;
  const unsigned short* Bb = B + (size_t)tN*128*ldb;

  const unsigned short* Asrc0;
  const unsigned short* Asrc1;
  int r0s = tid>>2, r1s = r0s + 64;
  {
    if (GATHER){
      Asrc0 = A + (size_t)tok[rb + r0s]*lda;
      Asrc1 = A + (size_t)tok[rb + r1s]*lda;
    } else {
      Asrc0 = A + (size_t)(rb + r0s)*lda;
      Asrc1 = A + (size_t)(rb + r1s)*lda;
    }
  }
  int kc = tid&3;
  int sw = (r0s>>1)&3;
  int kcS = (kc ^ sw)*8;

  f32x4 acc[4][4];
  #pragma unroll
  for (int m=0;m<4;m++)
    #pragma unroll
    for (int n=0;n<4;n++) acc[m][n] = (f32x4){0.f,0.f,0.f,0.f};

  auto STAGE = [&](int b, int k0){
    gload16(Asrc0 + k0 + kcS, As[b] + (size_t)tid*8);
    gload16(Asrc1 + k0 + kcS, As[b] + (size_t)(256+tid)*8);
    gload16(Bb + (size_t)r0s*ldb + k0 + kcS, Bs[b] + (size_t)tid*8);
    gload16(Bb + (size_t)r1s*ldb + k0 + kcS, Bs[b] + (size_t)(256+tid)*8);
  };

  int nt = K >> 5, L = nt - 1;
  STAGE(0, 0);
  if (L >= 1) STAGE(1, 32);
  int i15 = lane & 15, g = lane >> 4;
  for (int i=0; i<nt; ++i){
    int cur = i & 1;
    if (i < L) { VW(4); } else { VW(0); }
    BAR();
    short8 af[4], bfr[4];
    #pragma unroll
    for (int m=0;m<4;m++){
      int row = wr*64 + m*16 + i15;
      int geff = g ^ ((row>>1)&3);
      af[m] = *(const short8*)(As[cur] + row*32 + geff*8);
    }
    #pragma unroll
    for (int n=0;n<4;n++){
      int row = wc*64 + n*16 + i15;
      int geff = g ^ ((row>>1)&3);
      bfr[n] = *(const short8*)(Bs[cur] + row*32 + geff*8);
    }
    LW0();
    BAR();
    if (i + 2 <= L) STAGE(cur, (i+2)*32);
    __builtin_amdgcn_s_setprio(1);
    #pragma unroll
    for (int m=0;m<4;m++)
      #pragma unroll
      for (int n=0;n<4;n++)
        acc[m][n] = __builtin_amdgcn_mfma_f32_16x16x32_bf16(af[m], bfr[n], acc[m][n], 0,0,0);
    __builtin_amdgcn_s_setprio(0);
  }

  if (ACT){
    int rbase = rb + wr*64, cb = tN*128 + wc*64;
    #pragma unroll
    for (int m=0;m<4;m++){
      int r0 = rbase + m*16 + ((lane>>4)<<2);
      #pragma unroll
      for (int n=0;n<4;n++){
        int f = ((cb + n*16)>>1) + (lane&7);
        #pragma unroll
        for (int r=0;r<4;r++){
          float v = acc[m][n][r];
          float vp = __shfl_xor(v, 8);
          if (!(lane&8)){
            float gg = v;
            float a = gg/(1.f+__expf(-gg))*vp;
            C[(size_t)(r0+r)*ldc + f] = f2bf(a);
          }
        }
      }
    }
  } else {
    int rbase = rb + wr*64, cb = tN*128 + wc*64;
    #pragma unroll
    for (int m=0;m<4;m++){
      int r0 = rbase + m*16 + ((lane>>4)<<2);
      #pragma unroll
      for (int n=0;n<4;n++){
        int c = cb + n*16 + (lane&15);
        #pragma unroll
        for (int r=0;r<4;r++) C[(size_t)(r0+r)*ldc + c] = f2bf(acc[m][n][r]);
      }
    }
  }
}

// ---------------- high-precision bf16x3 GEMM (plain, XCD swizzle) ----
__global__ __launch_bounds__(256) void k_gemm_hp(
    const unsigned short* __restrict__ Ah, const unsigned short* __restrict__ Al,
    const unsigned short* __restrict__ Bh, const unsigned short* __restrict__ Bl,
    float* __restrict__ Cf,
    int K, int lda, int ldb, int ldc){
  int nx = gridDim.x, nwg = nx*gridDim.y;
  int w = xcd_swz(blockIdx.x + nx*blockIdx.y, nwg);
  int tN = w % nx, tM = w / nx;

  __shared__ __align__(16) unsigned short AsH[2][4096], AsL[2][4096];
  __shared__ __align__(16) unsigned short BsH[2][4096], BsL[2][4096];
  int tid = threadIdx.x, lane = tid & 63, wid = tid >> 6;
  int wr = wid >> 1, wc = wid & 1;
  const unsigned short* Abh = Ah + (size_t)tM*128*lda;
  const unsigned short* Abl = Al + (size_t)tM*128*lda;
  const unsigned short* Bbh = Bh + (size_t)tN*128*ldb;
  const unsigned short* Bbl = Bl + (size_t)tN*128*ldb;

  f32x4 acc[4][4];
  #pragma unroll
  for (int m=0;m<4;m++)
    #pragma unroll
    for (int n=0;n<4;n++) acc[m][n] = (f32x4){0.f,0.f,0.f,0.f};

  auto STAGE = [&](int b, int k0){
    #pragma unroll
    for (int j=0;j<2;j++){
      int cb = j*256 + tid;
      int row = cb>>2, kc = cb&3;
      int kcS = (kc ^ ((row>>1)&3))*8;
      size_t go = (size_t)row*lda + k0 + kcS;
      gload16(Abh + go, AsH[b] + (size_t)cb*8);
      gload16(Abl + go, AsL[b] + (size_t)cb*8);
      size_t bo = (size_t)row*ldb + k0 + kcS;
      gload16(Bbh + bo, BsH[b] + (size_t)cb*8);
      gload16(Bbl + bo, BsL[b] + (size_t)cb*8);
    }
  };

  int nt = K >> 5, L = nt - 1;
  STAGE(0, 0);
  if (L >= 1) STAGE(1, 32);
  int i15 = lane & 15, g = lane >> 4;
  for (int i=0; i<nt; ++i){
    int cur = i & 1;
    if (i < L) { VW(8); } else { VW(0); }
    BAR();
    short8 afh[4], afl[4], bfh[4], bfl[4];
    #pragma unroll
    for (int m=0;m<4;m++){
      int row = wr*64 + m*16 + i15;
      int ro = row*32 + (g ^ ((row>>1)&3))*8;
      afh[m] = *(const short8*)(AsH[cur] + ro);
      afl[m] = *(const short8*)(AsL[cur] + ro);
    }
    #pragma unroll
    for (int n=0;n<4;n++){
      int row = wc*64 + n*16 + i15;
      int ro = row*32 + (g ^ ((row>>1)&3))*8;
      bfh[n] = *(const short8*)(BsH[cur] + ro);
      bfl[n] = *(const short8*)(BsL[cur] + ro);
    }
    LW0();
    BAR();
    if (i + 2 <= L) STAGE(cur, (i+2)*32);
    __builtin_amdgcn_s_setprio(1);
    #pragma unroll
    for (int m=0;m<4;m++)
      #pragma unroll
      for (int n=0;n<4;n++){
        acc[m][n] = __builtin_amdgcn_mfma_f32_16x16x32_bf16(afh[m], bfh[n], acc[m][n], 0,0,0);
        acc[m][n] = __builtin_amdgcn_mfma_f32_16x16x32_bf16(afh[m], bfl[n], acc[m][n], 0,0,0);
        acc[m][n] = __builtin_amdgcn_mfma_f32_16x16x32_bf16(afl[m], bfh[n], acc[m][n], 0,0,0);
      }
    __builtin_amdgcn_s_setprio(0);
  }

  int rb = tM*128 + wr*64, cb = tN*128 + wc*64;
  #pragma unroll
  for (int m=0;m<4;m++){
    int r0 = rb + m*16 + ((lane>>4)<<2);
    #pragma unroll
    for (int n=0;n<4;n++){
      int c = cb + n*16 + (lane&15);
      #pragma unroll
      for (int r=0;r<4;r++) Cf[(size_t)(r0+r)*ldc + c] = acc[m][n][r];
    }
  }
}

// ------- persistent block-row QK^T (hp bf16x3): grid (tM, head) -------
__global__ __launch_bounds__(256) void k_qk_pers(
    const unsigned short* __restrict__ Qh, const unsigned short* __restrict__ Ql,
    const unsigned short* __restrict__ Kh, const unsigned short* __restrict__ Kl,
    float* __restrict__ Sp){
  int tM = blockIdx.x, z = blockIdx.y;
  int kvh = z >> 3;
  size_t tri = (size_t)tM*(tM+1)/2;
  const int ldq = NH*HD, ldk = NKV*HD;
  const unsigned short* Qbh = Qh + (size_t)(tM*128)*ldq + (size_t)z*HD;
  const unsigned short* Qbl = Ql + (size_t)(tM*128)*ldq + (size_t)z*HD;
  const unsigned short* Kbh = Kh + (size_t)kvh*HD;
  const unsigned short* Kbl = Kl + (size_t)kvh*HD;

  __shared__ __align__(16) unsigned short QsH[16384], QsL[16384];
  __shared__ __align__(16) unsigned short BsH[2][4096], BsL[2][4096];

  int tid = threadIdx.x, lane = tid & 63, wid = tid >> 6;
  int wr = wid >> 1, wc = wid & 1;
  int i15 = lane & 15, g = lane >> 4;

  #pragma unroll
  for (int j=0;j<8;j++){
    int gi = j*256 + tid;
    int chunk = gi >> 9;
    int row = (gi >> 2) & 127;
    int gg = gi & 3;
    int col = chunk*32 + (gg ^ ((row>>1)&3))*8;
    gload16(Qbh + (size_t)row*ldq + col, QsH + (size_t)gi*8);
    gload16(Qbl + (size_t)row*ldq + col, QsL + (size_t)gi*8);
  }

  auto BSTAGE = [&](int b, int ci){
    int tn = ci >> 2, c = ci & 3;
    const unsigned short* sh = Kbh + (size_t)(tn*128)*ldk;
    const unsigned short* sl = Kbl + (size_t)(tn*128)*ldk;
    #pragma unroll
    for (int j=0;j<2;j++){
      int gi = j*256 + tid;
      int row = gi >> 2, gg = gi & 3;
      int col = c*32 + (gg ^ ((row>>1)&3))*8;
      gload16(sh + (size_t)row*ldk + col, BsH[b] + (size_t)gi*8);
      gload16(sl + (size_t)row*ldk + col, BsL[b] + (size_t)gi*8);
    }
  };

  f32x4 acc[4][4];
  #pragma unroll
  for (int m=0;m<4;m++)
    #pragma unroll
    for (int n=0;n<4;n++) acc[m][n] = (f32x4){0.f,0.f,0.f,0.f};

  int NC = (tM+1)*4;
  BSTAGE(0, 0);
  BSTAGE(1, 1);
  for (int ci=0; ci<NC; ++ci){
    int cur = ci & 1, c = ci & 3, tn = ci >> 2;
    if (ci < NC-1) { VW(4); } else { VW(0); }
    BAR();
    short8 afh[4], afl[4], bfh[4], bfl[4];
    #pragma unroll
    for (int m=0;m<4;m++){
      int row = wr*64 + m*16 + i15;
      int ro = c*4096 + row*32 + (g ^ ((row>>1)&3))*8;
      afh[m] = *(const short8*)(QsH + ro);
      afl[m] = *(const short8*)(QsL + ro);
    }
    #pragma unroll
    for (int n=0;n<4;n++){
      int row = wc*64 + n*16 + i15;
      int ro = row*32 + (g ^ ((row>>1)&3))*8;
      bfh[n] = *(const short8*)(BsH[cur] + ro);
      bfl[n] = *(const short8*)(BsL[cur] + ro);
    }
    LW0();
    BAR();
    if (ci + 2 < NC) BSTAGE(cur, ci+2);
    __builtin_amdgcn_s_setprio(1);
    #pragma unroll
    for (int m=0;m<4;m++)
      #pragma unroll
      for (int n=0;n<4;n++){
        acc[m][n] = __builtin_amdgcn_mfma_f32_16x16x32_bf16(afh[m], bfh[n], acc[m][n], 0,0,0);
        acc[m][n] = __builtin_amdgcn_mfma_f32_16x16x32_bf16(afh[m], bfl[n], acc[m][n], 0,0,0);
        acc[m][n] = __builtin_amdgcn_mfma_f32_16x16x32_bf16(afl[m], bfh[n], acc[m][n], 0,0,0);
      }
    __builtin_amdgcn_s_setprio(0);
    if (c == 3){
      float* Cb = Sp + ((size_t)z*NBLK + tri + tn)*16384;
      #pragma unroll
      for (int m=0;m<4;m++){
        int r0 = wr*64 + m*16 + (g<<2);
        #pragma unroll
        for (int n=0;n<4;n++){
          int ccol = wc*64 + n*16 + i15;
          #pragma unroll
          for (int r=0;r<4;r++) Cb[(size_t)(r0+r)*128 + ccol] = acc[m][n][r];
        }
      }
      #pragma unroll
      for (int m=0;m<4;m++)
        #pragma unroll
        for (int n=0;n<4;n++) acc[m][n] = (f32x4){0.f,0.f,0.f,0.f};
    }
  }
}

// -------- softmax stats: m'' = rowmax + ln(rowsum); poison causal pad with -1e30 --------
__global__ void k_softmax_ml(float* __restrict__ Sp, float* __restrict__ mlb){
  int t = blockIdx.x, h = blockIdx.y, tid = threadIdx.x;
  int tM = t>>7, tr = t&127;
  size_t base = ((size_t)h*NBLK + (size_t)tM*(tM+1)/2)*16384 + (size_t)tr*128;
  int nv = t+1, kc = (tM+1)<<7;
  __shared__ float sm[4];
  float rv[8];
  #pragma unroll
  for (int j=0;j<8;j++){
    int s = tid + j*256;
    rv[j] = (s<nv) ? Sp[base + (size_t)(s>>7)*16384 + (s&127)]*SM_SCALE : -1e30f;
  }
  float m = rv[0];
  #pragma unroll
  for (int j=1;j<8;j++) m = fmaxf(m, rv[j]);
  #pragma unroll
  for (int o=32;o;o>>=1) m = fmaxf(m, __shfl_xor(m,o));
  if ((tid&63)==0) sm[tid>>6]=m;
  __syncthreads();
  m = fmaxf(fmaxf(sm[0],sm[1]),fmaxf(sm[2],sm[3]));
  __syncthreads();
  float sum = 0.f;
  #pragma unroll
  for (int j=0;j<8;j++) sum += __expf(rv[j]-m);
  #pragma unroll
  for (int o=32;o;o>>=1) sum += __shfl_xor(sum,o);
  if ((tid&63)==0) sm[tid>>6]=sum;
  __syncthreads();
  sum = sm[0]+sm[1]+sm[2]+sm[3];
  if (tid==0) mlb[(size_t)h*T_ + t] = m + logf(sum);
  for (int s = nv + tid; s < kc; s += 256)
    Sp[base + (size_t)(s>>7)*16384 + (s&127)] = -1e30f;
}

// ---------------- PV split-K, softmax fused in fragment read ----------------
__global__ __launch_bounds__(256) void k_pv_hp(
    const float* __restrict__ Sp, const float* __restrict__ mlb,
    const unsigned short* __restrict__ Vh, const unsigned short* __restrict__ Vl,
    float* __restrict__ part){
  int c = blockIdx.x, tM = blockIdx.y, z = blockIdx.z;
  int kbeg = c*512;
  int kend = min((tM+1)*128, (c+1)*512);
  if (kbeg >= kend) return;
  size_t tri = (size_t)tM*(tM+1)/2;
  const float* Ab = Sp + ((size_t)z*NBLK + tri)*16384;
  const unsigned short* Bbh = Vh + (size_t)(z>>3)*HD*T_;
  const unsigned short* Bbl = Vl + (size_t)(z>>3)*HD*T_;

  __shared__ __align__(16) float Asf[2][4096];
  __shared__ __align__(16) unsigned short BsH[2][4096], BsL[2][4096];
  int tid = threadIdx.x, lane = tid & 63, wid = tid >> 6;
  int wr = wid >> 1, wc = wid & 1;
  int i15 = lane & 15, g2 = (lane>>4)*2;

  float mrow[4];
  #pragma unroll
  for (int m=0;m<4;m++)
    mrow[m] = mlb[(size_t)z*T_ + tM*128 + wr*64 + m*16 + i15];

  int r0s = tid>>2, r1s = r0s + 64;
  int kcB = ((tid&3) ^ ((r0s>>1)&3))*8;
  int rowA = tid>>3, gA = tid&7;

  f32x4 acc[4][4];
  #pragma unroll
  for (int m=0;m<4;m++)
    #pragma unroll
    for (int n=0;n<4;n++) acc[m][n] = (f32x4){0.f,0.f,0.f,0.f};

  auto STAGE = [&](int b, int k0){
    #pragma unroll
    for (int j=0;j<4;j++){
      int r = j*32 + rowA;
      int gS = gA ^ (r & 7);
      size_t ga = (size_t)(k0>>7)*16384 + (size_t)r*128 + (k0&127) + gS*4;
      gload16(Ab + ga, Asf[b] + ((size_t)j*256 + tid)*4);
    }
    size_t bo0 = (size_t)r0s*T_ + k0 + kcB;
    size_t bo1 = (size_t)r1s*T_ + k0 + kcB;
    gload16(Bbh + bo0, BsH[b] + (size_t)tid*8);
    gload16(Bbh + bo1, BsH[b] + (size_t)(256+tid)*8);
    gload16(Bbl + bo0, BsL[b] + (size_t)tid*8);
    gload16(Bbl + bo1, BsL[b] + (size_t)(256+tid)*8);
  };

  int nt = (kend - kbeg) >> 5, L = nt - 1;
  STAGE(0, kbeg);
  if (L >= 1) STAGE(1, kbeg + 32);
  for (int i=0; i<nt; ++i){
    int cur = i & 1;
    if (i < L) { VW(8); } else { VW(0); }
    BAR();
    short8 afh[4], afl[4], bfh[4], bfl[4];
    #pragma unroll
    for (int m=0;m<4;m++){
      int r = wr*64 + m*16 + i15;
      int s0 = r*8 + ((g2  ) ^ (r&7));
      int s1 = r*8 + ((g2+1) ^ (r&7));
      f32x4 a0 = *(const f32x4*)(Asf[cur] + s0*4);
      f32x4 a1 = *(const f32x4*)(Asf[cur] + s1*4);
      float pv[8] = {a0[0],a0[1],a0[2],a0[3],a1[0],a1[1],a1[2],a1[3]};
      short8 h8, l8;
      #pragma unroll
      for (int j=0;j<8;j++){
        float p = __expf(pv[j]*SM_SCALE - mrow[m]);
        unsigned short hh, ll; split2(p, hh, ll);
        h8[j] = (short)hh; l8[j] = (short)ll;
      }
      afh[m] = h8; afl[m] = l8;
    }
    #pragma unroll
    for (int n=0;n<4;n++){
      int row = wc*64 + n*16 + i15;
      int ro = row*32 + ((lane>>4) ^ ((row>>1)&3))*8;
      bfh[n] = *(const short8*)(BsH[cur] + ro);
      bfl[n] = *(const short8*)(BsL[cur] + ro);
    }
    LW0();
    BAR();
    if (i + 2 <= L) STAGE(cur, kbeg + (i+2)*32);
    __builtin_amdgcn_s_setprio(1);
    #pragma unroll
    for (int m=0;m<4;m++)
      #pragma unroll
      for (int n=0;n<4;n++){
        acc[m][n] = __builtin_amdgcn_mfma_f32_16x16x32_bf16(afh[m], bfh[n], acc[m][n], 0,0,0);
        acc[m][n] = __builtin_amdgcn_mfma_f32_16x16x32_bf16(afh[m], bfl[n], acc[m][n], 0,0,0);
        acc[m][n] = __builtin_amdgcn_mfma_f32_16x16x32_bf16(afl[m], bfh[n], acc[m][n], 0,0,0);
      }
    __builtin_amdgcn_s_setprio(0);
  }

  float* Cb = part + (size_t)c*T_*DM + (size_t)tM*128*DM + (size_t)z*HD;
  #pragma unroll
  for (int m=0;m<4;m++){
    int r0 = wr*64 + m*16 + ((lane>>4)<<2);
    #pragma unroll
    for (int n=0;n<4;n++){
      int ccol = wc*64 + n*16 + (lane&15);
      #pragma unroll
      for (int r=0;r<4;r++) Cb[(size_t)(r0+r)*DM + ccol] = acc[m][n][r];
    }
  }
}

// reduce partials -> aoh/aol (bf16 hi/lo)
__global__ void k_pv_reduce(const float* __restrict__ part,
                            unsigned short* __restrict__ aoh, unsigned short* __restrict__ aol){
  int t = blockIdx.x, tid = threadIdx.x;
  int nc = ((t>>7) + 4) >> 2;
  #pragma unroll
  for (int half=0; half<2; ++half){
    int idx = tid + half*256;
    float4 s = ((const float4*)(part + (size_t)t*DM))[idx];
    for (int c=1; c<nc; ++c){
      float4 v = ((const float4*)(part + (size_t)c*T_*DM + (size_t)t*DM))[idx];
      s.x+=v.x; s.y+=v.y; s.z+=v.z; s.w+=v.w;
    }
    ushort4 h_, l_;
    split2(s.x,h_.x,l_.x); split2(s.y,h_.y,l_.y); split2(s.z,h_.z,l_.z); split2(s.w,h_.w,l_.w);
    ((ushort4*)(aoh + (size_t)t*DM))[idx] = h_;
    ((ushort4*)(aol + (size_t)t*DM))[idx] = l_;
  }
}

// ---------------- qkv post ----------------
__global__ void k_qkv_post_hp(const float* __restrict__ qkv, const float* __restrict__ bias,
                              const float* __restrict__ qnw, const float* __restrict__ knw,
                              const int* __restrict__ pos_,
                              unsigned short* __restrict__ qhi, unsigned short* __restrict__ qlo,
                              unsigned short* __restrict__ khi, unsigned short* __restrict__ klo,
                              unsigned short* __restrict__ vThi, unsigned short* __restrict__ vTlo){
  int t = blockIdx.x;
  int half = threadIdx.x >> 7;
  int d = threadIdx.x & 127;
  int wseg = (threadIdx.x >> 6) & 1;
  float posf = (float)pos_[t];
  __shared__ float buf[2][128];
  __shared__ float ssum[2][2];
  __shared__ float inv_sh[32];
  if (threadIdx.x < 32)
    inv_sh[threadIdx.x] = (float)pow(1000000.0, -(double)threadIdx.x/32.0);
  __syncthreads();
  for (int it=0; it<10; ++it){
    int seg = it*2 + half;
    float x = qkv[(size_t)t*QKVN + seg*128 + d] + bias[seg*128 + d];
    float p = x*x;
    #pragma unroll
    for (int o=32;o;o>>=1) p += __shfl_xor(p,o);
    if ((threadIdx.x&63)==0) ssum[half][wseg] = p;
    __syncthreads();
    float rs = rsqrtf((ssum[half][0]+ssum[half][1])*(1.f/128.f) + 1e-5f);
    float w = (seg<16) ? qnw[d] : ((seg<18) ? knw[d] : 1.f);
    float nv = x*rs*w;
    buf[half][d] = nv;
    __syncthreads();
    float outv = (seg<18) ? nv : x;
    if (seg < 18 && d < 64){
      int i = d & 31;
      float ang = posf * inv_sh[i];
      float sn, cs; sincosf(ang, &sn, &cs);
      if (d < 32) outv = nv*cs - buf[half][d+32]*sn;
      else        outv = nv*cs + buf[half][d-32]*sn;
    }
    unsigned short h_, l_; split2(outv, h_, l_);
    if (seg < 16){ size_t o = ((size_t)t*NH + seg)*HD + d; qhi[o]=h_; qlo[o]=l_; }
    else if (seg < 18){ size_t o = ((size_t)t*NKV + (seg-16))*HD + d; khi[o]=h_; klo[o]=l_; }
    else { size_t o = ((size_t)(seg-18)*HD + d)*T_ + t; vThi[o]=h_; vTlo[o]=l_; }
    __syncthreads();
  }
}

// ---- offplace: histogram + offsets + placement in one single-block kernel ----
__global__ void k_offplace(const int* __restrict__ idx4, int* __restrict__ offs,
                           int* __restrict__ rrow, int* __restrict__ tok){
  __shared__ int hist[16];
  __shared__ int hoff[16];
  __shared__ int fill[16];
  int tid = threadIdx.x;
  if (tid < 16) hist[tid] = 0;
  __syncthreads();
  for (int i = tid; i < ROWS_ALL; i += 256) tok[i] = 0;
  for (int i = tid; i < T_*4; i += 256)
    atomicAdd(&hist[idx4[i]], 1);
  __syncthreads();
  if (tid == 0){
    int o = 0;
    for (int e=0;e<16;e++){ hoff[e]=o; offs[e]=o; o += ((hist[e]+127)>>7)<<7; }
    offs[16]=o;
    offs[17]=o + T_;
  }
  if (tid < 16) fill[tid] = 0;
  __syncthreads();
  int off16 = offs[16];
  for (int t = tid; t < T_; t += 256){
    #pragma unroll
    for (int s=0;s<4;s++){
      int e = idx4[t*4+s];
      int p = atomicAdd(&fill[e],1);
      int r = hoff[e]+p;
      rrow[t*4+s]=r;
      tok[r]=t;
    }
    tok[off16+t] = t;
  }
}

__global__ void k_combine(const unsigned short* __restrict__ eout,
                          const int* __restrict__ rrow, const float* __restrict__ w4,
                          const int* __restrict__ offs, float* __restrict__ outh){
  int t = blockIdx.x;
  int rs = offs[16] + t;
  int r0=rrow[t*4+0], r1=rrow[t*4+1], r2=rrow[t*4+2], r3=rrow[t*4+3];
  float w0=w4[t*4+0], w1=w4[t*4+1], w2=w4[t*4+2], w3=w4[t*4+3];
  for (int d=threadIdx.x; d<DM; d+=256){
    float v = bf2f(eout[(size_t)rs*DM+d])
            + w0*bf2f(eout[(size_t)r0*DM+d]) + w1*bf2f(eout[(size_t)r1*DM+d])
            + w2*bf2f(eout[(size_t)r2*DM+d]) + w3*bf2f(eout[(size_t)r3*DM+d]);
    outh[(size_t)t*DM+d] = v;
  }
}

// =========================================================================
extern "C" void kernel_launch(void* const* d_in, const int* in_sizes, int n_in,
                              void* d_out, int out_size, void* d_ws, size_t ws_size,
                              hipStream_t stream){
  const int*   positions = (const int*)d_in[0];
  const float* hidden    = (const float*)d_in[1];
  const float* residual  = (const float*)d_in[2];
  const float* ln1       = (const float*)d_in[3];
  const float* ln2       = (const float*)d_in[4];
  const float* w_qkv     = (const float*)d_in[5];
  const float* b_qkv     = (const float*)d_in[6];
  const float* w_o       = (const float*)d_in[7];
  const float* qnw       = (const float*)d_in[8];
  const float* knw       = (const float*)d_in[9];
  const float* gate_w    = (const float*)d_in[10];
  const float* gate_b    = (const float*)d_in[11];
  const float* sh_wgu    = (const float*)d_in[12];
  const float* sh_wd     = (const float*)d_in[13];
  const float* e_wgu     = (const float*)d_in[14];
  const float* e_wd      = (const float*)d_in[15];
  float* out_h   = (float*)d_out;
  float* out_res = (float*)d_out + (size_t)T_*DM;

  char* ws = (char*)d_ws;
  size_t off = 0;
  auto alloc = [&](size_t b){ size_t r = off; off += (b + 255) & ~(size_t)255; return r; };

  // ---- persistent ----
  size_t o_h2b  = alloc((size_t)T_*DM*2);
  size_t o_idx  = alloc((size_t)T_*4*4);
  size_t o_w4   = alloc((size_t)T_*4*4);
  size_t o_offs = alloc(72);
  size_t o_rrow = alloc((size_t)T_*4*4);
  size_t o_tok  = alloc((size_t)ROWS_ALL*4);

  // ---- phase-union arena ----
  size_t U0 = off;
  size_t a = U0;
  auto allocA = [&](size_t b){ size_t r = a; a += (b + 255) & ~(size_t)255; return r; };
  size_t o_h1h  = allocA((size_t)T_*DM*2);
  size_t o_h1l  = allocA((size_t)T_*DM*2);
  size_t o_wqh  = allocA((size_t)QKVN*DM*2);
  size_t o_wql  = allocA((size_t)QKVN*DM*2);
  size_t o_qkvf = allocA((size_t)T_*QKVN*4);
  size_t o_qh   = allocA((size_t)T_*NH*HD*2);
  size_t o_ql   = allocA((size_t)T_*NH*HD*2);
  size_t o_kh   = allocA((size_t)T_*NKV*HD*2);
  size_t o_kl   = allocA((size_t)T_*NKV*HD*2);
  size_t o_vth  = allocA((size_t)NKV*HD*T_*2);
  size_t o_vtl  = allocA((size_t)NKV*HD*T_*2);
  size_t o_woh  = allocA((size_t)DM*DM*2);
  size_t o_wol  = allocA((size_t)DM*DM*2);
  size_t o_aoh  = allocA((size_t)T_*DM*2);
  size_t o_aol  = allocA((size_t)T_*DM*2);
  size_t o_attnP= allocA((size_t)T_*DM*4);
  size_t o_mlb  = allocA((size_t)NH*T_*4);
  size_t o_Sp   = allocA((size_t)NH*NBLK*16384*4);
  size_t o_pvp  = allocA((size_t)4*T_*DM*4);
  // phase B (MoE)
  size_t b_ = U0;
  auto allocB = [&](size_t b){ size_t r = b_; b_ += (b + 255) & ~(size_t)255; return r; };
  size_t o_ewgu = allocB((size_t)NE*2*IM*DM*2);
  size_t o_ewd  = allocB((size_t)NE*DM*IM*2);
  size_t o_shgu = allocB((size_t)2*ISH*DM*2);
  size_t o_shwd = allocB((size_t)DM*ISH*2);
  size_t o_actx = allocB((size_t)ROWS_ALL*IM*2);
  size_t o_eout = allocB((size_t)ROWS_ALL*DM*2);

  unsigned short* h2b   = (unsigned short*)(ws+o_h2b);
  int*   idx4  = (int*)(ws+o_idx);
  float* w4p   = (float*)(ws+o_w4);
  int*   offs  = (int*)(ws+o_offs);
  int*   rrow  = (int*)(ws+o_rrow);
  int*   tok   = (int*)(ws+o_tok);
  unsigned short* h1h = (unsigned short*)(ws+o_h1h);
  unsigned short* h1l = (unsigned short*)(ws+o_h1l);
  unsigned short* wqh = (unsigned short*)(ws+o_wqh);
  unsigned short* wql = (unsigned short*)(ws+o_wql);
  float*          qkvf= (float*)(ws+o_qkvf);
  unsigned short* qh  = (unsigned short*)(ws+o_qh);
  unsigned short* ql  = (unsigned short*)(ws+o_ql);
  unsigned short* kh  = (unsigned short*)(ws+o_kh);
  unsigned short* kl  = (unsigned short*)(ws+o_kl);
  unsigned short* vth = (unsigned short*)(ws+o_vth);
  unsigned short* vtl = (unsigned short*)(ws+o_vtl);
  unsigned short* woh = (unsigned short*)(ws+o_woh);
  unsigned short* wol = (unsigned short*)(ws+o_wol);
  unsigned short* aoh = (unsigned short*)(ws+o_aoh);
  unsigned short* aol = (unsigned short*)(ws+o_aol);
  float*          attnP=(float*)(ws+o_attnP);
  float*          mlb = (float*)(ws+o_mlb);
  float*          Sp  = (float*)(ws+o_Sp);
  float*          pvpart = (float*)(ws+o_pvp);
  unsigned short* ewguT=(unsigned short*)(ws+o_ewgu);
  unsigned short* ewdT = (unsigned short*)(ws+o_ewd);
  unsigned short* shguT=(unsigned short*)(ws+o_shgu);
  unsigned short* shwdT=(unsigned short*)(ws+o_shwd);
  unsigned short* actx= (unsigned short*)(ws+o_actx);
  unsigned short* eout= (unsigned short*)(ws+o_eout);

  // ---- attention phase (high precision) ----
  k_tconv2<<<dim3(QKVN/64, DM/64, 1),256,0,stream>>>(w_qkv, wqh, wql, DM, QKVN);
  k_tconv2<<<dim3(DM/64, DM/64, 1),256,0,stream>>>(w_o, woh, wol, DM, DM);

  k_add_rmsnorm<false><<<T_,256,0,stream>>>(hidden, residual, ln1, out_res, h1h, h1l, nullptr,
                                            nullptr, nullptr, nullptr, nullptr);

  k_gemm_hp<<<dim3(QKVN/128,T_/128,1),256,0,stream>>>(
      h1h, h1l, wqh, wql, qkvf, DM, DM, DM, QKVN);
  k_qkv_post_hp<<<T_,256,0,stream>>>(qkvf, b_qkv, qnw, knw, positions, qh, ql, kh, kl, vth, vtl);

  k_qk_pers<<<dim3(T_/128,NH),256,0,stream>>>(qh, ql, kh, kl, Sp);
  k_softmax_ml<<<dim3(T_,NH),256,0,stream>>>(Sp, mlb);
  k_pv_hp<<<dim3(4,T_/128,NH),256,0,stream>>>(Sp, mlb, vth, vtl, pvpart);
  k_pv_reduce<<<T_,256,0,stream>>>(pvpart, aoh, aol);
  k_gemm_hp<<<dim3(DM/128,T_/128,1),256,0,stream>>>(
      aoh, aol, woh, wol, attnP, DM, DM, DM, DM);

  // rmsnorm2 with fused MoE routing (no global atomics)
  k_add_rmsnorm<true><<<T_,256,0,stream>>>(attnP, out_res, ln2, out_res, nullptr, nullptr, h2b,
                                           gate_w, gate_b, idx4, w4p);

  k_offplace<<<1,256,0,stream>>>(idx4, offs, rrow, tok);

  // ---- weight conversion (phase A arena dead now); shared weights merged as z==16 ----
  k_tconv<true ><<<dim3(2*IM/64, DM/64, NE+1),256,0,stream>>>(
      e_wgu, ewguT, sh_wgu, shguT, DM, 2*IM, (size_t)DM*2*IM, (size_t)2*IM*DM);
  k_tconv<false><<<dim3(DM/64, IM/64, NE+1),256,0,stream>>>(
      e_wd,  ewdT,  sh_wd,  shwdT, IM, DM,   (size_t)IM*DM,   (size_t)DM*IM);

  // ---- unified grouped MLP (experts + shared); silu fused into up-GEMM epilogue ----
  k_gemm2<true, true ><<<dim3(2*IM/128, ROWS_ALL/128, 1),256,0,stream>>>(
      h2b, ewguT, shguT, actx, DM, DM, DM, IM, offs, (size_t)2*IM*DM, tok);
  k_gemm2<false, false><<<dim3(DM/128, ROWS_ALL/128, 1),256,0,stream>>>(
      actx, ewdT, shwdT, eout, IM, IM, IM, DM, offs, (size_t)DM*IM, nullptr);

  // ---- combine ----
  k_combine<<<T_,256,0,stream>>>(eout, rrow, w4p, offs, out_h);
}

// Round 19
// 700.345 us; speedup vs baseline: 1.1884x; 1.0529x over previous
//
#include <hip/hip_runtime.h>
#include <stdint.h>
#include <math.h>

#define T_ 2048
#define DM 2048
#define NH 16
#define NKV 2
#define HD 128
#define QKVN 2560
#define NE 16
#define IM 768
#define ISH 768
#define MAXROWS 10240
#define ROWS_ALL 12288   // MAXROWS + T_ (shared region appended)
#define NBLK 136         // 16*17/2 causal 128x128 blocks per head
#define SM_SCALE 0.08838834764831845f

typedef __attribute__((ext_vector_type(8))) short short8;
typedef __attribute__((ext_vector_type(4))) float f32x4;

__device__ __forceinline__ float bf2f(unsigned short u){ return __uint_as_float(((unsigned int)u)<<16); }
__device__ __forceinline__ unsigned short f2bf(float f){
  unsigned int u = __float_as_uint(f);
  return (unsigned short)((u + 0x7FFFu + ((u>>16)&1u)) >> 16);
}
__device__ __forceinline__ void split2(float x, unsigned short& hi, unsigned short& lo){
  hi = f2bf(x);
  lo = f2bf(x - bf2f(hi));
}

__device__ __forceinline__ void gload16(const void* g, void* l){
  __builtin_amdgcn_global_load_lds((const __attribute__((address_space(1))) unsigned int*)g,
                                   (__attribute__((address_space(3))) unsigned int*)l, 16, 0, 0);
}

// bijective XCD swizzle (m204)
__device__ __forceinline__ int xcd_swz(int bid, int nwg){
  int q = nwg >> 3, r = nwg & 7, x = bid & 7, p = bid >> 3;
  return (x < r ? x*(q+1) : r*(q+1) + (x-r)*q) + p;
}

#define BAR()    asm volatile("s_barrier" ::: "memory")
#define VW(N)    asm volatile("s_waitcnt vmcnt(" #N ")" ::: "memory")
#define LW0()    do{ asm volatile("s_waitcnt lgkmcnt(0)" ::: "memory"); __builtin_amdgcn_sched_barrier(0); }while(0)

// ------- transpose conv f32 -> bf16, vectorized (64x64 tile, float4 in, short8 out) ----
// ILV: g/u 8-col interleave. Last z (== gridDim.z-1) optionally reads/writes shared-weight ptrs.
template<bool ILV>
__global__ void k_tconv(const float* __restrict__ src, unsigned short* __restrict__ dst,
                        const float* __restrict__ srcS, unsigned short* __restrict__ dstS,
                        int R, int C, size_t sS, size_t sD){
  int z = blockIdx.z;
  if (srcS && z == gridDim.z-1){ src = srcS; dst = dstS; }
  else { src += (size_t)z * sS; dst += (size_t)z * sD; }
  __shared__ float tile[64*65];
  int tid = threadIdx.x;
  int r0 = blockIdx.y*64, c0 = blockIdx.x*64;
  int lr = tid>>4, lc = (tid&15)*4;
  #pragma unroll
  for (int j=0;j<4;j++){
    int row = j*16 + lr;
    float4 v = *(const float4*)&src[(size_t)(r0+row)*C + c0 + lc];
    float* t = &tile[row*65 + lc];
    t[0]=v.x; t[1]=v.y; t[2]=v.z; t[3]=v.w;
  }
  __syncthreads();
  #pragma unroll
  for (int jj=0;jj<2;jj++){
    int slot = jj*256 + tid;
    int c = slot>>3, ro = (slot&7)*8;
    int cg = c0 + c;
    int cd = cg;
    if (ILV){ int b = cg>>3, inner = cg&7; cd = (b<96 ? b*16 : (b-96)*16+8) + inner; }
    short8 o;
    #pragma unroll
    for (int k=0;k<8;k++) o[k] = (short)f2bf(tile[(ro+k)*65 + c]);
    *(short8*)&dst[(size_t)cd*R + r0 + ro] = o;
  }
}

// ------- transpose conv f32 -> bf16 hi + lo planes, vectorized; z=0 wqkv, z=1 w_o -------
__global__ void k_tconv2(const float* __restrict__ srcA, unsigned short* __restrict__ dhiA,
                         unsigned short* __restrict__ dloA,
                         const float* __restrict__ srcB, unsigned short* __restrict__ dhiB,
                         unsigned short* __restrict__ dloB){
  const float* src; unsigned short* dhi; unsigned short* dlo; int R, C;
  if (blockIdx.z == 0){ src = srcA; dhi = dhiA; dlo = dloA; R = DM; C = QKVN; }
  else {
    if (blockIdx.x >= DM/64) return;
    src = srcB; dhi = dhiB; dlo = dloB; R = DM; C = DM;
  }
  __shared__ float tile[64*65];
  int tid = threadIdx.x;
  int r0 = blockIdx.y*64, c0 = blockIdx.x*64;
  int lr = tid>>4, lc = (tid&15)*4;
  #pragma unroll
  for (int j=0;j<4;j++){
    int row = j*16 + lr;
    float4 v = *(const float4*)&src[(size_t)(r0+row)*C + c0 + lc];
    float* t = &tile[row*65 + lc];
    t[0]=v.x; t[1]=v.y; t[2]=v.z; t[3]=v.w;
  }
  __syncthreads();
  #pragma unroll
  for (int jj=0;jj<2;jj++){
    int slot = jj*256 + tid;
    int c = slot>>3, ro = (slot&7)*8;
    short8 oh, ol;
    #pragma unroll
    for (int k=0;k<8;k++){
      unsigned short h_, l_;
      split2(tile[(ro+k)*65 + c], h_, l_);
      oh[k] = (short)h_; ol[k] = (short)l_;
    }
    size_t o = (size_t)(c0+c)*R + r0 + ro;
    *(short8*)&dhi[o] = oh;
    *(short8*)&dlo[o] = ol;
  }
}

// ---------------- add + rmsnorm; ROUTE: fused MoE gate (no global atomics) ----------------
template<bool ROUTE>
__global__ void k_add_rmsnorm(const float* __restrict__ a, const float* __restrict__ b,
                              const float* __restrict__ w, float* __restrict__ resout,
                              unsigned short* __restrict__ ohi, unsigned short* __restrict__ olo,
                              unsigned short* __restrict__ obf,
                              const float* __restrict__ gw, const float* __restrict__ gbias,
                              int* __restrict__ idx4, float* __restrict__ w4){
  int t = blockIdx.x, tid = threadIdx.x;
  const float4* a4 = (const float4*)(a + (size_t)t*DM);
  const float4* b4 = (const float4*)(b + (size_t)t*DM);
  float4 va = a4[tid], vb = b4[tid];
  float4 wa = a4[tid+256], wb = b4[tid+256];
  float4 v0, v1;
  v0.x=va.x+vb.x; v0.y=va.y+vb.y; v0.z=va.z+vb.z; v0.w=va.w+vb.w;
  v1.x=wa.x+wb.x; v1.y=wa.y+wb.y; v1.z=wa.z+wb.z; v1.w=wa.w+wb.w;
  float s = v0.x*v0.x+v0.y*v0.y+v0.z*v0.z+v0.w*v0.w
          + v1.x*v1.x+v1.y*v1.y+v1.z*v1.z+v1.w*v1.w;
  #pragma unroll
  for (int o=32;o;o>>=1) s += __shfl_xor(s,o);
  __shared__ float sm[4];
  if ((tid&63)==0) sm[tid>>6]=s;
  __syncthreads();
  s = sm[0]+sm[1]+sm[2]+sm[3];
  float rs = rsqrtf(s*(1.f/(float)DM) + 1e-5f);
  ((float4*)(resout + (size_t)t*DM))[tid] = v0;
  ((float4*)(resout + (size_t)t*DM))[tid+256] = v1;
  const float4* w4p_ = (const float4*)w;
  float4 w0 = w4p_[tid], w1 = w4p_[tid+256];
  float n[8] = { v0.x*rs*w0.x, v0.y*rs*w0.y, v0.z*rs*w0.z, v0.w*rs*w0.w,
                 v1.x*rs*w1.x, v1.y*rs*w1.y, v1.z*rs*w1.z, v1.w*rs*w1.w };
  if (ohi){
    ushort4 h0,h1,l0,l1;
    split2(n[0],h0.x,l0.x); split2(n[1],h0.y,l0.y); split2(n[2],h0.z,l0.z); split2(n[3],h0.w,l0.w);
    split2(n[4],h1.x,l1.x); split2(n[5],h1.y,l1.y); split2(n[6],h1.z,l1.z); split2(n[7],h1.w,l1.w);
    ((ushort4*)(ohi + (size_t)t*DM))[tid] = h0;
    ((ushort4*)(ohi + (size_t)t*DM))[tid+256] = h1;
    ((ushort4*)(olo + (size_t)t*DM))[tid] = l0;
    ((ushort4*)(olo + (size_t)t*DM))[tid+256] = l1;
  }
  if (obf){
    ushort4 o0 = make_ushort4(f2bf(n[0]),f2bf(n[1]),f2bf(n[2]),f2bf(n[3]));
    ushort4 o1 = make_ushort4(f2bf(n[4]),f2bf(n[5]),f2bf(n[6]),f2bf(n[7]));
    ((ushort4*)(obf + (size_t)t*DM))[tid] = o0;
    ((ushort4*)(obf + (size_t)t*DM))[tid+256] = o1;
  }
  if constexpr (ROUTE){
    __shared__ float xrow[DM];          // 8 KB
    __shared__ float red[16][17];
    #pragma unroll
    for (int jj=0;jj<4;jj++) xrow[4*tid+jj] = n[jj];
    #pragma unroll
    for (int jj=0;jj<4;jj++) xrow[1024+4*tid+jj] = n[4+jj];
    __syncthreads();
    // coalesced gate GEMV: lane (grp=tid>>4, e=tid&15); gw row-major [DM][16]
    int e = tid & 15, grp = tid >> 4;
    float part = 0.f;
    #pragma unroll 8
    for (int c = grp; c < DM; c += 16)
      part += xrow[c] * gw[(size_t)c*16 + e];
    red[grp][e] = part;
    __syncthreads();
    if (tid==0){
      float sc[16], sb[16];
      for (int ee=0;ee<16;ee++){
        float lg = 0.f;
        for (int g2=0;g2<16;g2++) lg += red[g2][ee];
        sc[ee] = 1.f/(1.f+expf(-lg));
        sb[ee] = sc[ee] + gbias[ee];
      }
      float gs[4];
      for (int g=0;g<4;g++){
        float m1=-3.4e38f, m2=-3.4e38f;
        for (int j=0;j<4;j++){
          float v = sb[g*4+j];
          if (v>m1){ m2=m1; m1=v; } else if (v>m2) m2=v;
        }
        gs[g]=m1+m2;
      }
      int g1=0; for (int g=1;g<4;g++) if (gs[g]>gs[g1]) g1=g;
      int g2=-1; for (int g=0;g<4;g++){ if (g==g1) continue; if (g2<0 || gs[g]>gs[g2]) g2=g; }
      float msk[16];
      for (int ee=0;ee<16;ee++){ int g=ee>>2; msk[ee] = (g==g1||g==g2)? sb[ee] : -3.4e38f; }
      int id[4]; float wv[4]; float wsum=0.f;
      for (int s2=0;s2<4;s2++){
        int bb=0; float bv=-3.5e38f;
        for (int ee=0;ee<16;ee++) if (msk[ee]>bv){ bv=msk[ee]; bb=ee; }
        id[s2]=bb; wv[s2]=sc[bb]; wsum+=sc[bb]; msk[bb]=-3.5e38f;
      }
      float invs = 1.f/wsum;
      for (int s2=0;s2<4;s2++){
        idx4[t*4+s2]=id[s2];
        w4[t*4+s2]=wv[s2]*invs;
      }
    }
  }
}

// ------- grouped bf16 GEMM (experts + shared), BK=32 counted-vmcnt 2-deep pipeline -------
// ACT: B cols are (g,u) 8-interleaved; epilogue computes silu(g)*u -> bf16 C [rows][IM]
template<bool GATHER, bool ACT>
__global__ __launch_bounds__(256) void k_gemm2(
    const unsigned short* __restrict__ A, const unsigned short* __restrict__ Be,
    const unsigned short* __restrict__ Bsh, unsigned short* __restrict__ C,
    int K, int lda, int ldb, int ldc,
    const int* __restrict__ offs, size_t sBe, const int* __restrict__ tok){
  int nx = gridDim.x;
  int nwg = nx * gridDim.y;
  int wid_ = xcd_swz(blockIdx.x + nx*blockIdx.y, nwg);
  int tN = wid_ % nx, tM = wid_ / nx;
  int rb = tM*128;
  if (rb >= offs[17]) return;
  const unsigned short* B;
  if (rb >= offs[16]) B = Bsh;
  else {
    int e=0;
    for (; e<15; ++e) if (offs[e+1] > rb) break;
    B = Be + (size_t)e*sBe;
  }
  __shared__ __align__(16) unsigned short As[2][4096];
  __shared__ __align__(16) unsigned short Bs[2][4096];
  int tid = threadIdx.x, lane = tid & 63, wwid = tid >> 6;
  int wr = wwid >> 1, wc = wwid & 1;
  const unsigned short* Bb = B + (size_t)tN*128*ldb;

  const unsigned short* Asrc0;
  const unsigned short* Asrc1;
  int r0s = tid>>2, r1s = r0s + 64;
  {
    if (GATHER){
      Asrc0 = A + (size_t)tok[rb + r0s]*lda;
      Asrc1 = A + (size_t)tok[rb + r1s]*lda;
    } else {
      Asrc0 = A + (size_t)(rb + r0s)*lda;
      Asrc1 = A + (size_t)(rb + r1s)*lda;
    }
  }
  int kc = tid&3;
  int sw = (r0s>>1)&3;
  int kcS = (kc ^ sw)*8;

  f32x4 acc[4][4];
  #pragma unroll
  for (int m=0;m<4;m++)
    #pragma unroll
    for (int n=0;n<4;n++) acc[m][n] = (f32x4){0.f,0.f,0.f,0.f};

  auto STAGE = [&](int b, int k0){
    gload16(Asrc0 + k0 + kcS, As[b] + (size_t)tid*8);
    gload16(Asrc1 + k0 + kcS, As[b] + (size_t)(256+tid)*8);
    gload16(Bb + (size_t)r0s*ldb + k0 + kcS, Bs[b] + (size_t)tid*8);
    gload16(Bb + (size_t)r1s*ldb + k0 + kcS, Bs[b] + (size_t)(256+tid)*8);
  };

  int nt = K >> 5, L = nt - 1;
  STAGE(0, 0);
  if (L >= 1) STAGE(1, 32);
  int i15 = lane & 15, g = lane >> 4;
  for (int i=0; i<nt; ++i){
    int cur = i & 1;
    if (i < L) { VW(4); } else { VW(0); }
    BAR();
    short8 af[4], bfr[4];
    #pragma unroll
    for (int m=0;m<4;m++){
      int row = wr*64 + m*16 + i15;
      int geff = g ^ ((row>>1)&3);
      af[m] = *(const short8*)(As[cur] + row*32 + geff*8);
    }
    #pragma unroll
    for (int n=0;n<4;n++){
      int row = wc*64 + n*16 + i15;
      int geff = g ^ ((row>>1)&3);
      bfr[n] = *(const short8*)(Bs[cur] + row*32 + geff*8);
    }
    LW0();
    BAR();
    if (i + 2 <= L) STAGE(cur, (i+2)*32);
    __builtin_amdgcn_s_setprio(1);
    #pragma unroll
    for (int m=0;m<4;m++)
      #pragma unroll
      for (int n=0;n<4;n++)
        acc[m][n] = __builtin_amdgcn_mfma_f32_16x16x32_bf16(af[m], bfr[n], acc[m][n], 0,0,0);
    __builtin_amdgcn_s_setprio(0);
  }

  if (ACT){
    int rbase = rb + wr*64, cb = tN*128 + wc*64;
    #pragma unroll
    for (int m=0;m<4;m++){
      int r0 = rbase + m*16 + ((lane>>4)<<2);
      #pragma unroll
      for (int n=0;n<4;n++){
        int f = ((cb + n*16)>>1) + (lane&7);
        #pragma unroll
        for (int r=0;r<4;r++){
          float v = acc[m][n][r];
          float vp = __shfl_xor(v, 8);
          if (!(lane&8)){
            float gg = v;
            float a = gg/(1.f+__expf(-gg))*vp;
            C[(size_t)(r0+r)*ldc + f] = f2bf(a);
          }
        }
      }
    }
  } else {
    int rbase = rb + wr*64, cb = tN*128 + wc*64;
    #pragma unroll
    for (int m=0;m<4;m++){
      int r0 = rbase + m*16 + ((lane>>4)<<2);
      #pragma unroll
      for (int n=0;n<4;n++){
        int c = cb + n*16 + (lane&15);
        #pragma unroll
        for (int r=0;r<4;r++) C[(size_t)(r0+r)*ldc + c] = f2bf(acc[m][n][r]);
      }
    }
  }
}

// ---------------- high-precision bf16x3 GEMM (plain, XCD swizzle) ----
__global__ __launch_bounds__(256) void k_gemm_hp(
    const unsigned short* __restrict__ Ah, const unsigned short* __restrict__ Al,
    const unsigned short* __restrict__ Bh, const unsigned short* __restrict__ Bl,
    float* __restrict__ Cf,
    int K, int lda, int ldb, int ldc){
  int nx = gridDim.x, nwg = nx*gridDim.y;
  int w = xcd_swz(blockIdx.x + nx*blockIdx.y, nwg);
  int tN = w % nx, tM = w / nx;

  __shared__ __align__(16) unsigned short AsH[2][4096], AsL[2][4096];
  __shared__ __align__(16) unsigned short BsH[2][4096], BsL[2][4096];
  int tid = threadIdx.x, lane = tid & 63, wid = tid >> 6;
  int wr = wid >> 1, wc = wid & 1;
  const unsigned short* Abh = Ah + (size_t)tM*128*lda;
  const unsigned short* Abl = Al + (size_t)tM*128*lda;
  const unsigned short* Bbh = Bh + (size_t)tN*128*ldb;
  const unsigned short* Bbl = Bl + (size_t)tN*128*ldb;

  f32x4 acc[4][4];
  #pragma unroll
  for (int m=0;m<4;m++)
    #pragma unroll
    for (int n=0;n<4;n++) acc[m][n] = (f32x4){0.f,0.f,0.f,0.f};

  auto STAGE = [&](int b, int k0){
    #pragma unroll
    for (int j=0;j<2;j++){
      int cb = j*256 + tid;
      int row = cb>>2, kc = cb&3;
      int kcS = (kc ^ ((row>>1)&3))*8;
      size_t go = (size_t)row*lda + k0 + kcS;
      gload16(Abh + go, AsH[b] + (size_t)cb*8);
      gload16(Abl + go, AsL[b] + (size_t)cb*8);
      size_t bo = (size_t)row*ldb + k0 + kcS;
      gload16(Bbh + bo, BsH[b] + (size_t)cb*8);
      gload16(Bbl + bo, BsL[b] + (size_t)cb*8);
    }
  };

  int nt = K >> 5, L = nt - 1;
  STAGE(0, 0);
  if (L >= 1) STAGE(1, 32);
  int i15 = lane & 15, g = lane >> 4;
  for (int i=0; i<nt; ++i){
    int cur = i & 1;
    if (i < L) { VW(8); } else { VW(0); }
    BAR();
    short8 afh[4], afl[4], bfh[4], bfl[4];
    #pragma unroll
    for (int m=0;m<4;m++){
      int row = wr*64 + m*16 + i15;
      int ro = row*32 + (g ^ ((row>>1)&3))*8;
      afh[m] = *(const short8*)(AsH[cur] + ro);
      afl[m] = *(const short8*)(AsL[cur] + ro);
    }
    #pragma unroll
    for (int n=0;n<4;n++){
      int row = wc*64 + n*16 + i15;
      int ro = row*32 + (g ^ ((row>>1)&3))*8;
      bfh[n] = *(const short8*)(BsH[cur] + ro);
      bfl[n] = *(const short8*)(BsL[cur] + ro);
    }
    LW0();
    BAR();
    if (i + 2 <= L) STAGE(cur, (i+2)*32);
    __builtin_amdgcn_s_setprio(1);
    #pragma unroll
    for (int m=0;m<4;m++)
      #pragma unroll
      for (int n=0;n<4;n++){
        acc[m][n] = __builtin_amdgcn_mfma_f32_16x16x32_bf16(afh[m], bfh[n], acc[m][n], 0,0,0);
        acc[m][n] = __builtin_amdgcn_mfma_f32_16x16x32_bf16(afh[m], bfl[n], acc[m][n], 0,0,0);
        acc[m][n] = __builtin_amdgcn_mfma_f32_16x16x32_bf16(afl[m], bfh[n], acc[m][n], 0,0,0);
      }
    __builtin_amdgcn_s_setprio(0);
  }

  int rb = tM*128 + wr*64, cb = tN*128 + wc*64;
  #pragma unroll
  for (int m=0;m<4;m++){
    int r0 = rb + m*16 + ((lane>>4)<<2);
    #pragma unroll
    for (int n=0;n<4;n++){
      int c = cb + n*16 + (lane&15);
      #pragma unroll
      for (int r=0;r<4;r++) Cf[(size_t)(r0+r)*ldc + c] = acc[m][n][r];
    }
  }
}

// ------- persistent block-row QK^T (hp bf16x3): grid (tM, head) -------
__global__ __launch_bounds__(256) void k_qk_pers(
    const unsigned short* __restrict__ Qh, const unsigned short* __restrict__ Ql,
    const unsigned short* __restrict__ Kh, const unsigned short* __restrict__ Kl,
    float* __restrict__ Sp){
  int tM = blockIdx.x, z = blockIdx.y;
  int kvh = z >> 3;
  size_t tri = (size_t)tM*(tM+1)/2;
  const int ldq = NH*HD, ldk = NKV*HD;
  const unsigned short* Qbh = Qh + (size_t)(tM*128)*ldq + (size_t)z*HD;
  const unsigned short* Qbl = Ql + (size_t)(tM*128)*ldq + (size_t)z*HD;
  const unsigned short* Kbh = Kh + (size_t)kvh*HD;
  const unsigned short* Kbl = Kl + (size_t)kvh*HD;

  __shared__ __align__(16) unsigned short QsH[16384], QsL[16384];
  __shared__ __align__(16) unsigned short BsH[2][4096], BsL[2][4096];

  int tid = threadIdx.x, lane = tid & 63, wid = tid >> 6;
  int wr = wid >> 1, wc = wid & 1;
  int i15 = lane & 15, g = lane >> 4;

  #pragma unroll
  for (int j=0;j<8;j++){
    int gi = j*256 + tid;
    int chunk = gi >> 9;
    int row = (gi >> 2) & 127;
    int gg = gi & 3;
    int col = chunk*32 + (gg ^ ((row>>1)&3))*8;
    gload16(Qbh + (size_t)row*ldq + col, QsH + (size_t)gi*8);
    gload16(Qbl + (size_t)row*ldq + col, QsL + (size_t)gi*8);
  }

  auto BSTAGE = [&](int b, int ci){
    int tn = ci >> 2, c = ci & 3;
    const unsigned short* sh = Kbh + (size_t)(tn*128)*ldk;
    const unsigned short* sl = Kbl + (size_t)(tn*128)*ldk;
    #pragma unroll
    for (int j=0;j<2;j++){
      int gi = j*256 + tid;
      int row = gi >> 2, gg = gi & 3;
      int col = c*32 + (gg ^ ((row>>1)&3))*8;
      gload16(sh + (size_t)row*ldk + col, BsH[b] + (size_t)gi*8);
      gload16(sl + (size_t)row*ldk + col, BsL[b] + (size_t)gi*8);
    }
  };

  f32x4 acc[4][4];
  #pragma unroll
  for (int m=0;m<4;m++)
    #pragma unroll
    for (int n=0;n<4;n++) acc[m][n] = (f32x4){0.f,0.f,0.f,0.f};

  int NC = (tM+1)*4;
  BSTAGE(0, 0);
  BSTAGE(1, 1);
  for (int ci=0; ci<NC; ++ci){
    int cur = ci & 1, c = ci & 3, tn = ci >> 2;
    if (ci < NC-1) { VW(4); } else { VW(0); }
    BAR();
    short8 afh[4], afl[4], bfh[4], bfl[4];
    #pragma unroll
    for (int m=0;m<4;m++){
      int row = wr*64 + m*16 + i15;
      int ro = c*4096 + row*32 + (g ^ ((row>>1)&3))*8;
      afh[m] = *(const short8*)(QsH + ro);
      afl[m] = *(const short8*)(QsL + ro);
    }
    #pragma unroll
    for (int n=0;n<4;n++){
      int row = wc*64 + n*16 + i15;
      int ro = row*32 + (g ^ ((row>>1)&3))*8;
      bfh[n] = *(const short8*)(BsH[cur] + ro);
      bfl[n] = *(const short8*)(BsL[cur] + ro);
    }
    LW0();
    BAR();
    if (ci + 2 < NC) BSTAGE(cur, ci+2);
    __builtin_amdgcn_s_setprio(1);
    #pragma unroll
    for (int m=0;m<4;m++)
      #pragma unroll
      for (int n=0;n<4;n++){
        acc[m][n] = __builtin_amdgcn_mfma_f32_16x16x32_bf16(afh[m], bfh[n], acc[m][n], 0,0,0);
        acc[m][n] = __builtin_amdgcn_mfma_f32_16x16x32_bf16(afh[m], bfl[n], acc[m][n], 0,0,0);
        acc[m][n] = __builtin_amdgcn_mfma_f32_16x16x32_bf16(afl[m], bfh[n], acc[m][n], 0,0,0);
      }
    __builtin_amdgcn_s_setprio(0);
    if (c == 3){
      float* Cb = Sp + ((size_t)z*NBLK + tri + tn)*16384;
      #pragma unroll
      for (int m=0;m<4;m++){
        int r0 = wr*64 + m*16 + (g<<2);
        #pragma unroll
        for (int n=0;n<4;n++){
          int ccol = wc*64 + n*16 + i15;
          #pragma unroll
          for (int r=0;r<4;r++) Cb[(size_t)(r0+r)*128 + ccol] = acc[m][n][r];
        }
      }
      #pragma unroll
      for (int m=0;m<4;m++)
        #pragma unroll
        for (int n=0;n<4;n++) acc[m][n] = (f32x4){0.f,0.f,0.f,0.f};
    }
  }
}

// ---------------- PV split-K, unnormalized exp fused in fragment read (diag-masked) -------
// Accumulates O~ = sum exp(s*scale) * V and per-row sums; pv_reduce normalizes.
__global__ __launch_bounds__(256) void k_pv_hp(
    const float* __restrict__ Sp,
    const unsigned short* __restrict__ Vh, const unsigned short* __restrict__ Vl,
    float* __restrict__ part, float* __restrict__ rsums){
  int c = blockIdx.x, tM = blockIdx.y, z = blockIdx.z;
  int kbeg = c*512;
  int kend = min((tM+1)*128, (c+1)*512);
  if (kbeg >= kend) return;
  int tMk = tM*128;
  size_t tri = (size_t)tM*(tM+1)/2;
  const float* Ab = Sp + ((size_t)z*NBLK + tri)*16384;
  const unsigned short* Bbh = Vh + (size_t)(z>>3)*HD*T_;
  const unsigned short* Bbl = Vl + (size_t)(z>>3)*HD*T_;

  __shared__ __align__(16) float Asf[2][4096];
  __shared__ __align__(16) unsigned short BsH[2][4096], BsL[2][4096];
  int tid = threadIdx.x, lane = tid & 63, wid = tid >> 6;
  int wr = wid >> 1, wc = wid & 1;
  int i15 = lane & 15, g2 = (lane>>4)*2;

  int r0s = tid>>2, r1s = r0s + 64;
  int kcB = ((tid&3) ^ ((r0s>>1)&3))*8;
  int rowA = tid>>3, gA = tid&7;

  f32x4 acc[4][4];
  #pragma unroll
  for (int m=0;m<4;m++)
    #pragma unroll
    for (int n=0;n<4;n++) acc[m][n] = (f32x4){0.f,0.f,0.f,0.f};
  float rsum[4] = {0.f,0.f,0.f,0.f};

  auto STAGE = [&](int b, int k0){
    #pragma unroll
    for (int j=0;j<4;j++){
      int r = j*32 + rowA;
      int gS = gA ^ (r & 7);
      size_t ga = (size_t)(k0>>7)*16384 + (size_t)r*128 + (k0&127) + gS*4;
      gload16(Ab + ga, Asf[b] + ((size_t)j*256 + tid)*4);
    }
    size_t bo0 = (size_t)r0s*T_ + k0 + kcB;
    size_t bo1 = (size_t)r1s*T_ + k0 + kcB;
    gload16(Bbh + bo0, BsH[b] + (size_t)tid*8);
    gload16(Bbh + bo1, BsH[b] + (size_t)(256+tid)*8);
    gload16(Bbl + bo0, BsL[b] + (size_t)tid*8);
    gload16(Bbl + bo1, BsL[b] + (size_t)(256+tid)*8);
  };

  int nt = (kend - kbeg) >> 5, L = nt - 1;
  STAGE(0, kbeg);
  if (L >= 1) STAGE(1, kbeg + 32);
  for (int i=0; i<nt; ++i){
    int cur = i & 1;
    int k0 = kbeg + i*32;
    if (i < L) { VW(8); } else { VW(0); }
    BAR();
    int diag = (k0 >= tMk);
    short8 afh[4], afl[4], bfh[4], bfl[4];
    #pragma unroll
    for (int m=0;m<4;m++){
      int r = wr*64 + m*16 + i15;
      int s0 = r*8 + ((g2  ) ^ (r&7));
      int s1 = r*8 + ((g2+1) ^ (r&7));
      f32x4 a0 = *(const f32x4*)(Asf[cur] + s0*4);
      f32x4 a1 = *(const f32x4*)(Asf[cur] + s1*4);
      float pv[8] = {a0[0],a0[1],a0[2],a0[3],a1[0],a1[1],a1[2],a1[3]};
      if (diag){
        int kb = k0 & 127;
        #pragma unroll
        for (int j=0;j<8;j++){
          int kl = kb + ((j<4) ? g2*4 + j : (g2+1)*4 + (j-4));
          if (kl > r) pv[j] = -3.0e38f;
        }
      }
      short8 h8, l8;
      #pragma unroll
      for (int j=0;j<8;j++){
        float p = __expf(pv[j]*SM_SCALE);
        rsum[m] += p;
        unsigned short hh, ll; split2(p, hh, ll);
        h8[j] = (short)hh; l8[j] = (short)ll;
      }
      afh[m] = h8; afl[m] = l8;
    }
    #pragma unroll
    for (int n=0;n<4;n++){
      int row = wc*64 + n*16 + i15;
      int ro = row*32 + ((lane>>4) ^ ((row>>1)&3))*8;
      bfh[n] = *(const short8*)(BsH[cur] + ro);
      bfl[n] = *(const short8*)(BsL[cur] + ro);
    }
    LW0();
    BAR();
    if (i + 2 <= L) STAGE(cur, kbeg + (i+2)*32);
    __builtin_amdgcn_s_setprio(1);
    #pragma unroll
    for (int m=0;m<4;m++)
      #pragma unroll
      for (int n=0;n<4;n++){
        acc[m][n] = __builtin_amdgcn_mfma_f32_16x16x32_bf16(afh[m], bfh[n], acc[m][n], 0,0,0);
        acc[m][n] = __builtin_amdgcn_mfma_f32_16x16x32_bf16(afh[m], bfl[n], acc[m][n], 0,0,0);
        acc[m][n] = __builtin_amdgcn_mfma_f32_16x16x32_bf16(afl[m], bfh[n], acc[m][n], 0,0,0);
      }
    __builtin_amdgcn_s_setprio(0);
  }

  // per-row sum of exp over this chunk: reduce across the 4 lanes (lane bits 4-5)
  #pragma unroll
  for (int m=0;m<4;m++){
    float v = rsum[m];
    v += __shfl_xor(v, 16);
    v += __shfl_xor(v, 32);
    if ((lane>>4)==0 && wc==0)
      rsums[((size_t)c*NH + z)*T_ + tMk + wr*64 + m*16 + i15] = v;
  }

  float* Cb = part + (size_t)c*T_*DM + (size_t)tMk*DM + (size_t)z*HD;
  #pragma unroll
  for (int m=0;m<4;m++){
    int r0 = wr*64 + m*16 + ((lane>>4)<<2);
    #pragma unroll
    for (int n=0;n<4;n++){
      int ccol = wc*64 + n*16 + (lane&15);
      #pragma unroll
      for (int r=0;r<4;r++) Cb[(size_t)(r0+r)*DM + ccol] = acc[m][n][r];
    }
  }
}

// reduce partials, normalize by row sums -> aoh/aol (bf16 hi/lo)
__global__ void k_pv_reduce(const float* __restrict__ part, const float* __restrict__ rsums,
                            unsigned short* __restrict__ aoh, unsigned short* __restrict__ aol){
  int t = blockIdx.x, tid = threadIdx.x;
  int nc = ((t>>7) + 4) >> 2;
  #pragma unroll
  for (int half=0; half<2; ++half){
    int idx = tid + half*256;
    int z = idx >> 5;                      // float4 index -> head (idx*4 >> 7)
    float tot = 0.f;
    for (int c=0; c<nc; ++c) tot += rsums[((size_t)c*NH + z)*T_ + t];
    float inv = 1.f / tot;
    float4 s = ((const float4*)(part + (size_t)t*DM))[idx];
    for (int c=1; c<nc; ++c){
      float4 v = ((const float4*)(part + (size_t)c*T_*DM + (size_t)t*DM))[idx];
      s.x+=v.x; s.y+=v.y; s.z+=v.z; s.w+=v.w;
    }
    s.x*=inv; s.y*=inv; s.z*=inv; s.w*=inv;
    ushort4 h_, l_;
    split2(s.x,h_.x,l_.x); split2(s.y,h_.y,l_.y); split2(s.z,h_.z,l_.z); split2(s.w,h_.w,l_.w);
    ((ushort4*)(aoh + (size_t)t*DM))[idx] = h_;
    ((ushort4*)(aol + (size_t)t*DM))[idx] = l_;
  }
}

// ---------------- qkv post ----------------
__global__ void k_qkv_post_hp(const float* __restrict__ qkv, const float* __restrict__ bias,
                              const float* __restrict__ qnw, const float* __restrict__ knw,
                              const int* __restrict__ pos_,
                              unsigned short* __restrict__ qhi, unsigned short* __restrict__ qlo,
                              unsigned short* __restrict__ khi, unsigned short* __restrict__ klo,
                              unsigned short* __restrict__ vThi, unsigned short* __restrict__ vTlo){
  int t = blockIdx.x;
  int half = threadIdx.x >> 7;
  int d = threadIdx.x & 127;
  int wseg = (threadIdx.x >> 6) & 1;
  float posf = (float)pos_[t];
  __shared__ float buf[2][128];
  __shared__ float ssum[2][2];
  __shared__ float inv_sh[32];
  if (threadIdx.x < 32)
    inv_sh[threadIdx.x] = (float)pow(1000000.0, -(double)threadIdx.x/32.0);
  __syncthreads();
  for (int it=0; it<10; ++it){
    int seg = it*2 + half;
    float x = qkv[(size_t)t*QKVN + seg*128 + d] + bias[seg*128 + d];
    float p = x*x;
    #pragma unroll
    for (int o=32;o;o>>=1) p += __shfl_xor(p,o);
    if ((threadIdx.x&63)==0) ssum[half][wseg] = p;
    __syncthreads();
    float rs = rsqrtf((ssum[half][0]+ssum[half][1])*(1.f/128.f) + 1e-5f);
    float w = (seg<16) ? qnw[d] : ((seg<18) ? knw[d] : 1.f);
    float nv = x*rs*w;
    buf[half][d] = nv;
    __syncthreads();
    float outv = (seg<18) ? nv : x;
    if (seg < 18 && d < 64){
      int i = d & 31;
      float ang = posf * inv_sh[i];
      float sn, cs; sincosf(ang, &sn, &cs);
      if (d < 32) outv = nv*cs - buf[half][d+32]*sn;
      else        outv = nv*cs + buf[half][d-32]*sn;
    }
    unsigned short h_, l_; split2(outv, h_, l_);
    if (seg < 16){ size_t o = ((size_t)t*NH + seg)*HD + d; qhi[o]=h_; qlo[o]=l_; }
    else if (seg < 18){ size_t o = ((size_t)t*NKV + (seg-16))*HD + d; khi[o]=h_; klo[o]=l_; }
    else { size_t o = ((size_t)(seg-18)*HD + d)*T_ + t; vThi[o]=h_; vTlo[o]=l_; }
    __syncthreads();
  }
}

// ---- offplace: histogram + offsets + placement in one single-block kernel ----
__global__ void k_offplace(const int* __restrict__ idx4, int* __restrict__ offs,
                           int* __restrict__ rrow, int* __restrict__ tok){
  __shared__ int hist[16];
  __shared__ int hoff[16];
  __shared__ int fill[16];
  int tid = threadIdx.x;
  if (tid < 16) hist[tid] = 0;
  __syncthreads();
  for (int i = tid; i < ROWS_ALL; i += 256) tok[i] = 0;
  for (int i = tid; i < T_*4; i += 256)
    atomicAdd(&hist[idx4[i]], 1);
  __syncthreads();
  if (tid == 0){
    int o = 0;
    for (int e=0;e<16;e++){ hoff[e]=o; offs[e]=o; o += ((hist[e]+127)>>7)<<7; }
    offs[16]=o;
    offs[17]=o + T_;
  }
  if (tid < 16) fill[tid] = 0;
  __syncthreads();
  int off16 = offs[16];
  for (int t = tid; t < T_; t += 256){
    #pragma unroll
    for (int s=0;s<4;s++){
      int e = idx4[t*4+s];
      int p = atomicAdd(&fill[e],1);
      int r = hoff[e]+p;
      rrow[t*4+s]=r;
      tok[r]=t;
    }
    tok[off16+t] = t;
  }
}

__global__ void k_combine(const unsigned short* __restrict__ eout,
                          const int* __restrict__ rrow, const float* __restrict__ w4,
                          const int* __restrict__ offs, float* __restrict__ outh){
  int t = blockIdx.x;
  int rs = offs[16] + t;
  int r0=rrow[t*4+0], r1=rrow[t*4+1], r2=rrow[t*4+2], r3=rrow[t*4+3];
  float w0=w4[t*4+0], w1=w4[t*4+1], w2=w4[t*4+2], w3=w4[t*4+3];
  for (int d=threadIdx.x; d<DM; d+=256){
    float v = bf2f(eout[(size_t)rs*DM+d])
            + w0*bf2f(eout[(size_t)r0*DM+d]) + w1*bf2f(eout[(size_t)r1*DM+d])
            + w2*bf2f(eout[(size_t)r2*DM+d]) + w3*bf2f(eout[(size_t)r3*DM+d]);
    outh[(size_t)t*DM+d] = v;
  }
}

// =========================================================================
extern "C" void kernel_launch(void* const* d_in, const int* in_sizes, int n_in,
                              void* d_out, int out_size, void* d_ws, size_t ws_size,
                              hipStream_t stream){
  const int*   positions = (const int*)d_in[0];
  const float* hidden    = (const float*)d_in[1];
  const float* residual  = (const float*)d_in[2];
  const float* ln1       = (const float*)d_in[3];
  const float* ln2       = (const float*)d_in[4];
  const float* w_qkv     = (const float*)d_in[5];
  const float* b_qkv     = (const float*)d_in[6];
  const float* w_o       = (const float*)d_in[7];
  const float* qnw       = (const float*)d_in[8];
  const float* knw       = (const float*)d_in[9];
  const float* gate_w    = (const float*)d_in[10];
  const float* gate_b    = (const float*)d_in[11];
  const float* sh_wgu    = (const float*)d_in[12];
  const float* sh_wd     = (const float*)d_in[13];
  const float* e_wgu     = (const float*)d_in[14];
  const float* e_wd      = (const float*)d_in[15];
  float* out_h   = (float*)d_out;
  float* out_res = (float*)d_out + (size_t)T_*DM;

  char* ws = (char*)d_ws;
  size_t off = 0;
  auto alloc = [&](size_t b){ size_t r = off; off += (b + 255) & ~(size_t)255; return r; };

  // ---- persistent ----
  size_t o_h2b  = alloc((size_t)T_*DM*2);
  size_t o_idx  = alloc((size_t)T_*4*4);
  size_t o_w4   = alloc((size_t)T_*4*4);
  size_t o_offs = alloc(72);
  size_t o_rrow = alloc((size_t)T_*4*4);
  size_t o_tok  = alloc((size_t)ROWS_ALL*4);

  // ---- phase-union arena ----
  size_t U0 = off;
  size_t a = U0;
  auto allocA = [&](size_t b){ size_t r = a; a += (b + 255) & ~(size_t)255; return r; };
  size_t o_h1h  = allocA((size_t)T_*DM*2);
  size_t o_h1l  = allocA((size_t)T_*DM*2);
  size_t o_wqh  = allocA((size_t)QKVN*DM*2);
  size_t o_wql  = allocA((size_t)QKVN*DM*2);
  size_t o_qkvf = allocA((size_t)T_*QKVN*4);
  size_t o_qh   = allocA((size_t)T_*NH*HD*2);
  size_t o_ql   = allocA((size_t)T_*NH*HD*2);
  size_t o_kh   = allocA((size_t)T_*NKV*HD*2);
  size_t o_kl   = allocA((size_t)T_*NKV*HD*2);
  size_t o_vth  = allocA((size_t)NKV*HD*T_*2);
  size_t o_vtl  = allocA((size_t)NKV*HD*T_*2);
  size_t o_woh  = allocA((size_t)DM*DM*2);
  size_t o_wol  = allocA((size_t)DM*DM*2);
  size_t o_aoh  = allocA((size_t)T_*DM*2);
  size_t o_aol  = allocA((size_t)T_*DM*2);
  size_t o_attnP= allocA((size_t)T_*DM*4);
  size_t o_rsum = allocA((size_t)4*NH*T_*4);
  size_t o_Sp   = allocA((size_t)NH*NBLK*16384*4);
  size_t o_pvp  = allocA((size_t)4*T_*DM*4);
  // phase B (MoE)
  size_t b_ = U0;
  auto allocB = [&](size_t b){ size_t r = b_; b_ += (b + 255) & ~(size_t)255; return r; };
  size_t o_ewgu = allocB((size_t)NE*2*IM*DM*2);
  size_t o_ewd  = allocB((size_t)NE*DM*IM*2);
  size_t o_shgu = allocB((size_t)2*ISH*DM*2);
  size_t o_shwd = allocB((size_t)DM*ISH*2);
  size_t o_actx = allocB((size_t)ROWS_ALL*IM*2);
  size_t o_eout = allocB((size_t)ROWS_ALL*DM*2);

  unsigned short* h2b   = (unsigned short*)(ws+o_h2b);
  int*   idx4  = (int*)(ws+o_idx);
  float* w4p   = (float*)(ws+o_w4);
  int*   offs  = (int*)(ws+o_offs);
  int*   rrow  = (int*)(ws+o_rrow);
  int*   tok   = (int*)(ws+o_tok);
  unsigned short* h1h = (unsigned short*)(ws+o_h1h);
  unsigned short* h1l = (unsigned short*)(ws+o_h1l);
  unsigned short* wqh = (unsigned short*)(ws+o_wqh);
  unsigned short* wql = (unsigned short*)(ws+o_wql);
  float*          qkvf= (float*)(ws+o_qkvf);
  unsigned short* qh  = (unsigned short*)(ws+o_qh);
  unsigned short* ql  = (unsigned short*)(ws+o_ql);
  unsigned short* kh  = (unsigned short*)(ws+o_kh);
  unsigned short* kl  = (unsigned short*)(ws+o_kl);
  unsigned short* vth = (unsigned short*)(ws+o_vth);
  unsigned short* vtl = (unsigned short*)(ws+o_vtl);
  unsigned short* woh = (unsigned short*)(ws+o_woh);
  unsigned short* wol = (unsigned short*)(ws+o_wol);
  unsigned short* aoh = (unsigned short*)(ws+o_aoh);
  unsigned short* aol = (unsigned short*)(ws+o_aol);
  float*          attnP=(float*)(ws+o_attnP);
  float*          rsums=(float*)(ws+o_rsum);
  float*          Sp  = (float*)(ws+o_Sp);
  float*          pvpart = (float*)(ws+o_pvp);
  unsigned short* ewguT=(unsigned short*)(ws+o_ewgu);
  unsigned short* ewdT = (unsigned short*)(ws+o_ewd);
  unsigned short* shguT=(unsigned short*)(ws+o_shgu);
  unsigned short* shwdT=(unsigned short*)(ws+o_shwd);
  unsigned short* actx= (unsigned short*)(ws+o_actx);
  unsigned short* eout= (unsigned short*)(ws+o_eout);

  // ---- attention phase (high precision) ----
  k_tconv2<<<dim3(QKVN/64, DM/64, 2),256,0,stream>>>(w_qkv, wqh, wql, w_o, woh, wol);

  k_add_rmsnorm<false><<<T_,256,0,stream>>>(hidden, residual, ln1, out_res, h1h, h1l, nullptr,
                                            nullptr, nullptr, nullptr, nullptr);

  k_gemm_hp<<<dim3(QKVN/128,T_/128,1),256,0,stream>>>(
      h1h, h1l, wqh, wql, qkvf, DM, DM, DM, QKVN);
  k_qkv_post_hp<<<T_,256,0,stream>>>(qkvf, b_qkv, qnw, knw, positions, qh, ql, kh, kl, vth, vtl);

  k_qk_pers<<<dim3(T_/128,NH),256,0,stream>>>(qh, ql, kh, kl, Sp);
  k_pv_hp<<<dim3(4,T_/128,NH),256,0,stream>>>(Sp, vth, vtl, pvpart, rsums);
  k_pv_reduce<<<T_,256,0,stream>>>(pvpart, rsums, aoh, aol);
  k_gemm_hp<<<dim3(DM/128,T_/128,1),256,0,stream>>>(
      aoh, aol, woh, wol, attnP, DM, DM, DM, DM);

  // rmsnorm2 with fused MoE routing (no global atomics)
  k_add_rmsnorm<true><<<T_,256,0,stream>>>(attnP, out_res, ln2, out_res, nullptr, nullptr, h2b,
                                           gate_w, gate_b, idx4, w4p);

  k_offplace<<<1,256,0,stream>>>(idx4, offs, rrow, tok);

  // ---- weight conversion (phase A arena dead now); shared weights merged as z==16 ----
  k_tconv<true ><<<dim3(2*IM/64, DM/64, NE+1),256,0,stream>>>(
      e_wgu, ewguT, sh_wgu, shguT, DM, 2*IM, (size_t)DM*2*IM, (size_t)2*IM*DM);
  k_tconv<false><<<dim3(DM/64, IM/64, NE+1),256,0,stream>>>(
      e_wd,  ewdT,  sh_wd,  shwdT, IM, DM,   (size_t)IM*DM,   (size_t)DM*IM);

  // ---- unified grouped MLP (experts + shared); silu fused into up-GEMM epilogue ----
  k_gemm2<true, true ><<<dim3(2*IM/128, ROWS_ALL/128, 1),256,0,stream>>>(
      h2b, ewguT, shguT, actx, DM, DM, DM, IM, offs, (size_t)2*IM*DM, tok);
  k_gemm2<false, false><<<dim3(DM/128, ROWS_ALL/128, 1),256,0,stream>>>(
      actx, ewdT, shwdT, eout, IM, IM, IM, DM, offs, (size_t)DM*IM, nullptr);

  // ---- combine ----
  k_combine<<<T_,256,0,stream>>>(eout, rrow, w4p, offs, out_h);
}

// Round 20
// 664.449 us; speedup vs baseline: 1.2526x; 1.0540x over previous
//
#include <hip/hip_runtime.h>
#include <stdint.h>
#include <math.h>

#define T_ 2048
#define DM 2048
#define NH 16
#define NKV 2
#define HD 128
#define QKVN 2560
#define NE 16
#define IM 768
#define ISH 768
#define MAXROWS 10240
#define ROWS_ALL 12288   // MAXROWS + T_ (shared region appended)
#define NBLK 136         // 16*17/2 causal 128x128 blocks per head
#define SM_SCALE 0.08838834764831845f

typedef __attribute__((ext_vector_type(8))) short short8;
typedef __attribute__((ext_vector_type(4))) float f32x4;

__device__ __forceinline__ float bf2f(unsigned short u){ return __uint_as_float(((unsigned int)u)<<16); }
__device__ __forceinline__ unsigned short f2bf(float f){
  unsigned int u = __float_as_uint(f);
  return (unsigned short)((u + 0x7FFFu + ((u>>16)&1u)) >> 16);
}
__device__ __forceinline__ void split2(float x, unsigned short& hi, unsigned short& lo){
  hi = f2bf(x);
  lo = f2bf(x - bf2f(hi));
}

__device__ __forceinline__ void gload16(const void* g, void* l){
  __builtin_amdgcn_global_load_lds((const __attribute__((address_space(1))) unsigned int*)g,
                                   (__attribute__((address_space(3))) unsigned int*)l, 16, 0, 0);
}

// bijective XCD swizzle (m204)
__device__ __forceinline__ int xcd_swz(int bid, int nwg){
  int q = nwg >> 3, r = nwg & 7, x = bid & 7, p = bid >> 3;
  return (x < r ? x*(q+1) : r*(q+1) + (x-r)*q) + p;
}

#define BAR()    asm volatile("s_barrier" ::: "memory")
#define VW(N)    asm volatile("s_waitcnt vmcnt(" #N ")" ::: "memory")
#define LW0()    do{ asm volatile("s_waitcnt lgkmcnt(0)" ::: "memory"); __builtin_amdgcn_sched_barrier(0); }while(0)

// ------- transpose conv f32 -> bf16, vectorized (64x64 tile, float4 in, short8 out) ----
// ILV: g/u 8-col interleave. Last z (== gridDim.z-1) optionally reads/writes shared-weight ptrs.
template<bool ILV>
__global__ void k_tconv(const float* __restrict__ src, unsigned short* __restrict__ dst,
                        const float* __restrict__ srcS, unsigned short* __restrict__ dstS,
                        int R, int C, size_t sS, size_t sD){
  int z = blockIdx.z;
  if (srcS && z == gridDim.z-1){ src = srcS; dst = dstS; }
  else { src += (size_t)z * sS; dst += (size_t)z * sD; }
  __shared__ float tile[64*65];
  int tid = threadIdx.x;
  int r0 = blockIdx.y*64, c0 = blockIdx.x*64;
  int lr = tid>>4, lc = (tid&15)*4;
  #pragma unroll
  for (int j=0;j<4;j++){
    int row = j*16 + lr;
    float4 v = *(const float4*)&src[(size_t)(r0+row)*C + c0 + lc];
    float* t = &tile[row*65 + lc];
    t[0]=v.x; t[1]=v.y; t[2]=v.z; t[3]=v.w;
  }
  __syncthreads();
  #pragma unroll
  for (int jj=0;jj<2;jj++){
    int slot = jj*256 + tid;
    int c = slot>>3, ro = (slot&7)*8;
    int cg = c0 + c;
    int cd = cg;
    if (ILV){ int b = cg>>3, inner = cg&7; cd = (b<96 ? b*16 : (b-96)*16+8) + inner; }
    short8 o;
    #pragma unroll
    for (int k=0;k<8;k++) o[k] = (short)f2bf(tile[(ro+k)*65 + c]);
    *(short8*)&dst[(size_t)cd*R + r0 + ro] = o;
  }
}

// ------- transpose conv f32 -> bf16 hi + lo planes, vectorized; z=0 wqkv, z=1 w_o -------
__global__ void k_tconv2(const float* __restrict__ srcA, unsigned short* __restrict__ dhiA,
                         unsigned short* __restrict__ dloA,
                         const float* __restrict__ srcB, unsigned short* __restrict__ dhiB,
                         unsigned short* __restrict__ dloB){
  const float* src; unsigned short* dhi; unsigned short* dlo; int R, C;
  if (blockIdx.z == 0){ src = srcA; dhi = dhiA; dlo = dloA; R = DM; C = QKVN; }
  else {
    if (blockIdx.x >= DM/64) return;
    src = srcB; dhi = dhiB; dlo = dloB; R = DM; C = DM;
  }
  __shared__ float tile[64*65];
  int tid = threadIdx.x;
  int r0 = blockIdx.y*64, c0 = blockIdx.x*64;
  int lr = tid>>4, lc = (tid&15)*4;
  #pragma unroll
  for (int j=0;j<4;j++){
    int row = j*16 + lr;
    float4 v = *(const float4*)&src[(size_t)(r0+row)*C + c0 + lc];
    float* t = &tile[row*65 + lc];
    t[0]=v.x; t[1]=v.y; t[2]=v.z; t[3]=v.w;
  }
  __syncthreads();
  #pragma unroll
  for (int jj=0;jj<2;jj++){
    int slot = jj*256 + tid;
    int c = slot>>3, ro = (slot&7)*8;
    short8 oh, ol;
    #pragma unroll
    for (int k=0;k<8;k++){
      unsigned short h_, l_;
      split2(tile[(ro+k)*65 + c], h_, l_);
      oh[k] = (short)h_; ol[k] = (short)l_;
    }
    size_t o = (size_t)(c0+c)*R + r0 + ro;
    *(short8*)&dhi[o] = oh;
    *(short8*)&dlo[o] = ol;
  }
}

// ---------------- add + rmsnorm; ROUTE: fused MoE gate (no global atomics) ----------------
template<bool ROUTE>
__global__ void k_add_rmsnorm(const float* __restrict__ a, const float* __restrict__ b,
                              const float* __restrict__ w, float* __restrict__ resout,
                              unsigned short* __restrict__ ohi, unsigned short* __restrict__ olo,
                              unsigned short* __restrict__ obf,
                              const float* __restrict__ gw, const float* __restrict__ gbias,
                              int* __restrict__ idx4, float* __restrict__ w4){
  int t = blockIdx.x, tid = threadIdx.x;
  const float4* a4 = (const float4*)(a + (size_t)t*DM);
  const float4* b4 = (const float4*)(b + (size_t)t*DM);
  float4 va = a4[tid], vb = b4[tid];
  float4 wa = a4[tid+256], wb = b4[tid+256];
  float4 v0, v1;
  v0.x=va.x+vb.x; v0.y=va.y+vb.y; v0.z=va.z+vb.z; v0.w=va.w+vb.w;
  v1.x=wa.x+wb.x; v1.y=wa.y+wb.y; v1.z=wa.z+wb.z; v1.w=wa.w+wb.w;
  float s = v0.x*v0.x+v0.y*v0.y+v0.z*v0.z+v0.w*v0.w
          + v1.x*v1.x+v1.y*v1.y+v1.z*v1.z+v1.w*v1.w;
  #pragma unroll
  for (int o=32;o;o>>=1) s += __shfl_xor(s,o);
  __shared__ float sm[4];
  if ((tid&63)==0) sm[tid>>6]=s;
  __syncthreads();
  s = sm[0]+sm[1]+sm[2]+sm[3];
  float rs = rsqrtf(s*(1.f/(float)DM) + 1e-5f);
  ((float4*)(resout + (size_t)t*DM))[tid] = v0;
  ((float4*)(resout + (size_t)t*DM))[tid+256] = v1;
  const float4* w4p_ = (const float4*)w;
  float4 w0 = w4p_[tid], w1 = w4p_[tid+256];
  float n[8] = { v0.x*rs*w0.x, v0.y*rs*w0.y, v0.z*rs*w0.z, v0.w*rs*w0.w,
                 v1.x*rs*w1.x, v1.y*rs*w1.y, v1.z*rs*w1.z, v1.w*rs*w1.w };
  if (ohi){
    ushort4 h0,h1,l0,l1;
    split2(n[0],h0.x,l0.x); split2(n[1],h0.y,l0.y); split2(n[2],h0.z,l0.z); split2(n[3],h0.w,l0.w);
    split2(n[4],h1.x,l1.x); split2(n[5],h1.y,l1.y); split2(n[6],h1.z,l1.z); split2(n[7],h1.w,l1.w);
    ((ushort4*)(ohi + (size_t)t*DM))[tid] = h0;
    ((ushort4*)(ohi + (size_t)t*DM))[tid+256] = h1;
    ((ushort4*)(olo + (size_t)t*DM))[tid] = l0;
    ((ushort4*)(olo + (size_t)t*DM))[tid+256] = l1;
  }
  if (obf){
    ushort4 o0 = make_ushort4(f2bf(n[0]),f2bf(n[1]),f2bf(n[2]),f2bf(n[3]));
    ushort4 o1 = make_ushort4(f2bf(n[4]),f2bf(n[5]),f2bf(n[6]),f2bf(n[7]));
    ((ushort4*)(obf + (size_t)t*DM))[tid] = o0;
    ((ushort4*)(obf + (size_t)t*DM))[tid+256] = o1;
  }
  if constexpr (ROUTE){
    __shared__ float xrow[DM];          // 8 KB
    __shared__ float red[16][17];
    #pragma unroll
    for (int jj=0;jj<4;jj++) xrow[4*tid+jj] = n[jj];
    #pragma unroll
    for (int jj=0;jj<4;jj++) xrow[1024+4*tid+jj] = n[4+jj];
    __syncthreads();
    // coalesced gate GEMV: lane (grp=tid>>4, e=tid&15); gw row-major [DM][16]
    int e = tid & 15, grp = tid >> 4;
    float part = 0.f;
    #pragma unroll 8
    for (int c = grp; c < DM; c += 16)
      part += xrow[c] * gw[(size_t)c*16 + e];
    red[grp][e] = part;
    __syncthreads();
    if (tid==0){
      float sc[16], sb[16];
      for (int ee=0;ee<16;ee++){
        float lg = 0.f;
        for (int g2=0;g2<16;g2++) lg += red[g2][ee];
        sc[ee] = 1.f/(1.f+expf(-lg));
        sb[ee] = sc[ee] + gbias[ee];
      }
      float gs[4];
      for (int g=0;g<4;g++){
        float m1=-3.4e38f, m2=-3.4e38f;
        for (int j=0;j<4;j++){
          float v = sb[g*4+j];
          if (v>m1){ m2=m1; m1=v; } else if (v>m2) m2=v;
        }
        gs[g]=m1+m2;
      }
      int g1=0; for (int g=1;g<4;g++) if (gs[g]>gs[g1]) g1=g;
      int g2=-1; for (int g=0;g<4;g++){ if (g==g1) continue; if (g2<0 || gs[g]>gs[g2]) g2=g; }
      float msk[16];
      for (int ee=0;ee<16;ee++){ int g=ee>>2; msk[ee] = (g==g1||g==g2)? sb[ee] : -3.4e38f; }
      int id[4]; float wv[4]; float wsum=0.f;
      for (int s2=0;s2<4;s2++){
        int bb=0; float bv=-3.5e38f;
        for (int ee=0;ee<16;ee++) if (msk[ee]>bv){ bv=msk[ee]; bb=ee; }
        id[s2]=bb; wv[s2]=sc[bb]; wsum+=sc[bb]; msk[bb]=-3.5e38f;
      }
      float invs = 1.f/wsum;
      for (int s2=0;s2<4;s2++){
        idx4[t*4+s2]=id[s2];
        w4[t*4+s2]=wv[s2]*invs;
      }
    }
  }
}

// ------- grouped bf16 GEMM (experts + shared), BK=32 counted-vmcnt 2-deep pipeline -------
// ACT: B cols are (g,u) 8-interleaved; epilogue computes silu(g)*u -> bf16 C [rows][IM]
template<bool GATHER, bool ACT>
__global__ __launch_bounds__(256) void k_gemm2(
    const unsigned short* __restrict__ A, const unsigned short* __restrict__ Be,
    const unsigned short* __restrict__ Bsh, unsigned short* __restrict__ C,
    int K, int lda, int ldb, int ldc,
    const int* __restrict__ offs, size_t sBe, const int* __restrict__ tok){
  int nx = gridDim.x;
  int nwg = nx * gridDim.y;
  int wid_ = xcd_swz(blockIdx.x + nx*blockIdx.y, nwg);
  int tN = wid_ % nx, tM = wid_ / nx;
  int rb = tM*128;
  if (rb >= offs[17]) return;
  const unsigned short* B;
  if (rb >= offs[16]) B = Bsh;
  else {
    int e=0;
    for (; e<15; ++e) if (offs[e+1] > rb) break;
    B = Be + (size_t)e*sBe;
  }
  __shared__ __align__(16) unsigned short As[2][4096];
  __shared__ __align__(16) unsigned short Bs[2][4096];
  int tid = threadIdx.x, lane = tid & 63, wwid = tid >> 6;
  int wr = wwid >> 1, wc = wwid & 1;
  const unsigned short* Bb = B + (size_t)tN*128*ldb;

  const unsigned short* Asrc0;
  const unsigned short* Asrc1;
  int r0s = tid>>2, r1s = r0s + 64;
  {
    if (GATHER){
      Asrc0 = A + (size_t)tok[rb + r0s]*lda;
      Asrc1 = A + (size_t)tok[rb + r1s]*lda;
    } else {
      Asrc0 = A + (size_t)(rb + r0s)*lda;
      Asrc1 = A + (size_t)(rb + r1s)*lda;
    }
  }
  int kc = tid&3;
  int sw = (r0s>>1)&3;
  int kcS = (kc ^ sw)*8;

  f32x4 acc[4][4];
  #pragma unroll
  for (int m=0;m<4;m++)
    #pragma unroll
    for (int n=0;n<4;n++) acc[m][n] = (f32x4){0.f,0.f,0.f,0.f};

  auto STAGE = [&](int b, int k0){
    gload16(Asrc0 + k0 + kcS, As[b] + (size_t)tid*8);
    gload16(Asrc1 + k0 + kcS, As[b] + (size_t)(256+tid)*8);
    gload16(Bb + (size_t)r0s*ldb + k0 + kcS, Bs[b] + (size_t)tid*8);
    gload16(Bb + (size_t)r1s*ldb + k0 + kcS, Bs[b] + (size_t)(256+tid)*8);
  };

  int nt = K >> 5, L = nt - 1;
  STAGE(0, 0);
  if (L >= 1) STAGE(1, 32);
  int i15 = lane & 15, g = lane >> 4;
  for (int i=0; i<nt; ++i){
    int cur = i & 1;
    if (i < L) { VW(4); } else { VW(0); }
    BAR();
    short8 af[4], bfr[4];
    #pragma unroll
    for (int m=0;m<4;m++){
      int row = wr*64 + m*16 + i15;
      int geff = g ^ ((row>>1)&3);
      af[m] = *(const short8*)(As[cur] + row*32 + geff*8);
    }
    #pragma unroll
    for (int n=0;n<4;n++){
      int row = wc*64 + n*16 + i15;
      int geff = g ^ ((row>>1)&3);
      bfr[n] = *(const short8*)(Bs[cur] + row*32 + geff*8);
    }
    LW0();
    BAR();
    if (i + 2 <= L) STAGE(cur, (i+2)*32);
    __builtin_amdgcn_s_setprio(1);
    #pragma unroll
    for (int m=0;m<4;m++)
      #pragma unroll
      for (int n=0;n<4;n++)
        acc[m][n] = __builtin_amdgcn_mfma_f32_16x16x32_bf16(af[m], bfr[n], acc[m][n], 0,0,0);
    __builtin_amdgcn_s_setprio(0);
  }

  if (ACT){
    int rbase = rb + wr*64, cb = tN*128 + wc*64;
    #pragma unroll
    for (int m=0;m<4;m++){
      int r0 = rbase + m*16 + ((lane>>4)<<2);
      #pragma unroll
      for (int n=0;n<4;n++){
        int f = ((cb + n*16)>>1) + (lane&7);
        #pragma unroll
        for (int r=0;r<4;r++){
          float v = acc[m][n][r];
          float vp = __shfl_xor(v, 8);
          if (!(lane&8)){
            float gg = v;
            float a = gg/(1.f+__expf(-gg))*vp;
            C[(size_t)(r0+r)*ldc + f] = f2bf(a);
          }
        }
      }
    }
  } else {
    int rbase = rb + wr*64, cb = tN*128 + wc*64;
    #pragma unroll
    for (int m=0;m<4;m++){
      int r0 = rbase + m*16 + ((lane>>4)<<2);
      #pragma unroll
      for (int n=0;n<4;n++){
        int c = cb + n*16 + (lane&15);
        #pragma unroll
        for (int r=0;r<4;r++) C[(size_t)(r0+r)*ldc + c] = f2bf(acc[m][n][r]);
      }
    }
  }
}

// ---------------- high-precision bf16x3 GEMM (plain, XCD swizzle) ----
__global__ __launch_bounds__(256) void k_gemm_hp(
    const unsigned short* __restrict__ Ah, const unsigned short* __restrict__ Al,
    const unsigned short* __restrict__ Bh, const unsigned short* __restrict__ Bl,
    float* __restrict__ Cf,
    int K, int lda, int ldb, int ldc){
  int nx = gridDim.x, nwg = nx*gridDim.y;
  int w = xcd_swz(blockIdx.x + nx*blockIdx.y, nwg);
  int tN = w % nx, tM = w / nx;

  __shared__ __align__(16) unsigned short AsH[2][4096], AsL[2][4096];
  __shared__ __align__(16) unsigned short BsH[2][4096], BsL[2][4096];
  int tid = threadIdx.x, lane = tid & 63, wid = tid >> 6;
  int wr = wid >> 1, wc = wid & 1;
  const unsigned short* Abh = Ah + (size_t)tM*128*lda;
  const unsigned short* Abl = Al + (size_t)tM*128*lda;
  const unsigned short* Bbh = Bh + (size_t)tN*128*ldb;
  const unsigned short* Bbl = Bl + (size_t)tN*128*ldb;

  f32x4 acc[4][4];
  #pragma unroll
  for (int m=0;m<4;m++)
    #pragma unroll
    for (int n=0;n<4;n++) acc[m][n] = (f32x4){0.f,0.f,0.f,0.f};

  auto STAGE = [&](int b, int k0){
    #pragma unroll
    for (int j=0;j<2;j++){
      int cb = j*256 + tid;
      int row = cb>>2, kc = cb&3;
      int kcS = (kc ^ ((row>>1)&3))*8;
      size_t go = (size_t)row*lda + k0 + kcS;
      gload16(Abh + go, AsH[b] + (size_t)cb*8);
      gload16(Abl + go, AsL[b] + (size_t)cb*8);
      size_t bo = (size_t)row*ldb + k0 + kcS;
      gload16(Bbh + bo, BsH[b] + (size_t)cb*8);
      gload16(Bbl + bo, BsL[b] + (size_t)cb*8);
    }
  };

  int nt = K >> 5, L = nt - 1;
  STAGE(0, 0);
  if (L >= 1) STAGE(1, 32);
  int i15 = lane & 15, g = lane >> 4;
  for (int i=0; i<nt; ++i){
    int cur = i & 1;
    if (i < L) { VW(8); } else { VW(0); }
    BAR();
    short8 afh[4], afl[4], bfh[4], bfl[4];
    #pragma unroll
    for (int m=0;m<4;m++){
      int row = wr*64 + m*16 + i15;
      int ro = row*32 + (g ^ ((row>>1)&3))*8;
      afh[m] = *(const short8*)(AsH[cur] + ro);
      afl[m] = *(const short8*)(AsL[cur] + ro);
    }
    #pragma unroll
    for (int n=0;n<4;n++){
      int row = wc*64 + n*16 + i15;
      int ro = row*32 + (g ^ ((row>>1)&3))*8;
      bfh[n] = *(const short8*)(BsH[cur] + ro);
      bfl[n] = *(const short8*)(BsL[cur] + ro);
    }
    LW0();
    BAR();
    if (i + 2 <= L) STAGE(cur, (i+2)*32);
    __builtin_amdgcn_s_setprio(1);
    #pragma unroll
    for (int m=0;m<4;m++)
      #pragma unroll
      for (int n=0;n<4;n++){
        acc[m][n] = __builtin_amdgcn_mfma_f32_16x16x32_bf16(afh[m], bfh[n], acc[m][n], 0,0,0);
        acc[m][n] = __builtin_amdgcn_mfma_f32_16x16x32_bf16(afh[m], bfl[n], acc[m][n], 0,0,0);
        acc[m][n] = __builtin_amdgcn_mfma_f32_16x16x32_bf16(afl[m], bfh[n], acc[m][n], 0,0,0);
      }
    __builtin_amdgcn_s_setprio(0);
  }

  int rb = tM*128 + wr*64, cb = tN*128 + wc*64;
  #pragma unroll
  for (int m=0;m<4;m++){
    int r0 = rb + m*16 + ((lane>>4)<<2);
    #pragma unroll
    for (int n=0;n<4;n++){
      int c = cb + n*16 + (lane&15);
      #pragma unroll
      for (int r=0;r<4;r++) Cf[(size_t)(r0+r)*ldc + c] = acc[m][n][r];
    }
  }
}

// ------- balanced block-row QK^T (hp bf16x3): 2176 uniform tiles over 256 blocks -------
// blocks 0..127 take 9 tiles, 128..255 take 8; segments of same (z,tM) reuse staged Q.
__global__ __launch_bounds__(256) void k_qk_pers(
    const unsigned short* __restrict__ Qh, const unsigned short* __restrict__ Ql,
    const unsigned short* __restrict__ Kh, const unsigned short* __restrict__ Kl,
    float* __restrict__ Sp){
  int bb = blockIdx.x;
  int t0, ntile;
  if (bb < 128){ t0 = bb*9; ntile = 9; }
  else { t0 = 1152 + (bb-128)*8; ntile = 8; }
  const int ldq = NH*HD, ldk = NKV*HD;

  __shared__ __align__(16) unsigned short QsH[16384], QsL[16384];
  __shared__ __align__(16) unsigned short BsH[2][4096], BsL[2][4096];

  int tid = threadIdx.x, lane = tid & 63, wid = tid >> 6;
  int wr = wid >> 1, wc = wid & 1;
  int i15 = lane & 15, g = lane >> 4;

  f32x4 acc[4][4];
  #pragma unroll
  for (int m=0;m<4;m++)
    #pragma unroll
    for (int n=0;n<4;n++) acc[m][n] = (f32x4){0.f,0.f,0.f,0.f};

  int curZ = -1, curM = -1;
  const unsigned short* Kbh = Kh;
  const unsigned short* Kbl = Kl;
  int ti = 0;
  while (ti < ntile){
    int f = t0 + ti;
    int z = f / 136;
    int idx = f - z*136;
    int tM = 0;
    while ((tM+1)*(tM+2)/2 <= idx) tM++;
    int tri = tM*(tM+1)/2;
    int tnS = idx - tri;
    int run = ntile - ti;
    { int rem = tM+1 - tnS; if (rem < run) run = rem; }

    if (z != curZ || tM != curM){
      BAR();
      const unsigned short* Qbh = Qh + (size_t)(tM*128)*ldq + (size_t)z*HD;
      const unsigned short* Qbl = Ql + (size_t)(tM*128)*ldq + (size_t)z*HD;
      #pragma unroll
      for (int j=0;j<8;j++){
        int gi = j*256 + tid;
        int chunk = gi >> 9;
        int row = (gi >> 2) & 127;
        int gg = gi & 3;
        int col = chunk*32 + (gg ^ ((row>>1)&3))*8;
        gload16(Qbh + (size_t)row*ldq + col, QsH + (size_t)gi*8);
        gload16(Qbl + (size_t)row*ldq + col, QsL + (size_t)gi*8);
      }
      curZ = z; curM = tM;
      Kbh = Kh + (size_t)(z>>3)*HD;
      Kbl = Kl + (size_t)(z>>3)*HD;
    }

    auto BSTAGE = [&](int b, int ci){
      int tn = tnS + (ci >> 2), c = ci & 3;
      const unsigned short* sh = Kbh + (size_t)(tn*128)*ldk;
      const unsigned short* sl = Kbl + (size_t)(tn*128)*ldk;
      #pragma unroll
      for (int j=0;j<2;j++){
        int gi = j*256 + tid;
        int row = gi >> 2, gg = gi & 3;
        int col = c*32 + (gg ^ ((row>>1)&3))*8;
        gload16(sh + (size_t)row*ldk + col, BsH[b] + (size_t)gi*8);
        gload16(sl + (size_t)row*ldk + col, BsL[b] + (size_t)gi*8);
      }
    };

    int NC = run*4;
    BSTAGE(0, 0);
    BSTAGE(1, 1);
    for (int ci=0; ci<NC; ++ci){
      int cur = ci & 1, c = ci & 3, tn = tnS + (ci >> 2);
      if (ci < NC-1) { VW(4); } else { VW(0); }
      BAR();
      short8 afh[4], afl[4], bfh[4], bfl[4];
      #pragma unroll
      for (int m=0;m<4;m++){
        int row = wr*64 + m*16 + i15;
        int ro = c*4096 + row*32 + (g ^ ((row>>1)&3))*8;
        afh[m] = *(const short8*)(QsH + ro);
        afl[m] = *(const short8*)(QsL + ro);
      }
      #pragma unroll
      for (int n=0;n<4;n++){
        int row = wc*64 + n*16 + i15;
        int ro = row*32 + (g ^ ((row>>1)&3))*8;
        bfh[n] = *(const short8*)(BsH[cur] + ro);
        bfl[n] = *(const short8*)(BsL[cur] + ro);
      }
      LW0();
      BAR();
      if (ci + 2 < NC) BSTAGE(cur, ci+2);
      __builtin_amdgcn_s_setprio(1);
      #pragma unroll
      for (int m=0;m<4;m++)
        #pragma unroll
        for (int n=0;n<4;n++){
          acc[m][n] = __builtin_amdgcn_mfma_f32_16x16x32_bf16(afh[m], bfh[n], acc[m][n], 0,0,0);
          acc[m][n] = __builtin_amdgcn_mfma_f32_16x16x32_bf16(afh[m], bfl[n], acc[m][n], 0,0,0);
          acc[m][n] = __builtin_amdgcn_mfma_f32_16x16x32_bf16(afl[m], bfh[n], acc[m][n], 0,0,0);
        }
      __builtin_amdgcn_s_setprio(0);
      if (c == 3){
        float* Cb = Sp + ((size_t)z*NBLK + tri + tn)*16384;
        #pragma unroll
        for (int m=0;m<4;m++){
          int r0 = wr*64 + m*16 + (g<<2);
          #pragma unroll
          for (int n=0;n<4;n++){
            int ccol = wc*64 + n*16 + i15;
            #pragma unroll
            for (int r=0;r<4;r++) Cb[(size_t)(r0+r)*128 + ccol] = acc[m][n][r];
          }
        }
        #pragma unroll
        for (int m=0;m<4;m++)
          #pragma unroll
          for (int n=0;n<4;n++) acc[m][n] = (f32x4){0.f,0.f,0.f,0.f};
      }
    }
    ti += run;
  }
}

// ---------------- PV split-K, unnormalized exp fused in fragment read (diag-masked) -------
// Accumulates O~ = sum exp(s*scale) * V and per-row sums; pv_reduce normalizes.
__global__ __launch_bounds__(256) void k_pv_hp(
    const float* __restrict__ Sp,
    const unsigned short* __restrict__ Vh, const unsigned short* __restrict__ Vl,
    float* __restrict__ part, float* __restrict__ rsums){
  int c = blockIdx.x, tM = blockIdx.y, z = blockIdx.z;
  int kbeg = c*512;
  int kend = min((tM+1)*128, (c+1)*512);
  if (kbeg >= kend) return;
  int tMk = tM*128;
  size_t tri = (size_t)tM*(tM+1)/2;
  const float* Ab = Sp + ((size_t)z*NBLK + tri)*16384;
  const unsigned short* Bbh = Vh + (size_t)(z>>3)*HD*T_;
  const unsigned short* Bbl = Vl + (size_t)(z>>3)*HD*T_;

  __shared__ __align__(16) float Asf[2][4096];
  __shared__ __align__(16) unsigned short BsH[2][4096], BsL[2][4096];
  int tid = threadIdx.x, lane = tid & 63, wid = tid >> 6;
  int wr = wid >> 1, wc = wid & 1;
  int i15 = lane & 15, g2 = (lane>>4)*2;

  int r0s = tid>>2, r1s = r0s + 64;
  int kcB = ((tid&3) ^ ((r0s>>1)&3))*8;
  int rowA = tid>>3, gA = tid&7;

  f32x4 acc[4][4];
  #pragma unroll
  for (int m=0;m<4;m++)
    #pragma unroll
    for (int n=0;n<4;n++) acc[m][n] = (f32x4){0.f,0.f,0.f,0.f};
  float rsum[4] = {0.f,0.f,0.f,0.f};

  auto STAGE = [&](int b, int k0){
    #pragma unroll
    for (int j=0;j<4;j++){
      int r = j*32 + rowA;
      int gS = gA ^ (r & 7);
      size_t ga = (size_t)(k0>>7)*16384 + (size_t)r*128 + (k0&127) + gS*4;
      gload16(Ab + ga, Asf[b] + ((size_t)j*256 + tid)*4);
    }
    size_t bo0 = (size_t)r0s*T_ + k0 + kcB;
    size_t bo1 = (size_t)r1s*T_ + k0 + kcB;
    gload16(Bbh + bo0, BsH[b] + (size_t)tid*8);
    gload16(Bbh + bo1, BsH[b] + (size_t)(256+tid)*8);
    gload16(Bbl + bo0, BsL[b] + (size_t)tid*8);
    gload16(Bbl + bo1, BsL[b] + (size_t)(256+tid)*8);
  };

  int nt = (kend - kbeg) >> 5, L = nt - 1;
  STAGE(0, kbeg);
  if (L >= 1) STAGE(1, kbeg + 32);
  for (int i=0; i<nt; ++i){
    int cur = i & 1;
    int k0 = kbeg + i*32;
    if (i < L) { VW(8); } else { VW(0); }
    BAR();
    int diag = (k0 >= tMk);
    short8 afh[4], afl[4], bfh[4], bfl[4];
    #pragma unroll
    for (int m=0;m<4;m++){
      int r = wr*64 + m*16 + i15;
      int s0 = r*8 + ((g2  ) ^ (r&7));
      int s1 = r*8 + ((g2+1) ^ (r&7));
      f32x4 a0 = *(const f32x4*)(Asf[cur] + s0*4);
      f32x4 a1 = *(const f32x4*)(Asf[cur] + s1*4);
      float pv[8] = {a0[0],a0[1],a0[2],a0[3],a1[0],a1[1],a1[2],a1[3]};
      if (diag){
        int kb = k0 & 127;
        #pragma unroll
        for (int j=0;j<8;j++){
          int kl = kb + ((j<4) ? g2*4 + j : (g2+1)*4 + (j-4));
          if (kl > r) pv[j] = -3.0e38f;
        }
      }
      short8 h8, l8;
      #pragma unroll
      for (int j=0;j<8;j++){
        float p = __expf(pv[j]*SM_SCALE);
        rsum[m] += p;
        unsigned short hh, ll; split2(p, hh, ll);
        h8[j] = (short)hh; l8[j] = (short)ll;
      }
      afh[m] = h8; afl[m] = l8;
    }
    #pragma unroll
    for (int n=0;n<4;n++){
      int row = wc*64 + n*16 + i15;
      int ro = row*32 + ((lane>>4) ^ ((row>>1)&3))*8;
      bfh[n] = *(const short8*)(BsH[cur] + ro);
      bfl[n] = *(const short8*)(BsL[cur] + ro);
    }
    LW0();
    BAR();
    if (i + 2 <= L) STAGE(cur, kbeg + (i+2)*32);
    __builtin_amdgcn_s_setprio(1);
    #pragma unroll
    for (int m=0;m<4;m++)
      #pragma unroll
      for (int n=0;n<4;n++){
        acc[m][n] = __builtin_amdgcn_mfma_f32_16x16x32_bf16(afh[m], bfh[n], acc[m][n], 0,0,0);
        acc[m][n] = __builtin_amdgcn_mfma_f32_16x16x32_bf16(afh[m], bfl[n], acc[m][n], 0,0,0);
        acc[m][n] = __builtin_amdgcn_mfma_f32_16x16x32_bf16(afl[m], bfh[n], acc[m][n], 0,0,0);
      }
    __builtin_amdgcn_s_setprio(0);
  }

  // per-row sum of exp over this chunk: reduce across the 4 lanes (lane bits 4-5)
  #pragma unroll
  for (int m=0;m<4;m++){
    float v = rsum[m];
    v += __shfl_xor(v, 16);
    v += __shfl_xor(v, 32);
    if ((lane>>4)==0 && wc==0)
      rsums[((size_t)c*NH + z)*T_ + tMk + wr*64 + m*16 + i15] = v;
  }

  float* Cb = part + (size_t)c*T_*DM + (size_t)tMk*DM + (size_t)z*HD;
  #pragma unroll
  for (int m=0;m<4;m++){
    int r0 = wr*64 + m*16 + ((lane>>4)<<2);
    #pragma unroll
    for (int n=0;n<4;n++){
      int ccol = wc*64 + n*16 + (lane&15);
      #pragma unroll
      for (int r=0;r<4;r++) Cb[(size_t)(r0+r)*DM + ccol] = acc[m][n][r];
    }
  }
}

// reduce partials, normalize by row sums -> aoh/aol (bf16 hi/lo)
__global__ void k_pv_reduce(const float* __restrict__ part, const float* __restrict__ rsums,
                            unsigned short* __restrict__ aoh, unsigned short* __restrict__ aol){
  int t = blockIdx.x, tid = threadIdx.x;
  int nc = ((t>>7) + 4) >> 2;
  #pragma unroll
  for (int half=0; half<2; ++half){
    int idx = tid + half*256;
    int z = idx >> 5;                      // float4 index -> head (idx*4 >> 7)
    float tot = 0.f;
    for (int c=0; c<nc; ++c) tot += rsums[((size_t)c*NH + z)*T_ + t];
    float inv = 1.f / tot;
    float4 s = ((const float4*)(part + (size_t)t*DM))[idx];
    for (int c=1; c<nc; ++c){
      float4 v = ((const float4*)(part + (size_t)c*T_*DM + (size_t)t*DM))[idx];
      s.x+=v.x; s.y+=v.y; s.z+=v.z; s.w+=v.w;
    }
    s.x*=inv; s.y*=inv; s.z*=inv; s.w*=inv;
    ushort4 h_, l_;
    split2(s.x,h_.x,l_.x); split2(s.y,h_.y,l_.y); split2(s.z,h_.z,l_.z); split2(s.w,h_.w,l_.w);
    ((ushort4*)(aoh + (size_t)t*DM))[idx] = h_;
    ((ushort4*)(aol + (size_t)t*DM))[idx] = l_;
  }
}

// ---------------- qkv post ----------------
__global__ void k_qkv_post_hp(const float* __restrict__ qkv, const float* __restrict__ bias,
                              const float* __restrict__ qnw, const float* __restrict__ knw,
                              const int* __restrict__ pos_,
                              unsigned short* __restrict__ qhi, unsigned short* __restrict__ qlo,
                              unsigned short* __restrict__ khi, unsigned short* __restrict__ klo,
                              unsigned short* __restrict__ vThi, unsigned short* __restrict__ vTlo){
  int t = blockIdx.x;
  int half = threadIdx.x >> 7;
  int d = threadIdx.x & 127;
  int wseg = (threadIdx.x >> 6) & 1;
  float posf = (float)pos_[t];
  __shared__ float buf[2][128];
  __shared__ float ssum[2][2];
  __shared__ float inv_sh[32];
  if (threadIdx.x < 32)
    inv_sh[threadIdx.x] = (float)pow(1000000.0, -(double)threadIdx.x/32.0);
  __syncthreads();
  for (int it=0; it<10; ++it){
    int seg = it*2 + half;
    float x = qkv[(size_t)t*QKVN + seg*128 + d] + bias[seg*128 + d];
    float p = x*x;
    #pragma unroll
    for (int o=32;o;o>>=1) p += __shfl_xor(p,o);
    if ((threadIdx.x&63)==0) ssum[half][wseg] = p;
    __syncthreads();
    float rs = rsqrtf((ssum[half][0]+ssum[half][1])*(1.f/128.f) + 1e-5f);
    float w = (seg<16) ? qnw[d] : ((seg<18) ? knw[d] : 1.f);
    float nv = x*rs*w;
    buf[half][d] = nv;
    __syncthreads();
    float outv = (seg<18) ? nv : x;
    if (seg < 18 && d < 64){
      int i = d & 31;
      float ang = posf * inv_sh[i];
      float sn, cs; sincosf(ang, &sn, &cs);
      if (d < 32) outv = nv*cs - buf[half][d+32]*sn;
      else        outv = nv*cs + buf[half][d-32]*sn;
    }
    unsigned short h_, l_; split2(outv, h_, l_);
    if (seg < 16){ size_t o = ((size_t)t*NH + seg)*HD + d; qhi[o]=h_; qlo[o]=l_; }
    else if (seg < 18){ size_t o = ((size_t)t*NKV + (seg-16))*HD + d; khi[o]=h_; klo[o]=l_; }
    else { size_t o = ((size_t)(seg-18)*HD + d)*T_ + t; vThi[o]=h_; vTlo[o]=l_; }
    __syncthreads();
  }
}

// ---- offplace: histogram + offsets + placement in one single-block kernel ----
__global__ void k_offplace(const int* __restrict__ idx4, int* __restrict__ offs,
                           int* __restrict__ rrow, int* __restrict__ tok){
  __shared__ int hist[16];
  __shared__ int hoff[16];
  __shared__ int fill[16];
  int tid = threadIdx.x;
  if (tid < 16) hist[tid] = 0;
  __syncthreads();
  for (int i = tid; i < ROWS_ALL; i += 256) tok[i] = 0;
  for (int i = tid; i < T_*4; i += 256)
    atomicAdd(&hist[idx4[i]], 1);
  __syncthreads();
  if (tid == 0){
    int o = 0;
    for (int e=0;e<16;e++){ hoff[e]=o; offs[e]=o; o += ((hist[e]+127)>>7)<<7; }
    offs[16]=o;
    offs[17]=o + T_;
  }
  if (tid < 16) fill[tid] = 0;
  __syncthreads();
  int off16 = offs[16];
  for (int t = tid; t < T_; t += 256){
    #pragma unroll
    for (int s=0;s<4;s++){
      int e = idx4[t*4+s];
      int p = atomicAdd(&fill[e],1);
      int r = hoff[e]+p;
      rrow[t*4+s]=r;
      tok[r]=t;
    }
    tok[off16+t] = t;
  }
}

__global__ void k_combine(const unsigned short* __restrict__ eout,
                          const int* __restrict__ rrow, const float* __restrict__ w4,
                          const int* __restrict__ offs, float* __restrict__ outh){
  int t = blockIdx.x;
  int rs = offs[16] + t;
  int r0=rrow[t*4+0], r1=rrow[t*4+1], r2=rrow[t*4+2], r3=rrow[t*4+3];
  float w0=w4[t*4+0], w1=w4[t*4+1], w2=w4[t*4+2], w3=w4[t*4+3];
  for (int d=threadIdx.x; d<DM; d+=256){
    float v = bf2f(eout[(size_t)rs*DM+d])
            + w0*bf2f(eout[(size_t)r0*DM+d]) + w1*bf2f(eout[(size_t)r1*DM+d])
            + w2*bf2f(eout[(size_t)r2*DM+d]) + w3*bf2f(eout[(size_t)r3*DM+d]);
    outh[(size_t)t*DM+d] = v;
  }
}

// =========================================================================
extern "C" void kernel_launch(void* const* d_in, const int* in_sizes, int n_in,
                              void* d_out, int out_size, void* d_ws, size_t ws_size,
                              hipStream_t stream){
  const int*   positions = (const int*)d_in[0];
  const float* hidden    = (const float*)d_in[1];
  const float* residual  = (const float*)d_in[2];
  const float* ln1       = (const float*)d_in[3];
  const float* ln2       = (const float*)d_in[4];
  const float* w_qkv     = (const float*)d_in[5];
  const float* b_qkv     = (const float*)d_in[6];
  const float* w_o       = (const float*)d_in[7];
  const float* qnw       = (const float*)d_in[8];
  const float* knw       = (const float*)d_in[9];
  const float* gate_w    = (const float*)d_in[10];
  const float* gate_b    = (const float*)d_in[11];
  const float* sh_wgu    = (const float*)d_in[12];
  const float* sh_wd     = (const float*)d_in[13];
  const float* e_wgu     = (const float*)d_in[14];
  const float* e_wd      = (const float*)d_in[15];
  float* out_h   = (float*)d_out;
  float* out_res = (float*)d_out + (size_t)T_*DM;

  char* ws = (char*)d_ws;
  size_t off = 0;
  auto alloc = [&](size_t b){ size_t r = off; off += (b + 255) & ~(size_t)255; return r; };

  // ---- persistent ----
  size_t o_h2b  = alloc((size_t)T_*DM*2);
  size_t o_idx  = alloc((size_t)T_*4*4);
  size_t o_w4   = alloc((size_t)T_*4*4);
  size_t o_offs = alloc(72);
  size_t o_rrow = alloc((size_t)T_*4*4);
  size_t o_tok  = alloc((size_t)ROWS_ALL*4);

  // ---- phase-union arena ----
  size_t U0 = off;
  size_t a = U0;
  auto allocA = [&](size_t b){ size_t r = a; a += (b + 255) & ~(size_t)255; return r; };
  size_t o_h1h  = allocA((size_t)T_*DM*2);
  size_t o_h1l  = allocA((size_t)T_*DM*2);
  size_t o_wqh  = allocA((size_t)QKVN*DM*2);
  size_t o_wql  = allocA((size_t)QKVN*DM*2);
  size_t o_qkvf = allocA((size_t)T_*QKVN*4);
  size_t o_qh   = allocA((size_t)T_*NH*HD*2);
  size_t o_ql   = allocA((size_t)T_*NH*HD*2);
  size_t o_kh   = allocA((size_t)T_*NKV*HD*2);
  size_t o_kl   = allocA((size_t)T_*NKV*HD*2);
  size_t o_vth  = allocA((size_t)NKV*HD*T_*2);
  size_t o_vtl  = allocA((size_t)NKV*HD*T_*2);
  size_t o_woh  = allocA((size_t)DM*DM*2);
  size_t o_wol  = allocA((size_t)DM*DM*2);
  size_t o_aoh  = allocA((size_t)T_*DM*2);
  size_t o_aol  = allocA((size_t)T_*DM*2);
  size_t o_attnP= allocA((size_t)T_*DM*4);
  size_t o_rsum = allocA((size_t)4*NH*T_*4);
  size_t o_Sp   = allocA((size_t)NH*NBLK*16384*4);
  size_t o_pvp  = allocA((size_t)4*T_*DM*4);
  // phase B (MoE)
  size_t b_ = U0;
  auto allocB = [&](size_t b){ size_t r = b_; b_ += (b + 255) & ~(size_t)255; return r; };
  size_t o_ewgu = allocB((size_t)NE*2*IM*DM*2);
  size_t o_ewd  = allocB((size_t)NE*DM*IM*2);
  size_t o_shgu = allocB((size_t)2*ISH*DM*2);
  size_t o_shwd = allocB((size_t)DM*ISH*2);
  size_t o_actx = allocB((size_t)ROWS_ALL*IM*2);
  size_t o_eout = allocB((size_t)ROWS_ALL*DM*2);

  unsigned short* h2b   = (unsigned short*)(ws+o_h2b);
  int*   idx4  = (int*)(ws+o_idx);
  float* w4p   = (float*)(ws+o_w4);
  int*   offs  = (int*)(ws+o_offs);
  int*   rrow  = (int*)(ws+o_rrow);
  int*   tok   = (int*)(ws+o_tok);
  unsigned short* h1h = (unsigned short*)(ws+o_h1h);
  unsigned short* h1l = (unsigned short*)(ws+o_h1l);
  unsigned short* wqh = (unsigned short*)(ws+o_wqh);
  unsigned short* wql = (unsigned short*)(ws+o_wql);
  float*          qkvf= (float*)(ws+o_qkvf);
  unsigned short* qh  = (unsigned short*)(ws+o_qh);
  unsigned short* ql  = (unsigned short*)(ws+o_ql);
  unsigned short* kh  = (unsigned short*)(ws+o_kh);
  unsigned short* kl  = (unsigned short*)(ws+o_kl);
  unsigned short* vth = (unsigned short*)(ws+o_vth);
  unsigned short* vtl = (unsigned short*)(ws+o_vtl);
  unsigned short* woh = (unsigned short*)(ws+o_woh);
  unsigned short* wol = (unsigned short*)(ws+o_wol);
  unsigned short* aoh = (unsigned short*)(ws+o_aoh);
  unsigned short* aol = (unsigned short*)(ws+o_aol);
  float*          attnP=(float*)(ws+o_attnP);
  float*          rsums=(float*)(ws+o_rsum);
  float*          Sp  = (float*)(ws+o_Sp);
  float*          pvpart = (float*)(ws+o_pvp);
  unsigned short* ewguT=(unsigned short*)(ws+o_ewgu);
  unsigned short* ewdT = (unsigned short*)(ws+o_ewd);
  unsigned short* shguT=(unsigned short*)(ws+o_shgu);
  unsigned short* shwdT=(unsigned short*)(ws+o_shwd);
  unsigned short* actx= (unsigned short*)(ws+o_actx);
  unsigned short* eout= (unsigned short*)(ws+o_eout);

  // ---- attention phase (high precision) ----
  k_tconv2<<<dim3(QKVN/64, DM/64, 2),256,0,stream>>>(w_qkv, wqh, wql, w_o, woh, wol);

  k_add_rmsnorm<false><<<T_,256,0,stream>>>(hidden, residual, ln1, out_res, h1h, h1l, nullptr,
                                            nullptr, nullptr, nullptr, nullptr);

  k_gemm_hp<<<dim3(QKVN/128,T_/128,1),256,0,stream>>>(
      h1h, h1l, wqh, wql, qkvf, DM, DM, DM, QKVN);
  k_qkv_post_hp<<<T_,256,0,stream>>>(qkvf, b_qkv, qnw, knw, positions, qh, ql, kh, kl, vth, vtl);

  k_qk_pers<<<dim3(256),256,0,stream>>>(qh, ql, kh, kl, Sp);
  k_pv_hp<<<dim3(4,T_/128,NH),256,0,stream>>>(Sp, vth, vtl, pvpart, rsums);
  k_pv_reduce<<<T_,256,0,stream>>>(pvpart, rsums, aoh, aol);
  k_gemm_hp<<<dim3(DM/128,T_/128,1),256,0,stream>>>(
      aoh, aol, woh, wol, attnP, DM, DM, DM, DM);

  // rmsnorm2 with fused MoE routing (no global atomics)
  k_add_rmsnorm<true><<<T_,256,0,stream>>>(attnP, out_res, ln2, out_res, nullptr, nullptr, h2b,
                                           gate_w, gate_b, idx4, w4p);

  k_offplace<<<1,256,0,stream>>>(idx4, offs, rrow, tok);

  // ---- weight conversion (phase A arena dead now); shared weights merged as z==16 ----
  k_tconv<true ><<<dim3(2*IM/64, DM/64, NE+1),256,0,stream>>>(
      e_wgu, ewguT, sh_wgu, shguT, DM, 2*IM, (size_t)DM*2*IM, (size_t)2*IM*DM);
  k_tconv<false><<<dim3(DM/64, IM/64, NE+1),256,0,stream>>>(
      e_wd,  ewdT,  sh_wd,  shwdT, IM, DM,   (size_t)IM*DM,   (size_t)DM*IM);

  // ---- unified grouped MLP (experts + shared); silu fused into up-GEMM epilogue ----
  k_gemm2<true, true ><<<dim3(2*IM/128, ROWS_ALL/128, 1),256,0,stream>>>(
      h2b, ewguT, shguT, actx, DM, DM, DM, IM, offs, (size_t)2*IM*DM, tok);
  k_gemm2<false, false><<<dim3(DM/128, ROWS_ALL/128, 1),256,0,stream>>>(
      actx, ewdT, shwdT, eout, IM, IM, IM, DM, offs, (size_t)DM*IM, nullptr);

  // ---- combine ----
  k_combine<<<T_,256,0,stream>>>(eout, rrow, w4p, offs, out_h);
}

// Round 21
// 663.133 us; speedup vs baseline: 1.2551x; 1.0020x over previous
//
#include <hip/hip_runtime.h>
#include <stdint.h>
#include <math.h>

#define T_ 2048
#define DM 2048
#define NH 16
#define NKV 2
#define HD 128
#define QKVN 2560
#define NE 16
#define IM 768
#define ISH 768
#define MAXROWS 10240
#define ROWS_ALL 12288   // MAXROWS + T_ (shared region appended)
#define NBLK 136         // 16*17/2 causal 128x128 blocks per head
#define SM_SCALE 0.08838834764831845f

typedef __attribute__((ext_vector_type(8))) short short8;
typedef __attribute__((ext_vector_type(4))) float f32x4;

__device__ __forceinline__ float bf2f(unsigned short u){ return __uint_as_float(((unsigned int)u)<<16); }
__device__ __forceinline__ unsigned short f2bf(float f){
  unsigned int u = __float_as_uint(f);
  return (unsigned short)((u + 0x7FFFu + ((u>>16)&1u)) >> 16);
}
__device__ __forceinline__ void split2(float x, unsigned short& hi, unsigned short& lo){
  hi = f2bf(x);
  lo = f2bf(x - bf2f(hi));
}

__device__ __forceinline__ void gload16(const void* g, void* l){
  __builtin_amdgcn_global_load_lds((const __attribute__((address_space(1))) unsigned int*)g,
                                   (__attribute__((address_space(3))) unsigned int*)l, 16, 0, 0);
}

// bijective XCD swizzle (m204)
__device__ __forceinline__ int xcd_swz(int bid, int nwg){
  int q = nwg >> 3, r = nwg & 7, x = bid & 7, p = bid >> 3;
  return (x < r ? x*(q+1) : r*(q+1) + (x-r)*q) + p;
}

#define BAR()    asm volatile("s_barrier" ::: "memory")
#define VW(N)    asm volatile("s_waitcnt vmcnt(" #N ")" ::: "memory")
#define LW0()    do{ asm volatile("s_waitcnt lgkmcnt(0)" ::: "memory"); __builtin_amdgcn_sched_barrier(0); }while(0)

// ---- offplace body: histogram + offsets + placement (single block executes) ----
__device__ void do_offplace(const int* __restrict__ idx4, int* __restrict__ offs,
                            int* __restrict__ rrow, int* __restrict__ tok){
  __shared__ int hist[16];
  __shared__ int hoff[16];
  __shared__ int fill[16];
  int tid = threadIdx.x;
  if (tid < 16) hist[tid] = 0;
  __syncthreads();
  for (int i = tid; i < ROWS_ALL; i += 256) tok[i] = 0;
  for (int i = tid; i < T_*4; i += 256)
    atomicAdd(&hist[idx4[i]], 1);
  __syncthreads();
  if (tid == 0){
    int o = 0;
    for (int e=0;e<16;e++){ hoff[e]=o; offs[e]=o; o += ((hist[e]+127)>>7)<<7; }
    offs[16]=o;
    offs[17]=o + T_;
  }
  if (tid < 16) fill[tid] = 0;
  __syncthreads();
  int off16 = offs[16];
  for (int t = tid; t < T_; t += 256){
    #pragma unroll
    for (int s=0;s<4;s++){
      int e = idx4[t*4+s];
      int p = atomicAdd(&fill[e],1);
      int r = hoff[e]+p;
      rrow[t*4+s]=r;
      tok[r]=t;
    }
    tok[off16+t] = t;
  }
}

// ------- fused weight conversion (wgu + wd + hidden offplace) -------
// grid (48, 32, 17): x<24 -> wgu tile (ILV), x>=24 -> wd tile via flat reindex;
// one permanently-empty block (z==16,x==47,y==31) runs offplace concurrently.
__global__ void k_wconv(const float* __restrict__ e_wgu, unsigned short* __restrict__ ewguT,
                        const float* __restrict__ sh_wgu, unsigned short* __restrict__ shguT,
                        const float* __restrict__ e_wd, unsigned short* __restrict__ ewdT,
                        const float* __restrict__ sh_wd, unsigned short* __restrict__ shwdT,
                        const int* __restrict__ idx4, int* __restrict__ offs,
                        int* __restrict__ rrow, int* __restrict__ tok){
  __shared__ float tile[64*65];
  int z = blockIdx.z, x = blockIdx.x, y = blockIdx.y;
  int tid = threadIdx.x;
  const float* src; unsigned short* dst;
  int R, C, r0, c0;
  bool ilv;
  if (x < 24){
    src = (z==16)? sh_wgu : e_wgu + (size_t)z*((size_t)DM*2*IM);
    dst = (z==16)? shguT : ewguT + (size_t)z*((size_t)2*IM*DM);
    R = DM; C = 2*IM; r0 = y*64; c0 = x*64; ilv = true;
  } else {
    int flat = (x-24) + 24*y;
    if (flat >= 384){
      if (z==16 && x==47 && y==31) do_offplace(idx4, offs, rrow, tok);
      return;
    }
    src = (z==16)? sh_wd : e_wd + (size_t)z*((size_t)IM*DM);
    dst = (z==16)? shwdT : ewdT + (size_t)z*((size_t)DM*IM);
    R = IM; C = DM; r0 = (flat/32)*64; c0 = (flat%32)*64; ilv = false;
  }
  int lr = tid>>4, lc = (tid&15)*4;
  #pragma unroll
  for (int j=0;j<4;j++){
    int row = j*16 + lr;
    float4 v = *(const float4*)&src[(size_t)(r0+row)*C + c0 + lc];
    float* t = &tile[row*65 + lc];
    t[0]=v.x; t[1]=v.y; t[2]=v.z; t[3]=v.w;
  }
  __syncthreads();
  #pragma unroll
  for (int jj=0;jj<2;jj++){
    int slot = jj*256 + tid;
    int c = slot>>3, ro = (slot&7)*8;
    int cg = c0 + c;
    int cd = cg;
    if (ilv){ int b = cg>>3, inner = cg&7; cd = (b<96 ? b*16 : (b-96)*16+8) + inner; }
    short8 o;
    #pragma unroll
    for (int k=0;k<8;k++) o[k] = (short)f2bf(tile[(ro+k)*65 + c]);
    *(short8*)&dst[(size_t)cd*R + r0 + ro] = o;
  }
}

// ------- transpose conv f32 -> bf16 hi + lo planes, vectorized; z=0 wqkv, z=1 w_o -------
__global__ void k_tconv2(const float* __restrict__ srcA, unsigned short* __restrict__ dhiA,
                         unsigned short* __restrict__ dloA,
                         const float* __restrict__ srcB, unsigned short* __restrict__ dhiB,
                         unsigned short* __restrict__ dloB){
  const float* src; unsigned short* dhi; unsigned short* dlo; int R, C;
  if (blockIdx.z == 0){ src = srcA; dhi = dhiA; dlo = dloA; R = DM; C = QKVN; }
  else {
    if (blockIdx.x >= DM/64) return;
    src = srcB; dhi = dhiB; dlo = dloB; R = DM; C = DM;
  }
  __shared__ float tile[64*65];
  int tid = threadIdx.x;
  int r0 = blockIdx.y*64, c0 = blockIdx.x*64;
  int lr = tid>>4, lc = (tid&15)*4;
  #pragma unroll
  for (int j=0;j<4;j++){
    int row = j*16 + lr;
    float4 v = *(const float4*)&src[(size_t)(r0+row)*C + c0 + lc];
    float* t = &tile[row*65 + lc];
    t[0]=v.x; t[1]=v.y; t[2]=v.z; t[3]=v.w;
  }
  __syncthreads();
  #pragma unroll
  for (int jj=0;jj<2;jj++){
    int slot = jj*256 + tid;
    int c = slot>>3, ro = (slot&7)*8;
    short8 oh, ol;
    #pragma unroll
    for (int k=0;k<8;k++){
      unsigned short h_, l_;
      split2(tile[(ro+k)*65 + c], h_, l_);
      oh[k] = (short)h_; ol[k] = (short)l_;
    }
    size_t o = (size_t)(c0+c)*R + r0 + ro;
    *(short8*)&dhi[o] = oh;
    *(short8*)&dlo[o] = ol;
  }
}

// ---------------- add + rmsnorm; ROUTE: fused MoE gate (no global atomics) ----------------
template<bool ROUTE>
__global__ void k_add_rmsnorm(const float* __restrict__ a, const float* __restrict__ b,
                              const float* __restrict__ w, float* __restrict__ resout,
                              unsigned short* __restrict__ ohi, unsigned short* __restrict__ olo,
                              unsigned short* __restrict__ obf,
                              const float* __restrict__ gw, const float* __restrict__ gbias,
                              int* __restrict__ idx4, float* __restrict__ w4){
  int t = blockIdx.x, tid = threadIdx.x;
  const float4* a4 = (const float4*)(a + (size_t)t*DM);
  const float4* b4 = (const float4*)(b + (size_t)t*DM);
  float4 va = a4[tid], vb = b4[tid];
  float4 wa = a4[tid+256], wb = b4[tid+256];
  float4 v0, v1;
  v0.x=va.x+vb.x; v0.y=va.y+vb.y; v0.z=va.z+vb.z; v0.w=va.w+vb.w;
  v1.x=wa.x+wb.x; v1.y=wa.y+wb.y; v1.z=wa.z+wb.z; v1.w=wa.w+wb.w;
  float s = v0.x*v0.x+v0.y*v0.y+v0.z*v0.z+v0.w*v0.w
          + v1.x*v1.x+v1.y*v1.y+v1.z*v1.z+v1.w*v1.w;
  #pragma unroll
  for (int o=32;o;o>>=1) s += __shfl_xor(s,o);
  __shared__ float sm[4];
  if ((tid&63)==0) sm[tid>>6]=s;
  __syncthreads();
  s = sm[0]+sm[1]+sm[2]+sm[3];
  float rs = rsqrtf(s*(1.f/(float)DM) + 1e-5f);
  ((float4*)(resout + (size_t)t*DM))[tid] = v0;
  ((float4*)(resout + (size_t)t*DM))[tid+256] = v1;
  const float4* w4p_ = (const float4*)w;
  float4 w0 = w4p_[tid], w1 = w4p_[tid+256];
  float n[8] = { v0.x*rs*w0.x, v0.y*rs*w0.y, v0.z*rs*w0.z, v0.w*rs*w0.w,
                 v1.x*rs*w1.x, v1.y*rs*w1.y, v1.z*rs*w1.z, v1.w*rs*w1.w };
  if (ohi){
    ushort4 h0,h1,l0,l1;
    split2(n[0],h0.x,l0.x); split2(n[1],h0.y,l0.y); split2(n[2],h0.z,l0.z); split2(n[3],h0.w,l0.w);
    split2(n[4],h1.x,l1.x); split2(n[5],h1.y,l1.y); split2(n[6],h1.z,l1.z); split2(n[7],h1.w,l1.w);
    ((ushort4*)(ohi + (size_t)t*DM))[tid] = h0;
    ((ushort4*)(ohi + (size_t)t*DM))[tid+256] = h1;
    ((ushort4*)(olo + (size_t)t*DM))[tid] = l0;
    ((ushort4*)(olo + (size_t)t*DM))[tid+256] = l1;
  }
  if (obf){
    ushort4 o0 = make_ushort4(f2bf(n[0]),f2bf(n[1]),f2bf(n[2]),f2bf(n[3]));
    ushort4 o1 = make_ushort4(f2bf(n[4]),f2bf(n[5]),f2bf(n[6]),f2bf(n[7]));
    ((ushort4*)(obf + (size_t)t*DM))[tid] = o0;
    ((ushort4*)(obf + (size_t)t*DM))[tid+256] = o1;
  }
  if constexpr (ROUTE){
    __shared__ float xrow[DM];          // 8 KB
    __shared__ float red[16][17];
    #pragma unroll
    for (int jj=0;jj<4;jj++) xrow[4*tid+jj] = n[jj];
    #pragma unroll
    for (int jj=0;jj<4;jj++) xrow[1024+4*tid+jj] = n[4+jj];
    __syncthreads();
    // coalesced gate GEMV: lane (grp=tid>>4, e=tid&15); gw row-major [DM][16]
    int e = tid & 15, grp = tid >> 4;
    float part = 0.f;
    #pragma unroll 8
    for (int c = grp; c < DM; c += 16)
      part += xrow[c] * gw[(size_t)c*16 + e];
    red[grp][e] = part;
    __syncthreads();
    if (tid==0){
      float sc[16], sb[16];
      for (int ee=0;ee<16;ee++){
        float lg = 0.f;
        for (int g2=0;g2<16;g2++) lg += red[g2][ee];
        sc[ee] = 1.f/(1.f+expf(-lg));
        sb[ee] = sc[ee] + gbias[ee];
      }
      float gs[4];
      for (int g=0;g<4;g++){
        float m1=-3.4e38f, m2=-3.4e38f;
        for (int j=0;j<4;j++){
          float v = sb[g*4+j];
          if (v>m1){ m2=m1; m1=v; } else if (v>m2) m2=v;
        }
        gs[g]=m1+m2;
      }
      int g1=0; for (int g=1;g<4;g++) if (gs[g]>gs[g1]) g1=g;
      int g2=-1; for (int g=0;g<4;g++){ if (g==g1) continue; if (g2<0 || gs[g]>gs[g2]) g2=g; }
      float msk[16];
      for (int ee=0;ee<16;ee++){ int g=ee>>2; msk[ee] = (g==g1||g==g2)? sb[ee] : -3.4e38f; }
      int id[4]; float wv[4]; float wsum=0.f;
      for (int s2=0;s2<4;s2++){
        int bb=0; float bv=-3.5e38f;
        for (int ee=0;ee<16;ee++) if (msk[ee]>bv){ bv=msk[ee]; bb=ee; }
        id[s2]=bb; wv[s2]=sc[bb]; wsum+=sc[bb]; msk[bb]=-3.5e38f;
      }
      float invs = 1.f/wsum;
      for (int s2=0;s2<4;s2++){
        idx4[t*4+s2]=id[s2];
        w4[t*4+s2]=wv[s2]*invs;
      }
    }
  }
}

// ------- grouped bf16 GEMM (experts + shared), BK=32 counted-vmcnt 2-deep pipeline -------
// ACT: B cols are (g,u) 8-interleaved; epilogue computes silu(g)*u -> bf16 C [rows][IM]
template<bool GATHER, bool ACT>
__global__ __launch_bounds__(256) void k_gemm2(
    const unsigned short* __restrict__ A, const unsigned short* __restrict__ Be,
    const unsigned short* __restrict__ Bsh, unsigned short* __restrict__ C,
    int K, int lda, int ldb, int ldc,
    const int* __restrict__ offs, size_t sBe, const int* __restrict__ tok){
  int nx = gridDim.x;
  int nwg = nx * gridDim.y;
  int wid_ = xcd_swz(blockIdx.x + nx*blockIdx.y, nwg);
  int tN = wid_ % nx, tM = wid_ / nx;
  int rb = tM*128;
  if (rb >= offs[17]) return;
  const unsigned short* B;
  if (rb >= offs[16]) B = Bsh;
  else {
    int e=0;
    for (; e<15; ++e) if (offs[e+1] > rb) break;
    B = Be + (size_t)e*sBe;
  }
  __shared__ __align__(16) unsigned short As[2][4096];
  __shared__ __align__(16) unsigned short Bs[2][4096];
  int tid = threadIdx.x, lane = tid & 63, wwid = tid >> 6;
  int wr = wwid >> 1, wc = wwid & 1;
  const unsigned short* Bb = B + (size_t)tN*128*ldb;

  const unsigned short* Asrc0;
  const unsigned short* Asrc1;
  int r0s = tid>>2, r1s = r0s + 64;
  {
    if (GATHER){
      Asrc0 = A + (size_t)tok[rb + r0s]*lda;
      Asrc1 = A + (size_t)tok[rb + r1s]*lda;
    } else {
      Asrc0 = A + (size_t)(rb + r0s)*lda;
      Asrc1 = A + (size_t)(rb + r1s)*lda;
    }
  }
  int kc = tid&3;
  int sw = (r0s>>1)&3;
  int kcS = (kc ^ sw)*8;

  f32x4 acc[4][4];
  #pragma unroll
  for (int m=0;m<4;m++)
    #pragma unroll
    for (int n=0;n<4;n++) acc[m][n] = (f32x4){0.f,0.f,0.f,0.f};

  auto STAGE = [&](int b, int k0){
    gload16(Asrc0 + k0 + kcS, As[b] + (size_t)tid*8);
    gload16(Asrc1 + k0 + kcS, As[b] + (size_t)(256+tid)*8);
    gload16(Bb + (size_t)r0s*ldb + k0 + kcS, Bs[b] + (size_t)tid*8);
    gload16(Bb + (size_t)r1s*ldb + k0 + kcS, Bs[b] + (size_t)(256+tid)*8);
  };

  int nt = K >> 5, L = nt - 1;
  STAGE(0, 0);
  if (L >= 1) STAGE(1, 32);
  int i15 = lane & 15, g = lane >> 4;
  for (int i=0; i<nt; ++i){
    int cur = i & 1;
    if (i < L) { VW(4); } else { VW(0); }
    BAR();
    short8 af[4], bfr[4];
    #pragma unroll
    for (int m=0;m<4;m++){
      int row = wr*64 + m*16 + i15;
      int geff = g ^ ((row>>1)&3);
      af[m] = *(const short8*)(As[cur] + row*32 + geff*8);
    }
    #pragma unroll
    for (int n=0;n<4;n++){
      int row = wc*64 + n*16 + i15;
      int geff = g ^ ((row>>1)&3);
      bfr[n] = *(const short8*)(Bs[cur] + row*32 + geff*8);
    }
    LW0();
    BAR();
    if (i + 2 <= L) STAGE(cur, (i+2)*32);
    __builtin_amdgcn_s_setprio(1);
    #pragma unroll
    for (int m=0;m<4;m++)
      #pragma unroll
      for (int n=0;n<4;n++)
        acc[m][n] = __builtin_amdgcn_mfma_f32_16x16x32_bf16(af[m], bfr[n], acc[m][n], 0,0,0);
    __builtin_amdgcn_s_setprio(0);
  }

  if (ACT){
    int rbase = rb + wr*64, cb = tN*128 + wc*64;
    #pragma unroll
    for (int m=0;m<4;m++){
      int r0 = rbase + m*16 + ((lane>>4)<<2);
      #pragma unroll
      for (int n=0;n<4;n++){
        int f = ((cb + n*16)>>1) + (lane&7);
        #pragma unroll
        for (int r=0;r<4;r++){
          float v = acc[m][n][r];
          float vp = __shfl_xor(v, 8);
          if (!(lane&8)){
            float gg = v;
            float a = gg/(1.f+__expf(-gg))*vp;
            C[(size_t)(r0+r)*ldc + f] = f2bf(a);
          }
        }
      }
    }
  } else {
    int rbase = rb + wr*64, cb = tN*128 + wc*64;
    #pragma unroll
    for (int m=0;m<4;m++){
      int r0 = rbase + m*16 + ((lane>>4)<<2);
      #pragma unroll
      for (int n=0;n<4;n++){
        int c = cb + n*16 + (lane&15);
        #pragma unroll
        for (int r=0;r<4;r++) C[(size_t)(r0+r)*ldc + c] = f2bf(acc[m][n][r]);
      }
    }
  }
}

// ---------------- high-precision bf16x3 GEMM (plain, XCD swizzle) ----
__global__ __launch_bounds__(256) void k_gemm_hp(
    const unsigned short* __restrict__ Ah, const unsigned short* __restrict__ Al,
    const unsigned short* __restrict__ Bh, const unsigned short* __restrict__ Bl,
    float* __restrict__ Cf,
    int K, int lda, int ldb, int ldc){
  int nx = gridDim.x, nwg = nx*gridDim.y;
  int w = xcd_swz(blockIdx.x + nx*blockIdx.y, nwg);
  int tN = w % nx, tM = w / nx;

  __shared__ __align__(16) unsigned short AsH[2][4096], AsL[2][4096];
  __shared__ __align__(16) unsigned short BsH[2][4096], BsL[2][4096];
  int tid = threadIdx.x, lane = tid & 63, wid = tid >> 6;
  int wr = wid >> 1, wc = wid & 1;
  const unsigned short* Abh = Ah + (size_t)tM*128*lda;
  const unsigned short* Abl = Al + (size_t)tM*128*lda;
  const unsigned short* Bbh = Bh + (size_t)tN*128*ldb;
  const unsigned short* Bbl = Bl + (size_t)tN*128*ldb;

  f32x4 acc[4][4];
  #pragma unroll
  for (int m=0;m<4;m++)
    #pragma unroll
    for (int n=0;n<4;n++) acc[m][n] = (f32x4){0.f,0.f,0.f,0.f};

  auto STAGE = [&](int b, int k0){
    #pragma unroll
    for (int j=0;j<2;j++){
      int cb = j*256 + tid;
      int row = cb>>2, kc = cb&3;
      int kcS = (kc ^ ((row>>1)&3))*8;
      size_t go = (size_t)row*lda + k0 + kcS;
      gload16(Abh + go, AsH[b] + (size_t)cb*8);
      gload16(Abl + go, AsL[b] + (size_t)cb*8);
      size_t bo = (size_t)row*ldb + k0 + kcS;
      gload16(Bbh + bo, BsH[b] + (size_t)cb*8);
      gload16(Bbl + bo, BsL[b] + (size_t)cb*8);
    }
  };

  int nt = K >> 5, L = nt - 1;
  STAGE(0, 0);
  if (L >= 1) STAGE(1, 32);
  int i15 = lane & 15, g = lane >> 4;
  for (int i=0; i<nt; ++i){
    int cur = i & 1;
    if (i < L) { VW(8); } else { VW(0); }
    BAR();
    short8 afh[4], afl[4], bfh[4], bfl[4];
    #pragma unroll
    for (int m=0;m<4;m++){
      int row = wr*64 + m*16 + i15;
      int ro = row*32 + (g ^ ((row>>1)&3))*8;
      afh[m] = *(const short8*)(AsH[cur] + ro);
      afl[m] = *(const short8*)(AsL[cur] + ro);
    }
    #pragma unroll
    for (int n=0;n<4;n++){
      int row = wc*64 + n*16 + i15;
      int ro = row*32 + (g ^ ((row>>1)&3))*8;
      bfh[n] = *(const short8*)(BsH[cur] + ro);
      bfl[n] = *(const short8*)(BsL[cur] + ro);
    }
    LW0();
    BAR();
    if (i + 2 <= L) STAGE(cur, (i+2)*32);
    __builtin_amdgcn_s_setprio(1);
    #pragma unroll
    for (int m=0;m<4;m++)
      #pragma unroll
      for (int n=0;n<4;n++){
        acc[m][n] = __builtin_amdgcn_mfma_f32_16x16x32_bf16(afh[m], bfh[n], acc[m][n], 0,0,0);
        acc[m][n] = __builtin_amdgcn_mfma_f32_16x16x32_bf16(afh[m], bfl[n], acc[m][n], 0,0,0);
        acc[m][n] = __builtin_amdgcn_mfma_f32_16x16x32_bf16(afl[m], bfh[n], acc[m][n], 0,0,0);
      }
    __builtin_amdgcn_s_setprio(0);
  }

  int rb = tM*128 + wr*64, cb = tN*128 + wc*64;
  #pragma unroll
  for (int m=0;m<4;m++){
    int r0 = rb + m*16 + ((lane>>4)<<2);
    #pragma unroll
    for (int n=0;n<4;n++){
      int c = cb + n*16 + (lane&15);
      #pragma unroll
      for (int r=0;r<4;r++) Cf[(size_t)(r0+r)*ldc + c] = acc[m][n][r];
    }
  }
}

// ------- balanced block-row QK^T (hp bf16x3): 2176 uniform tiles over 256 blocks -------
// blocks 0..127 take 9 tiles, 128..255 take 8; segments of same (z,tM) reuse staged Q.
__global__ __launch_bounds__(256) void k_qk_pers(
    const unsigned short* __restrict__ Qh, const unsigned short* __restrict__ Ql,
    const unsigned short* __restrict__ Kh, const unsigned short* __restrict__ Kl,
    float* __restrict__ Sp){
  int bb = blockIdx.x;
  int t0, ntile;
  if (bb < 128){ t0 = bb*9; ntile = 9; }
  else { t0 = 1152 + (bb-128)*8; ntile = 8; }
  const int ldq = NH*HD, ldk = NKV*HD;

  __shared__ __align__(16) unsigned short QsH[16384], QsL[16384];
  __shared__ __align__(16) unsigned short BsH[2][4096], BsL[2][4096];

  int tid = threadIdx.x, lane = tid & 63, wid = tid >> 6;
  int wr = wid >> 1, wc = wid & 1;
  int i15 = lane & 15, g = lane >> 4;

  f32x4 acc[4][4];
  #pragma unroll
  for (int m=0;m<4;m++)
    #pragma unroll
    for (int n=0;n<4;n++) acc[m][n] = (f32x4){0.f,0.f,0.f,0.f};

  int curZ = -1, curM = -1;
  const unsigned short* Kbh = Kh;
  const unsigned short* Kbl = Kl;
  int ti = 0;
  while (ti < ntile){
    int f = t0 + ti;
    int z = f / 136;
    int idx = f - z*136;
    int tM = 0;
    while ((tM+1)*(tM+2)/2 <= idx) tM++;
    int tri = tM*(tM+1)/2;
    int tnS = idx - tri;
    int run = ntile - ti;
    { int rem = tM+1 - tnS; if (rem < run) run = rem; }

    if (z != curZ || tM != curM){
      BAR();
      const unsigned short* Qbh = Qh + (size_t)(tM*128)*ldq + (size_t)z*HD;
      const unsigned short* Qbl = Ql + (size_t)(tM*128)*ldq + (size_t)z*HD;
      #pragma unroll
      for (int j=0;j<8;j++){
        int gi = j*256 + tid;
        int chunk = gi >> 9;
        int row = (gi >> 2) & 127;
        int gg = gi & 3;
        int col = chunk*32 + (gg ^ ((row>>1)&3))*8;
        gload16(Qbh + (size_t)row*ldq + col, QsH + (size_t)gi*8);
        gload16(Qbl + (size_t)row*ldq + col, QsL + (size_t)gi*8);
      }
      curZ = z; curM = tM;
      Kbh = Kh + (size_t)(z>>3)*HD;
      Kbl = Kl + (size_t)(z>>3)*HD;
    }

    auto BSTAGE = [&](int b, int ci){
      int tn = tnS + (ci >> 2), c = ci & 3;
      const unsigned short* sh = Kbh + (size_t)(tn*128)*ldk;
      const unsigned short* sl = Kbl + (size_t)(tn*128)*ldk;
      #pragma unroll
      for (int j=0;j<2;j++){
        int gi = j*256 + tid;
        int row = gi >> 2, gg = gi & 3;
        int col = c*32 + (gg ^ ((row>>1)&3))*8;
        gload16(sh + (size_t)row*ldk + col, BsH[b] + (size_t)gi*8);
        gload16(sl + (size_t)row*ldk + col, BsL[b] + (size_t)gi*8);
      }
    };

    int NC = run*4;
    BSTAGE(0, 0);
    BSTAGE(1, 1);
    for (int ci=0; ci<NC; ++ci){
      int cur = ci & 1, c = ci & 3, tn = tnS + (ci >> 2);
      if (ci < NC-1) { VW(4); } else { VW(0); }
      BAR();
      short8 afh[4], afl[4], bfh[4], bfl[4];
      #pragma unroll
      for (int m=0;m<4;m++){
        int row = wr*64 + m*16 + i15;
        int ro = c*4096 + row*32 + (g ^ ((row>>1)&3))*8;
        afh[m] = *(const short8*)(QsH + ro);
        afl[m] = *(const short8*)(QsL + ro);
      }
      #pragma unroll
      for (int n=0;n<4;n++){
        int row = wc*64 + n*16 + i15;
        int ro = row*32 + (g ^ ((row>>1)&3))*8;
        bfh[n] = *(const short8*)(BsH[cur] + ro);
        bfl[n] = *(const short8*)(BsL[cur] + ro);
      }
      LW0();
      BAR();
      if (ci + 2 < NC) BSTAGE(cur, ci+2);
      __builtin_amdgcn_s_setprio(1);
      #pragma unroll
      for (int m=0;m<4;m++)
        #pragma unroll
        for (int n=0;n<4;n++){
          acc[m][n] = __builtin_amdgcn_mfma_f32_16x16x32_bf16(afh[m], bfh[n], acc[m][n], 0,0,0);
          acc[m][n] = __builtin_amdgcn_mfma_f32_16x16x32_bf16(afh[m], bfl[n], acc[m][n], 0,0,0);
          acc[m][n] = __builtin_amdgcn_mfma_f32_16x16x32_bf16(afl[m], bfh[n], acc[m][n], 0,0,0);
        }
      __builtin_amdgcn_s_setprio(0);
      if (c == 3){
        float* Cb = Sp + ((size_t)z*NBLK + tri + tn)*16384;
        #pragma unroll
        for (int m=0;m<4;m++){
          int r0 = wr*64 + m*16 + (g<<2);
          #pragma unroll
          for (int n=0;n<4;n++){
            int ccol = wc*64 + n*16 + i15;
            #pragma unroll
            for (int r=0;r<4;r++) Cb[(size_t)(r0+r)*128 + ccol] = acc[m][n][r];
          }
        }
        #pragma unroll
        for (int m=0;m<4;m++)
          #pragma unroll
          for (int n=0;n<4;n++) acc[m][n] = (f32x4){0.f,0.f,0.f,0.f};
      }
    }
    ti += run;
  }
}

// ---------------- PV split-K (balanced chunks), unnormalized exp fused in fragment read ---
// Accumulates O~ = sum exp(s*scale) * V and per-row sums; pv_reduce normalizes.
__global__ __launch_bounds__(256) void k_pv_hp(
    const float* __restrict__ Sp,
    const unsigned short* __restrict__ Vh, const unsigned short* __restrict__ Vl,
    float* __restrict__ part, float* __restrict__ rsums){
  int c = blockIdx.x, tM = blockIdx.y, z = blockIdx.z;
  int nc = (tM+4)>>2;               // == ceil((tM+1)/4), matches pv_reduce
  if (c >= nc) return;
  int ntile = tM+1;
  int base = ntile/nc, rem = ntile - base*nc;
  int start = c*base + (c<rem ? c : rem);
  int len = base + (c<rem ? 1 : 0);
  int kbeg = start*128;
  int kend = kbeg + len*128;
  int tMk = tM*128;
  size_t tri = (size_t)tM*(tM+1)/2;
  const float* Ab = Sp + ((size_t)z*NBLK + tri)*16384;
  const unsigned short* Bbh = Vh + (size_t)(z>>3)*HD*T_;
  const unsigned short* Bbl = Vl + (size_t)(z>>3)*HD*T_;

  __shared__ __align__(16) float Asf[2][4096];
  __shared__ __align__(16) unsigned short BsH[2][4096], BsL[2][4096];
  int tid = threadIdx.x, lane = tid & 63, wid = tid >> 6;
  int wr = wid >> 1, wc = wid & 1;
  int i15 = lane & 15, g2 = (lane>>4)*2;

  int r0s = tid>>2, r1s = r0s + 64;
  int kcB = ((tid&3) ^ ((r0s>>1)&3))*8;
  int rowA = tid>>3, gA = tid&7;

  f32x4 acc[4][4];
  #pragma unroll
  for (int m=0;m<4;m++)
    #pragma unroll
    for (int n=0;n<4;n++) acc[m][n] = (f32x4){0.f,0.f,0.f,0.f};
  float rsum[4] = {0.f,0.f,0.f,0.f};

  auto STAGE = [&](int b, int k0){
    #pragma unroll
    for (int j=0;j<4;j++){
      int r = j*32 + rowA;
      int gS = gA ^ (r & 7);
      size_t ga = (size_t)(k0>>7)*16384 + (size_t)r*128 + (k0&127) + gS*4;
      gload16(Ab + ga, Asf[b] + ((size_t)j*256 + tid)*4);
    }
    size_t bo0 = (size_t)r0s*T_ + k0 + kcB;
    size_t bo1 = (size_t)r1s*T_ + k0 + kcB;
    gload16(Bbh + bo0, BsH[b] + (size_t)tid*8);
    gload16(Bbh + bo1, BsH[b] + (size_t)(256+tid)*8);
    gload16(Bbl + bo0, BsL[b] + (size_t)tid*8);
    gload16(Bbl + bo1, BsL[b] + (size_t)(256+tid)*8);
  };

  int nt = (kend - kbeg) >> 5, L = nt - 1;
  STAGE(0, kbeg);
  if (L >= 1) STAGE(1, kbeg + 32);
  for (int i=0; i<nt; ++i){
    int cur = i & 1;
    int k0 = kbeg + i*32;
    if (i < L) { VW(8); } else { VW(0); }
    BAR();
    int diag = (k0 >= tMk);
    short8 afh[4], afl[4], bfh[4], bfl[4];
    #pragma unroll
    for (int m=0;m<4;m++){
      int r = wr*64 + m*16 + i15;
      int s0 = r*8 + ((g2  ) ^ (r&7));
      int s1 = r*8 + ((g2+1) ^ (r&7));
      f32x4 a0 = *(const f32x4*)(Asf[cur] + s0*4);
      f32x4 a1 = *(const f32x4*)(Asf[cur] + s1*4);
      float pv[8] = {a0[0],a0[1],a0[2],a0[3],a1[0],a1[1],a1[2],a1[3]};
      if (diag){
        int kb = k0 & 127;
        #pragma unroll
        for (int j=0;j<8;j++){
          int kl = kb + ((j<4) ? g2*4 + j : (g2+1)*4 + (j-4));
          if (kl > r) pv[j] = -3.0e38f;
        }
      }
      short8 h8, l8;
      #pragma unroll
      for (int j=0;j<8;j++){
        float p = __expf(pv[j]*SM_SCALE);
        rsum[m] += p;
        unsigned short hh, ll; split2(p, hh, ll);
        h8[j] = (short)hh; l8[j] = (short)ll;
      }
      afh[m] = h8; afl[m] = l8;
    }
    #pragma unroll
    for (int n=0;n<4;n++){
      int row = wc*64 + n*16 + i15;
      int ro = row*32 + ((lane>>4) ^ ((row>>1)&3))*8;
      bfh[n] = *(const short8*)(BsH[cur] + ro);
      bfl[n] = *(const short8*)(BsL[cur] + ro);
    }
    LW0();
    BAR();
    if (i + 2 <= L) STAGE(cur, kbeg + (i+2)*32);
    __builtin_amdgcn_s_setprio(1);
    #pragma unroll
    for (int m=0;m<4;m++)
      #pragma unroll
      for (int n=0;n<4;n++){
        acc[m][n] = __builtin_amdgcn_mfma_f32_16x16x32_bf16(afh[m], bfh[n], acc[m][n], 0,0,0);
        acc[m][n] = __builtin_amdgcn_mfma_f32_16x16x32_bf16(afh[m], bfl[n], acc[m][n], 0,0,0);
        acc[m][n] = __builtin_amdgcn_mfma_f32_16x16x32_bf16(afl[m], bfh[n], acc[m][n], 0,0,0);
      }
    __builtin_amdgcn_s_setprio(0);
  }

  // per-row sum of exp over this chunk: reduce across the 4 lanes (lane bits 4-5)
  #pragma unroll
  for (int m=0;m<4;m++){
    float v = rsum[m];
    v += __shfl_xor(v, 16);
    v += __shfl_xor(v, 32);
    if ((lane>>4)==0 && wc==0)
      rsums[((size_t)c*NH + z)*T_ + tMk + wr*64 + m*16 + i15] = v;
  }

  float* Cb = part + (size_t)c*T_*DM + (size_t)tMk*DM + (size_t)z*HD;
  #pragma unroll
  for (int m=0;m<4;m++){
    int r0 = wr*64 + m*16 + ((lane>>4)<<2);
    #pragma unroll
    for (int n=0;n<4;n++){
      int ccol = wc*64 + n*16 + (lane&15);
      #pragma unroll
      for (int r=0;r<4;r++) Cb[(size_t)(r0+r)*DM + ccol] = acc[m][n][r];
    }
  }
}

// reduce partials, normalize by row sums -> aoh/aol (bf16 hi/lo)
__global__ void k_pv_reduce(const float* __restrict__ part, const float* __restrict__ rsums,
                            unsigned short* __restrict__ aoh, unsigned short* __restrict__ aol){
  int t = blockIdx.x, tid = threadIdx.x;
  int nc = ((t>>7) + 4) >> 2;
  #pragma unroll
  for (int half=0; half<2; ++half){
    int idx = tid + half*256;
    int z = idx >> 5;                      // float4 index -> head (idx*4 >> 7)
    float tot = 0.f;
    for (int c=0; c<nc; ++c) tot += rsums[((size_t)c*NH + z)*T_ + t];
    float inv = 1.f / tot;
    float4 s = ((const float4*)(part + (size_t)t*DM))[idx];
    for (int c=1; c<nc; ++c){
      float4 v = ((const float4*)(part + (size_t)c*T_*DM + (size_t)t*DM))[idx];
      s.x+=v.x; s.y+=v.y; s.z+=v.z; s.w+=v.w;
    }
    s.x*=inv; s.y*=inv; s.z*=inv; s.w*=inv;
    ushort4 h_, l_;
    split2(s.x,h_.x,l_.x); split2(s.y,h_.y,l_.y); split2(s.z,h_.z,l_.z); split2(s.w,h_.w,l_.w);
    ((ushort4*)(aoh + (size_t)t*DM))[idx] = h_;
    ((ushort4*)(aol + (size_t)t*DM))[idx] = l_;
  }
}

// ---------------- qkv post ----------------
__global__ void k_qkv_post_hp(const float* __restrict__ qkv, const float* __restrict__ bias,
                              const float* __restrict__ qnw, const float* __restrict__ knw,
                              const int* __restrict__ pos_,
                              unsigned short* __restrict__ qhi, unsigned short* __restrict__ qlo,
                              unsigned short* __restrict__ khi, unsigned short* __restrict__ klo,
                              unsigned short* __restrict__ vThi, unsigned short* __restrict__ vTlo){
  int t = blockIdx.x;
  int half = threadIdx.x >> 7;
  int d = threadIdx.x & 127;
  int wseg = (threadIdx.x >> 6) & 1;
  float posf = (float)pos_[t];
  __shared__ float buf[2][128];
  __shared__ float ssum[2][2];
  __shared__ float inv_sh[32];
  if (threadIdx.x < 32)
    inv_sh[threadIdx.x] = (float)pow(1000000.0, -(double)threadIdx.x/32.0);
  __syncthreads();
  for (int it=0; it<10; ++it){
    int seg = it*2 + half;
    float x = qkv[(size_t)t*QKVN + seg*128 + d] + bias[seg*128 + d];
    float p = x*x;
    #pragma unroll
    for (int o=32;o;o>>=1) p += __shfl_xor(p,o);
    if ((threadIdx.x&63)==0) ssum[half][wseg] = p;
    __syncthreads();
    float rs = rsqrtf((ssum[half][0]+ssum[half][1])*(1.f/128.f) + 1e-5f);
    float w = (seg<16) ? qnw[d] : ((seg<18) ? knw[d] : 1.f);
    float nv = x*rs*w;
    buf[half][d] = nv;
    __syncthreads();
    float outv = (seg<18) ? nv : x;
    if (seg < 18 && d < 64){
      int i = d & 31;
      float ang = posf * inv_sh[i];
      float sn, cs; sincosf(ang, &sn, &cs);
      if (d < 32) outv = nv*cs - buf[half][d+32]*sn;
      else        outv = nv*cs + buf[half][d-32]*sn;
    }
    unsigned short h_, l_; split2(outv, h_, l_);
    if (seg < 16){ size_t o = ((size_t)t*NH + seg)*HD + d; qhi[o]=h_; qlo[o]=l_; }
    else if (seg < 18){ size_t o = ((size_t)t*NKV + (seg-16))*HD + d; khi[o]=h_; klo[o]=l_; }
    else { size_t o = ((size_t)(seg-18)*HD + d)*T_ + t; vThi[o]=h_; vTlo[o]=l_; }
    __syncthreads();
  }
}

__global__ void k_combine(const unsigned short* __restrict__ eout,
                          const int* __restrict__ rrow, const float* __restrict__ w4,
                          const int* __restrict__ offs, float* __restrict__ outh){
  int t = blockIdx.x;
  int rs = offs[16] + t;
  int r0=rrow[t*4+0], r1=rrow[t*4+1], r2=rrow[t*4+2], r3=rrow[t*4+3];
  float w0=w4[t*4+0], w1=w4[t*4+1], w2=w4[t*4+2], w3=w4[t*4+3];
  for (int d=threadIdx.x; d<DM; d+=256){
    float v = bf2f(eout[(size_t)rs*DM+d])
            + w0*bf2f(eout[(size_t)r0*DM+d]) + w1*bf2f(eout[(size_t)r1*DM+d])
            + w2*bf2f(eout[(size_t)r2*DM+d]) + w3*bf2f(eout[(size_t)r3*DM+d]);
    outh[(size_t)t*DM+d] = v;
  }
}

// =========================================================================
extern "C" void kernel_launch(void* const* d_in, const int* in_sizes, int n_in,
                              void* d_out, int out_size, void* d_ws, size_t ws_size,
                              hipStream_t stream){
  const int*   positions = (const int*)d_in[0];
  const float* hidden    = (const float*)d_in[1];
  const float* residual  = (const float*)d_in[2];
  const float* ln1       = (const float*)d_in[3];
  const float* ln2       = (const float*)d_in[4];
  const float* w_qkv     = (const float*)d_in[5];
  const float* b_qkv     = (const float*)d_in[6];
  const float* w_o       = (const float*)d_in[7];
  const float* qnw       = (const float*)d_in[8];
  const float* knw       = (const float*)d_in[9];
  const float* gate_w    = (const float*)d_in[10];
  const float* gate_b    = (const float*)d_in[11];
  const float* sh_wgu    = (const float*)d_in[12];
  const float* sh_wd     = (const float*)d_in[13];
  const float* e_wgu     = (const float*)d_in[14];
  const float* e_wd      = (const float*)d_in[15];
  float* out_h   = (float*)d_out;
  float* out_res = (float*)d_out + (size_t)T_*DM;

  char* ws = (char*)d_ws;
  size_t off = 0;
  auto alloc = [&](size_t b){ size_t r = off; off += (b + 255) & ~(size_t)255; return r; };

  // ---- persistent ----
  size_t o_h2b  = alloc((size_t)T_*DM*2);
  size_t o_idx  = alloc((size_t)T_*4*4);
  size_t o_w4   = alloc((size_t)T_*4*4);
  size_t o_offs = alloc(72);
  size_t o_rrow = alloc((size_t)T_*4*4);
  size_t o_tok  = alloc((size_t)ROWS_ALL*4);

  // ---- phase-union arena ----
  size_t U0 = off;
  size_t a = U0;
  auto allocA = [&](size_t b){ size_t r = a; a += (b + 255) & ~(size_t)255; return r; };
  size_t o_h1h  = allocA((size_t)T_*DM*2);
  size_t o_h1l  = allocA((size_t)T_*DM*2);
  size_t o_wqh  = allocA((size_t)QKVN*DM*2);
  size_t o_wql  = allocA((size_t)QKVN*DM*2);
  size_t o_qkvf = allocA((size_t)T_*QKVN*4);
  size_t o_qh   = allocA((size_t)T_*NH*HD*2);
  size_t o_ql   = allocA((size_t)T_*NH*HD*2);
  size_t o_kh   = allocA((size_t)T_*NKV*HD*2);
  size_t o_kl   = allocA((size_t)T_*NKV*HD*2);
  size_t o_vth  = allocA((size_t)NKV*HD*T_*2);
  size_t o_vtl  = allocA((size_t)NKV*HD*T_*2);
  size_t o_woh  = allocA((size_t)DM*DM*2);
  size_t o_wol  = allocA((size_t)DM*DM*2);
  size_t o_aoh  = allocA((size_t)T_*DM*2);
  size_t o_aol  = allocA((size_t)T_*DM*2);
  size_t o_attnP= allocA((size_t)T_*DM*4);
  size_t o_rsum = allocA((size_t)4*NH*T_*4);
  size_t o_Sp   = allocA((size_t)NH*NBLK*16384*4);
  size_t o_pvp  = allocA((size_t)4*T_*DM*4);
  // phase B (MoE)
  size_t b_ = U0;
  auto allocB = [&](size_t b){ size_t r = b_; b_ += (b + 255) & ~(size_t)255; return r; };
  size_t o_ewgu = allocB((size_t)NE*2*IM*DM*2);
  size_t o_ewd  = allocB((size_t)NE*DM*IM*2);
  size_t o_shgu = allocB((size_t)2*ISH*DM*2);
  size_t o_shwd = allocB((size_t)DM*ISH*2);
  size_t o_actx = allocB((size_t)ROWS_ALL*IM*2);
  size_t o_eout = allocB((size_t)ROWS_ALL*DM*2);

  unsigned short* h2b   = (unsigned short*)(ws+o_h2b);
  int*   idx4  = (int*)(ws+o_idx);
  float* w4p   = (float*)(ws+o_w4);
  int*   offs  = (int*)(ws+o_offs);
  int*   rrow  = (int*)(ws+o_rrow);
  int*   tok   = (int*)(ws+o_tok);
  unsigned short* h1h = (unsigned short*)(ws+o_h1h);
  unsigned short* h1l = (unsigned short*)(ws+o_h1l);
  unsigned short* wqh = (unsigned short*)(ws+o_wqh);
  unsigned short* wql = (unsigned short*)(ws+o_wql);
  float*          qkvf= (float*)(ws+o_qkvf);
  unsigned short* qh  = (unsigned short*)(ws+o_qh);
  unsigned short* ql  = (unsigned short*)(ws+o_ql);
  unsigned short* kh  = (unsigned short*)(ws+o_kh);
  unsigned short* kl  = (unsigned short*)(ws+o_kl);
  unsigned short* vth = (unsigned short*)(ws+o_vth);
  unsigned short* vtl = (unsigned short*)(ws+o_vtl);
  unsigned short* woh = (unsigned short*)(ws+o_woh);
  unsigned short* wol = (unsigned short*)(ws+o_wol);
  unsigned short* aoh = (unsigned short*)(ws+o_aoh);
  unsigned short* aol = (unsigned short*)(ws+o_aol);
  float*          attnP=(float*)(ws+o_attnP);
  float*          rsums=(float*)(ws+o_rsum);
  float*          Sp  = (float*)(ws+o_Sp);
  float*          pvpart = (float*)(ws+o_pvp);
  unsigned short* ewguT=(unsigned short*)(ws+o_ewgu);
  unsigned short* ewdT = (unsigned short*)(ws+o_ewd);
  unsigned short* shguT=(unsigned short*)(ws+o_shgu);
  unsigned short* shwdT=(unsigned short*)(ws+o_shwd);
  unsigned short* actx= (unsigned short*)(ws+o_actx);
  unsigned short* eout= (unsigned short*)(ws+o_eout);

  // ---- attention phase (high precision) ----
  k_tconv2<<<dim3(QKVN/64, DM/64, 2),256,0,stream>>>(w_qkv, wqh, wql, w_o, woh, wol);

  k_add_rmsnorm<false><<<T_,256,0,stream>>>(hidden, residual, ln1, out_res, h1h, h1l, nullptr,
                                            nullptr, nullptr, nullptr, nullptr);

  k_gemm_hp<<<dim3(QKVN/128,T_/128,1),256,0,stream>>>(
      h1h, h1l, wqh, wql, qkvf, DM, DM, DM, QKVN);
  k_qkv_post_hp<<<T_,256,0,stream>>>(qkvf, b_qkv, qnw, knw, positions, qh, ql, kh, kl, vth, vtl);

  k_qk_pers<<<dim3(256),256,0,stream>>>(qh, ql, kh, kl, Sp);
  k_pv_hp<<<dim3(4,T_/128,NH),256,0,stream>>>(Sp, vth, vtl, pvpart, rsums);
  k_pv_reduce<<<T_,256,0,stream>>>(pvpart, rsums, aoh, aol);
  k_gemm_hp<<<dim3(DM/128,T_/128,1),256,0,stream>>>(
      aoh, aol, woh, wol, attnP, DM, DM, DM, DM);

  // rmsnorm2 with fused MoE routing (no global atomics)
  k_add_rmsnorm<true><<<T_,256,0,stream>>>(attnP, out_res, ln2, out_res, nullptr, nullptr, h2b,
                                           gate_w, gate_b, idx4, w4p);

  // ---- fused weight conversion + hidden offplace (phase A arena dead now) ----
  k_wconv<<<dim3(48,32,NE+1),256,0,stream>>>(
      e_wgu, ewguT, sh_wgu, shguT, e_wd, ewdT, sh_wd, shwdT, idx4, offs, rrow, tok);

  // ---- unified grouped MLP (experts + shared); silu fused into up-GEMM epilogue ----
  k_gemm2<true, true ><<<dim3(2*IM/128, ROWS_ALL/128, 1),256,0,stream>>>(
      h2b, ewguT, shguT, actx, DM, DM, DM, IM, offs, (size_t)2*IM*DM, tok);
  k_gemm2<false, false><<<dim3(DM/128, ROWS_ALL/128, 1),256,0,stream>>>(
      actx, ewdT, shwdT, eout, IM, IM, IM, DM, offs, (size_t)DM*IM, nullptr);

  // ---- combine ----
  k_combine<<<T_,256,0,stream>>>(eout, rrow, w4p, offs, out_h);
}